// Round 12
// baseline (639.209 us; speedup 1.0000x reference)
//
#include <hip/hip_runtime.h>
#include <math.h>

#define BB 4
#define SS 1024
#define EE 1024
#define HH 16
#define DD 64
#define RR 129
#define PRELW 130   // Pr LDS row stride (ushorts)

typedef __attribute__((ext_vector_type(4))) float f32x4;
typedef __attribute__((ext_vector_type(4))) int   i32x4;
typedef __attribute__((ext_vector_type(8))) short bf8;   // 8 bf16 = 4 VGPR (MFMA A/B frag)
typedef __attribute__((ext_vector_type(4))) short s4v;   // 4 bf16 = 8B

#define MFMA(a, b, c) __builtin_amdgcn_mfma_f32_16x16x32_bf16(a, b, c, 0, 0, 0)

__device__ __forceinline__ float bf2f(unsigned short u) {
    return __uint_as_float(((unsigned)u) << 16);
}
__device__ __forceinline__ unsigned short f2bf(float x) {  // RNE
    unsigned u = __float_as_uint(x);
    return (unsigned short)((u + 0x7fffu + ((u >> 16) & 1u)) >> 16);
}

// ---------------------------------------------------------------------------
// Weight transpose+split: W[K][N] fp32 -> Wt_hi/lo[N][K] bf16.
// ---------------------------------------------------------------------------
__global__ __launch_bounds__(256, 4)
void wtrans_kernel(const float* __restrict__ Wq, const float* __restrict__ Wk,
                   const float* __restrict__ Wv, const float* __restrict__ Wo,
                   unsigned short* __restrict__ wt_hi, unsigned short* __restrict__ wt_lo)
{
    __shared__ float T[64][65];
    const int w = blockIdx.z;
    const float* W = w == 0 ? Wq : (w == 1 ? Wk : (w == 2 ? Wv : Wo));
    const int n0 = blockIdx.x * 64, k0 = blockIdx.y * 64;
    const int tid = threadIdx.x;
#pragma unroll
    for (int i = 0; i < 4; ++i) {
        int c = tid + 256 * i; int r = c >> 4, c4 = c & 15;
        f32x4 v = *(const f32x4*)(W + (size_t)(k0 + r) * EE + n0 + c4 * 4);
        T[r][c4 * 4 + 0] = v.x; T[r][c4 * 4 + 1] = v.y;
        T[r][c4 * 4 + 2] = v.z; T[r][c4 * 4 + 3] = v.w;
    }
    __syncthreads();
#pragma unroll
    for (int i = 0; i < 4; ++i) {
        int c = tid + 256 * i; int r = c >> 4, c4 = c & 15;   // r = n_local, c4 = k group
        float x0 = T[c4 * 4 + 0][r], x1 = T[c4 * 4 + 1][r];
        float x2 = T[c4 * 4 + 2][r], x3 = T[c4 * 4 + 3][r];
        unsigned short h0 = f2bf(x0), h1 = f2bf(x1), h2 = f2bf(x2), h3 = f2bf(x3);
        unsigned short l0 = f2bf(x0 - bf2f(h0)), l1 = f2bf(x1 - bf2f(h1));
        unsigned short l2 = f2bf(x2 - bf2f(h2)), l3 = f2bf(x3 - bf2f(h3));
        size_t o = (size_t)w * 1048576 + (size_t)(n0 + r) * 1024 + k0 + c4 * 4;
        *(s4v*)&wt_hi[o] = (s4v){(short)h0, (short)h1, (short)h2, (short)h3};
        *(s4v*)&wt_lo[o] = (s4v){(short)l0, (short)l1, (short)l2, (short)l3};
    }
}

// ---------------------------------------------------------------------------
// Pack attn_mask int32 -> bitmask u64 words. One thread per word (64 ints).
// ---------------------------------------------------------------------------
__global__ __launch_bounds__(256)
void maskbits_kernel(const int* __restrict__ mask, unsigned long long* __restrict__ mb)
{
    const int w = blockIdx.x * 256 + threadIdx.x;   // 65536 words
    const int* p = mask + (size_t)w * 64;
    unsigned long long bits = 0;
#pragma unroll
    for (int i = 0; i < 16; ++i) {
        int4 v = *(const int4*)(p + i * 4);
        bits |= (unsigned long long)(v.x != 0) << (i * 4 + 0);
        bits |= (unsigned long long)(v.y != 0) << (i * 4 + 1);
        bits |= (unsigned long long)(v.z != 0) << (i * 4 + 2);
        bits |= (unsigned long long)(v.w != 0) << (i * 4 + 3);
    }
    mb[w] = bits;
}

// ---------------------------------------------------------------------------
// Split-bf16 MFMA GEMM body (projections / out-proj).
// ---------------------------------------------------------------------------
template<int ASRC, int EPI>
__device__ __forceinline__ void gemm_body(
    const float* __restrict__ Af,
    const unsigned short* __restrict__ Ah_g, const unsigned short* __restrict__ Al_g,
    const unsigned short* __restrict__ Bh_g, const unsigned short* __restrict__ Bl_g,
    const float* __restrict__ bias,
    float* __restrict__ Yf, unsigned short* __restrict__ Yh, unsigned short* __restrict__ Yl,
    unsigned short* As_h, unsigned short* As_l, unsigned short* Bs_h, unsigned short* Bs_l,
    int m0, int n0)
{
    const int tid = threadIdx.x, lane = tid & 63, wid = tid >> 6;
    const int wm = (wid >> 1) * 64, wn = (wid & 1) * 64;
    f32x4 zero4 = {0.f, 0.f, 0.f, 0.f};
    f32x4 acc[4][4];
#pragma unroll
    for (int a = 0; a < 4; ++a)
#pragma unroll
        for (int b = 0; b < 4; ++b) acc[a][b] = zero4;

    for (int kt = 0; kt < 1024; kt += 64) {
        __syncthreads();
        if (ASRC == 0) {
#pragma unroll
            for (int i = 0; i < 8; ++i) {
                int c = tid + 256 * i; int r = c >> 4, c4 = c & 15;
                f32x4 v = *(const f32x4*)(Af + (size_t)(m0 + r) * 1024 + kt + c4 * 4);
                unsigned short h0 = f2bf(v.x), h1 = f2bf(v.y), h2 = f2bf(v.z), h3 = f2bf(v.w);
                unsigned short l0 = f2bf(v.x - bf2f(h0)), l1 = f2bf(v.y - bf2f(h1));
                unsigned short l2 = f2bf(v.z - bf2f(h2)), l3 = f2bf(v.w - bf2f(h3));
                int off = r * 64 + (((c4 >> 1) ^ (r & 7)) * 8) + (c4 & 1) * 4;
                *(s4v*)&As_h[off] = (s4v){(short)h0, (short)h1, (short)h2, (short)h3};
                *(s4v*)&As_l[off] = (s4v){(short)l0, (short)l1, (short)l2, (short)l3};
            }
        } else {
#pragma unroll
            for (int i = 0; i < 4; ++i) {
                int c = tid + 256 * i; int r = c >> 3, cc = c & 7;
                int off = r * 64 + ((cc ^ (r & 7)) * 8);
                *(bf8*)&As_h[off] = *(const bf8*)(Ah_g + (size_t)(m0 + r) * 1024 + kt + cc * 8);
                *(bf8*)&As_l[off] = *(const bf8*)(Al_g + (size_t)(m0 + r) * 1024 + kt + cc * 8);
            }
        }
#pragma unroll
        for (int i = 0; i < 4; ++i) {
            int c = tid + 256 * i; int r = c >> 3, cc = c & 7;
            int off = r * 64 + ((cc ^ (r & 7)) * 8);
            *(bf8*)&Bs_h[off] = *(const bf8*)(Bh_g + (size_t)(n0 + r) * 1024 + kt + cc * 8);
            *(bf8*)&Bs_l[off] = *(const bf8*)(Bl_g + (size_t)(n0 + r) * 1024 + kt + cc * 8);
        }
        __syncthreads();
#pragma unroll
        for (int ks = 0; ks < 2; ++ks) {
            bf8 ah[4], al[4], bh[4], bl[4];
#pragma unroll
            for (int f = 0; f < 4; ++f) {
                int ra = wm + f * 16 + (lane & 15);
                int ca = (ks * 4 + (lane >> 4)) ^ (ra & 7);
                ah[f] = *(const bf8*)&As_h[ra * 64 + ca * 8];
                al[f] = *(const bf8*)&As_l[ra * 64 + ca * 8];
                int rb = wn + f * 16 + (lane & 15);
                int cb = (ks * 4 + (lane >> 4)) ^ (rb & 7);
                bh[f] = *(const bf8*)&Bs_h[rb * 64 + cb * 8];
                bl[f] = *(const bf8*)&Bs_l[rb * 64 + cb * 8];
            }
#pragma unroll
            for (int fi = 0; fi < 4; ++fi)
#pragma unroll
                for (int fj = 0; fj < 4; ++fj) {
                    acc[fi][fj] = MFMA(ah[fi], bh[fj], acc[fi][fj]);
                    acc[fi][fj] = MFMA(al[fi], bh[fj], acc[fi][fj]);
                    acc[fi][fj] = MFMA(ah[fi], bl[fj], acc[fi][fj]);
                }
        }
    }
    // epilogue: C/D layout (m89): col = lane&15, row = (lane>>4)*4 + reg
#pragma unroll
    for (int fi = 0; fi < 4; ++fi)
#pragma unroll
        for (int fj = 0; fj < 4; ++fj)
#pragma unroll
            for (int rg = 0; rg < 4; ++rg) {
                int m = m0 + wm + fi * 16 + ((lane >> 4) << 2) + rg;
                int n = n0 + wn + fj * 16 + (lane & 15);
                float val = acc[fi][fj][rg] + bias[n];
                if (EPI == 0) {
                    int b = m >> 10, s = m & 1023, h = n >> 6, d = n & 63;
                    size_t o = (((size_t)(b * 16 + h)) * 1024 + s) * 64 + d;
                    unsigned short hv = f2bf(val);
                    unsigned short lv = f2bf(val - bf2f(hv));
                    Yh[o] = hv; Yl[o] = lv;
                } else {
                    Yf[(size_t)m * 1024 + n] = val;
                }
            }
}

__global__ __launch_bounds__(256, 2)
void proj_qkv_kernel(const float* __restrict__ q_in, const float* __restrict__ k_in,
                     const float* __restrict__ v_in,
                     const unsigned short* __restrict__ wt_hi, const unsigned short* __restrict__ wt_lo,
                     const float* __restrict__ bq, const float* __restrict__ bk,
                     const float* __restrict__ bv,
                     unsigned short* qh_hi, unsigned short* qh_lo,
                     unsigned short* kh_hi, unsigned short* kh_lo,
                     unsigned short* vh_hi, unsigned short* vh_lo)
{
    __shared__ __align__(16) unsigned short As_h[128 * 64], As_l[128 * 64];
    __shared__ __align__(16) unsigned short Bs_h[128 * 64], Bs_l[128 * 64];
    const int z = blockIdx.z;
    const float* X = z == 0 ? q_in : (z == 1 ? k_in : v_in);
    const float* bias = z == 0 ? bq : (z == 1 ? bk : bv);
    unsigned short* Yh = z == 0 ? qh_hi : (z == 1 ? kh_hi : vh_hi);
    unsigned short* Yl = z == 0 ? qh_lo : (z == 1 ? kh_lo : vh_lo);
    gemm_body<0, 0>(X, nullptr, nullptr,
                    wt_hi + (size_t)z * 1048576, wt_lo + (size_t)z * 1048576,
                    bias, nullptr, Yh, Yl, As_h, As_l, Bs_h, Bs_l,
                    blockIdx.x * 128, blockIdx.y * 128);
}

__global__ __launch_bounds__(256, 2)
void outproj_kernel(const unsigned short* __restrict__ ctx_hi, const unsigned short* __restrict__ ctx_lo,
                    const unsigned short* __restrict__ wo_hi, const unsigned short* __restrict__ wo_lo,
                    const float* __restrict__ bo, float* __restrict__ out)
{
    __shared__ __align__(16) unsigned short As_h[128 * 64], As_l[128 * 64];
    __shared__ __align__(16) unsigned short Bs_h[128 * 64], Bs_l[128 * 64];
    gemm_body<1, 1>(nullptr, ctx_hi, ctx_lo, wo_hi, wo_lo, bo, out, nullptr, nullptr,
                    As_h, As_l, Bs_h, Bs_l, blockIdx.x * 128, blockIdx.y * 128);
}

// ---------------------------------------------------------------------------
// V transpose: vh[bh][s][d] (ushort) -> vt[bh][d][s]. z: 0=hi,1=lo buffers.
// ---------------------------------------------------------------------------
__global__ __launch_bounds__(256, 4)
void vtrans_kernel(const unsigned short* __restrict__ vh_hi, const unsigned short* __restrict__ vh_lo,
                   unsigned short* __restrict__ vt_hi, unsigned short* __restrict__ vt_lo)
{
    __shared__ unsigned short T[64][72];
    const unsigned short* src = blockIdx.z ? vh_lo : vh_hi;
    unsigned short* dst = blockIdx.z ? vt_lo : vt_hi;
    const int st = blockIdx.x * 64, bh = blockIdx.y, tid = threadIdx.x;
#pragma unroll
    for (int i = 0; i < 4; ++i) {
        int c = tid + 256 * i; int r = c >> 4, d4 = c & 15;
        s4v v = *(const s4v*)(src + ((size_t)bh * 1024 + st + r) * 64 + d4 * 4);
        T[r][d4 * 4 + 0] = (unsigned short)v.x; T[r][d4 * 4 + 1] = (unsigned short)v.y;
        T[r][d4 * 4 + 2] = (unsigned short)v.z; T[r][d4 * 4 + 3] = (unsigned short)v.w;
    }
    __syncthreads();
#pragma unroll
    for (int i = 0; i < 4; ++i) {
        int c = tid + 256 * i; int r = c >> 4, s4_ = c & 15;  // r = d row
        s4v o = {(short)T[s4_ * 4 + 0][r], (short)T[s4_ * 4 + 1][r],
                 (short)T[s4_ * 4 + 2][r], (short)T[s4_ * 4 + 3][r]};
        *(s4v*)(dst + ((size_t)bh * 64 + r) * 1024 + st + s4_ * 4) = o;
    }
}

// ---------------------------------------------------------------------------
// Fused attention (r8 structure, 8 waves): per block 128 i-rows x one head.
// 512 threads keep LDS identical but double waves/CU (8 -> 16): latency was
// the r7-r11 limiter (nothing saturated, occupancy 22%). Grid (x=head,
// y=i-block) for per-XCD K/V L2 reuse; nt stores as in r8 (fastest measured).
// wi in {0..3} owns 32 i-rows (2 frags), wj in {0,1} owns a 64-j half.
// ---------------------------------------------------------------------------
__global__ __launch_bounds__(512, 4)
void attn_fused_kernel(const unsigned short* __restrict__ qh_hi, const unsigned short* __restrict__ qh_lo,
                       const unsigned short* __restrict__ kh_hi, const unsigned short* __restrict__ kh_lo,
                       const unsigned short* __restrict__ vt_hi, const unsigned short* __restrict__ vt_lo,
                       const float* __restrict__ emb, const unsigned long long* __restrict__ mb,
                       float* __restrict__ attn,
                       unsigned short* __restrict__ ctx_hi, unsigned short* __restrict__ ctx_lo)
{
    __shared__ __align__(16) unsigned short SKV[2 * 128 * 64];   // Sh|Sl contiguous (32 KB)
    __shared__ __align__(16) unsigned short Pr[128 * PRELW];
    __shared__ float Sm[2][128], Ss[2][128], SmF[128], SsF[128];
    unsigned short* Sh = SKV;
    unsigned short* Sl = SKV + 128 * 64;
    const int tid = threadIdx.x, lane = tid & 63, wid = tid >> 6;
    const int wi = wid >> 1, wj = wid & 1;           // wi 0..3, wj 0..1
    const int g = lane >> 4, li = lane & 15;
    const int bh = blockIdx.x, i0 = blockIdx.y * 128, b = bh >> 4;
    const f32x4 zero4 = {0.f, 0.f, 0.f, 0.f};

    // ---- stage Q tile (swizzled rows = i) ----
    const unsigned short* qbh = qh_hi + ((size_t)bh * 1024 + i0) * 64;
    const unsigned short* qbl = qh_lo + ((size_t)bh * 1024 + i0) * 64;
#pragma unroll
    for (int i = 0; i < 2; ++i) {
        int c = tid + 512 * i; int r = c >> 3, cc = c & 7;
        int off = r * 64 + ((cc ^ (r & 7)) * 8);
        *(bf8*)&Sh[off] = *(const bf8*)(qbh + r * 64 + cc * 8);
        *(bf8*)&Sl[off] = *(const bf8*)(qbl + r * 64 + cc * 8);
    }
    __syncthreads();

    // ---- Q fragments to registers (2 per wave) ----
    bf8 qfh[2][2], qfl[2][2];
#pragma unroll
    for (int fi = 0; fi < 2; ++fi)
#pragma unroll
        for (int ks = 0; ks < 2; ++ks) {
            int rb = wi * 32 + fi * 16 + li;
            int cb = (ks * 4 + g) ^ (rb & 7);
            qfh[fi][ks] = *(const bf8*)&Sh[rb * 64 + cb * 8];
            qfl[fi][ks] = *(const bf8*)&Sl[rb * 64 + cb * 8];
        }

    // ---- rel-bias Pr[i][r] = q_hi[i]. emb[r] via MFMA, stored bf16 ----
    for (int t = wid; t < 72; t += 8) {       // 8 i-tiles x 9 r-tiles
        const int it = t / 9, rt = t % 9;
        f32x4 pc = zero4;
#pragma unroll
        for (int ks = 0; ks < 2; ++ks) {
            int ra = it * 16 + li;
            int ca = (ks * 4 + g) ^ (ra & 7);
            bf8 aq = *(const bf8*)&Sh[ra * 64 + ca * 8];
            int er = rt * 16 + li; if (er > 128) er = 128;   // clamp OOB rows
            const float* ep = emb + (size_t)er * 64 + ks * 32 + g * 8;
            f32x4 e0 = *(const f32x4*)ep;
            f32x4 e1 = *(const f32x4*)(ep + 4);
            bf8 be = {(short)f2bf(e0.x), (short)f2bf(e0.y), (short)f2bf(e0.z), (short)f2bf(e0.w),
                      (short)f2bf(e1.x), (short)f2bf(e1.y), (short)f2bf(e1.z), (short)f2bf(e1.w)};
            pc = MFMA(aq, be, pc);
        }
        const int rcol = rt * 16 + li;
        if (rcol < RR) {
#pragma unroll
            for (int rg = 0; rg < 4; ++rg)
                Pr[(it * 16 + g * 4 + rg) * PRELW + rcol] = f2bf(pc[rg]);
        }
    }

    float rm[2], rs[2];
#pragma unroll
    for (int i = 0; i < 2; ++i) { rm[i] = -3.0e38f; rs[i] = 0.f; }

    // ================= PASS 1: stats only =================
    for (int jt = 0; jt < 8; ++jt) {
        __syncthreads();   // Pr writes done (jt=0); prior frag reads done (jt>0)
        const unsigned short* kbh = kh_hi + ((size_t)bh * 1024 + jt * 128) * 64;
        const unsigned short* kbl = kh_lo + ((size_t)bh * 1024 + jt * 128) * 64;
#pragma unroll
        for (int i = 0; i < 2; ++i) {
            int c = tid + 512 * i; int r = c >> 3, cc = c & 7;
            int off = r * 64 + ((cc ^ (r & 7)) * 8);
            *(bf8*)&Sh[off] = *(const bf8*)(kbh + r * 64 + cc * 8);
            *(bf8*)&Sl[off] = *(const bf8*)(kbl + r * 64 + cc * 8);
        }
        __syncthreads();
        f32x4 acc[4][2];  // [fj][fi]
#pragma unroll
        for (int a = 0; a < 4; ++a)
#pragma unroll
            for (int c = 0; c < 2; ++c) acc[a][c] = zero4;
#pragma unroll
        for (int ks = 0; ks < 2; ++ks) {
            bf8 kfh[4], kfl[4];
#pragma unroll
            for (int fj = 0; fj < 4; ++fj) {
                int ra = wj * 64 + fj * 16 + li;
                int ca = (ks * 4 + g) ^ (ra & 7);
                kfh[fj] = *(const bf8*)&Sh[ra * 64 + ca * 8];
                kfl[fj] = *(const bf8*)&Sl[ra * 64 + ca * 8];
            }
#pragma unroll
            for (int fj = 0; fj < 4; ++fj)
#pragma unroll
                for (int fi = 0; fi < 2; ++fi) {
                    acc[fj][fi] = MFMA(kfh[fj], qfh[fi][ks], acc[fj][fi]);
                    acc[fj][fi] = MFMA(kfl[fj], qfh[fi][ks], acc[fj][fi]);
                    acc[fj][fi] = MFMA(kfh[fj], qfl[fi][ks], acc[fj][fi]);
                }
        }
#pragma unroll
        for (int fi = 0; fi < 2; ++fi) {
            const int rowL = wi * 32 + fi * 16 + li;
            const int ii = i0 + rowL;
            const unsigned long long mw = mb[((size_t)b * 1024 + ii) * 16 + jt * 2 + wj];
            float p16[4][4];
            float tmax = -3.0e38f;
#pragma unroll
            for (int fj = 0; fj < 4; ++fj)
#pragma unroll
                for (int rg = 0; rg < 4; ++rg) {
                    int jloc = fj * 16 + g * 4 + rg;
                    int jj = jt * 128 + wj * 64 + jloc;
                    int dd = ii - jj; dd = dd < -64 ? -64 : (dd > 64 ? 64 : dd);
                    float s = acc[fj][fi][rg] * 0.125f + bf2f(Pr[rowL * PRELW + dd + 64]);
                    if (!((mw >> jloc) & 1ull)) s = -1.0e30f;
                    p16[fj][rg] = s;
                    tmax = fmaxf(tmax, s);
                }
            tmax = fmaxf(tmax, __shfl_xor(tmax, 16, 64));
            tmax = fmaxf(tmax, __shfl_xor(tmax, 32, 64));
            float nm = fmaxf(rm[fi], tmax);
            float ps = 0.f;
#pragma unroll
            for (int fj = 0; fj < 4; ++fj)
#pragma unroll
                for (int rg = 0; rg < 4; ++rg) ps += __expf(p16[fj][rg] - nm);
            ps += __shfl_xor(ps, 16, 64);
            ps += __shfl_xor(ps, 32, 64);
            rs[fi] = rs[fi] * __expf(rm[fi] - nm) + ps;
            rm[fi] = nm;
        }
    }
    // combine the two j-half waves per i-row
#pragma unroll
    for (int fi = 0; fi < 2; ++fi) {
        if (lane < 16) {
            Sm[wj][wi * 32 + fi * 16 + li] = rm[fi];
            Ss[wj][wi * 32 + fi * 16 + li] = rs[fi];
        }
    }
    __syncthreads();
    if (tid < 128) {
        float m0_ = Sm[0][tid], m1_ = Sm[1][tid];
        float mmx = fmaxf(m0_, m1_);
        SmF[tid] = mmx;
        SsF[tid] = Ss[0][tid] * __expf(m0_ - mmx) + Ss[1][tid] * __expf(m1_ - mmx);
    }
    __syncthreads();
    float mm2[2], iv2[2];
#pragma unroll
    for (int fi = 0; fi < 2; ++fi) {
        mm2[fi] = SmF[wi * 32 + fi * 16 + li];
        iv2[fi] = 1.f / SsF[wi * 32 + fi * 16 + li];
    }

    f32x4 ctx_acc[2][4];  // [fi][fd]
#pragma unroll
    for (int a = 0; a < 2; ++a)
#pragma unroll
        for (int c = 0; c < 4; ++c) ctx_acc[a][c] = zero4;

    // ================= PASS 2: weights write + PV =================
    for (int jt = 0; jt < 8; ++jt) {
        __syncthreads();
        const unsigned short* kbh = kh_hi + ((size_t)bh * 1024 + jt * 128) * 64;
        const unsigned short* kbl = kh_lo + ((size_t)bh * 1024 + jt * 128) * 64;
#pragma unroll
        for (int i = 0; i < 2; ++i) {
            int c = tid + 512 * i; int r = c >> 3, cc = c & 7;
            int off = r * 64 + ((cc ^ (r & 7)) * 8);
            *(bf8*)&Sh[off] = *(const bf8*)(kbh + r * 64 + cc * 8);
            *(bf8*)&Sl[off] = *(const bf8*)(kbl + r * 64 + cc * 8);
        }
        __syncthreads();
        f32x4 acc[4][2];  // identical recompute -> identical s values
#pragma unroll
        for (int a = 0; a < 4; ++a)
#pragma unroll
            for (int c = 0; c < 2; ++c) acc[a][c] = zero4;
#pragma unroll
        for (int ks = 0; ks < 2; ++ks) {
            bf8 kfh[4], kfl[4];
#pragma unroll
            for (int fj = 0; fj < 4; ++fj) {
                int ra = wj * 64 + fj * 16 + li;
                int ca = (ks * 4 + g) ^ (ra & 7);
                kfh[fj] = *(const bf8*)&Sh[ra * 64 + ca * 8];
                kfl[fj] = *(const bf8*)&Sl[ra * 64 + ca * 8];
            }
#pragma unroll
            for (int fj = 0; fj < 4; ++fj)
#pragma unroll
                for (int fi = 0; fi < 2; ++fi) {
                    acc[fj][fi] = MFMA(kfh[fj], qfh[fi][ks], acc[fj][fi]);
                    acc[fj][fi] = MFMA(kfl[fj], qfh[fi][ks], acc[fj][fi]);
                    acc[fj][fi] = MFMA(kfh[fj], qfl[fi][ks], acc[fj][fi]);
                }
        }
        // per 32-j chunk: V frags from global vt, p+store+pack, shfl, PV MFMA
#pragma unroll
        for (int c = 0; c < 2; ++c) {
            bf8 vfh[4], vfl[4];
#pragma unroll
            for (int fd = 0; fd < 4; ++fd) {
                size_t vb = (size_t)bh * 65536 + (size_t)(fd * 16 + li) * 1024
                          + jt * 128 + wj * 64 + c * 32 + g * 8;
                vfh[fd] = *(const bf8*)(vt_hi + vb);
                vfl[fd] = *(const bf8*)(vt_lo + vb);
            }
#pragma unroll
            for (int fi = 0; fi < 2; ++fi) {
                const int rowL = wi * 32 + fi * 16 + li;
                const int ii = i0 + rowL;
                const unsigned long long mw = mb[((size_t)b * 1024 + ii) * 16 + jt * 2 + wj];
                const float mmf = mm2[fi], ivf = iv2[fi];
                float* arow = attn + ((size_t)bh * 1024 + ii) * 1024 + jt * 128 + wj * 64 + g * 4;
                unsigned wh[2][2], wl[2][2];
#pragma unroll
                for (int t = 0; t < 2; ++t) {
                    const int fj = c * 2 + t;
                    f32x4 pv;
#pragma unroll
                    for (int rg = 0; rg < 4; ++rg) {
                        int jloc = fj * 16 + g * 4 + rg;
                        int jj = jt * 128 + wj * 64 + jloc;
                        int dd = ii - jj; dd = dd < -64 ? -64 : (dd > 64 ? 64 : dd);
                        float s = acc[fj][fi][rg] * 0.125f + bf2f(Pr[rowL * PRELW + dd + 64]);
                        if (!((mw >> jloc) & 1ull)) s = -1.0e30f;
                        pv[rg] = __expf(s - mmf) * ivf;
                    }
                    __builtin_nontemporal_store(pv, (f32x4*)(arow + fj * 16));  // final weights
                    unsigned short h0 = f2bf(pv.x), h1 = f2bf(pv.y), h2 = f2bf(pv.z), h3 = f2bf(pv.w);
                    wh[t][0] = (unsigned)h0 | ((unsigned)h1 << 16);
                    wh[t][1] = (unsigned)h2 | ((unsigned)h3 << 16);
                    unsigned short l0 = f2bf(pv.x - bf2f(h0)), l1 = f2bf(pv.y - bf2f(h1));
                    unsigned short l2 = f2bf(pv.z - bf2f(h2)), l3 = f2bf(pv.w - bf2f(h3));
                    wl[t][0] = (unsigned)l0 | ((unsigned)l1 << 16);
                    wl[t][1] = (unsigned)l2 | ((unsigned)l3 << 16);
                }
                // redistribute: dest lane g needs tile (g>>1), source groups (g&1)*2, +1
                const int src0 = ((g & 1) * 2) * 16 + li;
                const int src1 = src0 + 16;
                const bool hiT = (g >> 1) & 1;
                int x0A = __shfl((int)wh[0][0], src0, 64), x0B = __shfl((int)wh[1][0], src0, 64);
                int x1A = __shfl((int)wh[0][1], src0, 64), x1B = __shfl((int)wh[1][1], src0, 64);
                int x2A = __shfl((int)wh[0][0], src1, 64), x2B = __shfl((int)wh[1][0], src1, 64);
                int x3A = __shfl((int)wh[0][1], src1, 64), x3B = __shfl((int)wh[1][1], src1, 64);
                i32x4 awh = {hiT ? x0B : x0A, hiT ? x1B : x1A, hiT ? x2B : x2A, hiT ? x3B : x3A};
                bf8 pah = *(bf8*)&awh;
                int y0A = __shfl((int)wl[0][0], src0, 64), y0B = __shfl((int)wl[1][0], src0, 64);
                int y1A = __shfl((int)wl[0][1], src0, 64), y1B = __shfl((int)wl[1][1], src0, 64);
                int y2A = __shfl((int)wl[0][0], src1, 64), y2B = __shfl((int)wl[1][0], src1, 64);
                int y3A = __shfl((int)wl[0][1], src1, 64), y3B = __shfl((int)wl[1][1], src1, 64);
                i32x4 awl = {hiT ? y0B : y0A, hiT ? y1B : y1A, hiT ? y2B : y2A, hiT ? y3B : y3A};
                bf8 pal = *(bf8*)&awl;
#pragma unroll
                for (int fd = 0; fd < 4; ++fd) {
                    ctx_acc[fi][fd] = MFMA(pah, vfh[fd], ctx_acc[fi][fd]);
                    ctx_acc[fi][fd] = MFMA(pal, vfh[fd], ctx_acc[fi][fd]);
                    ctx_acc[fi][fd] = MFMA(pah, vfl[fd], ctx_acc[fi][fd]);
                }
            }
        }
    }

    // ---- reduce ctx_acc across the wj wave pair (SKV reused as scratch) ----
    __syncthreads();                         // all waves done reading Sh/Sl
    float* red = (float*)SKV + (size_t)wi * 2048;   // 2048 floats per wi quarter
    if (wj == 1) {
#pragma unroll
        for (int fi = 0; fi < 2; ++fi)
#pragma unroll
            for (int fd = 0; fd < 4; ++fd)
#pragma unroll
                for (int rg = 0; rg < 4; ++rg) {
                    int idx = (fi * 4 + fd) * 4 + rg;
                    red[lane * 32 + ((idx + lane) & 31)] = ctx_acc[fi][fd][rg];
                }
    }
    __syncthreads();
    if (wj == 0) {
        const int b_ = bh >> 4, h = bh & 15;
#pragma unroll
        for (int fi = 0; fi < 2; ++fi)
#pragma unroll
            for (int fd = 0; fd < 4; ++fd)
#pragma unroll
                for (int rg = 0; rg < 4; ++rg) {
                    int idx = (fi * 4 + fd) * 4 + rg;
                    float val = ctx_acc[fi][fd][rg] + red[lane * 32 + ((idx + lane) & 31)];
                    int ii = i0 + wi * 32 + fi * 16 + g * 4 + rg;
                    int d = fd * 16 + li;
                    size_t o = ((size_t)b_ * 1024 + ii) * 1024 + h * 64 + d;
                    unsigned short hv = f2bf(val);
                    unsigned short lv = f2bf(val - bf2f(hv));
                    __builtin_nontemporal_store(hv, &ctx_hi[o]);
                    __builtin_nontemporal_store(lv, &ctx_lo[o]);
                }
    }
}

extern "C" void kernel_launch(void* const* d_in, const int* in_sizes, int n_in,
                              void* d_out, int out_size, void* d_ws, size_t ws_size,
                              hipStream_t stream)
{
    const float* query = (const float*)d_in[0];
    const float* key_  = (const float*)d_in[1];
    const float* value = (const float*)d_in[2];
    const int*   mask  = (const int*)d_in[3];
    const float* Wq = (const float*)d_in[4];
    const float* bq = (const float*)d_in[5];
    const float* Wk = (const float*)d_in[6];
    const float* bk = (const float*)d_in[7];
    const float* Wv = (const float*)d_in[8];
    const float* bv = (const float*)d_in[9];
    const float* Wo = (const float*)d_in[10];
    const float* bo = (const float*)d_in[11];
    const float* emb = (const float*)d_in[12];

    // workspace: 80.0 MB (<= 84.1 MB proven in earlier rounds)
    unsigned short* wt_hi = (unsigned short*)d_ws;           // [4][1024][1024]
    unsigned short* wt_lo = wt_hi + (size_t)4 * 1048576;
    unsigned short* qh_hi = wt_lo + (size_t)4 * 1048576;     // [64][1024][64]
    unsigned short* qh_lo = qh_hi + 4194304;
    unsigned short* kh_hi = qh_lo + 4194304;
    unsigned short* kh_lo = kh_hi + 4194304;
    unsigned short* vt_hi = kh_lo + 4194304;                 // [64][64][1024]
    unsigned short* vt_lo = vt_hi + 4194304;
    unsigned short* ctx_hi = vt_lo + 4194304;                // [4][1024][1024]
    unsigned short* ctx_lo = ctx_hi + 4194304;
    // bitmask overlays the (dead-after-projection) Wq^T-hi region:
    unsigned long long* mb = (unsigned long long*)d_ws;      // [65536] = 512 KB
    // v-heads scratch lives in the out region (dead after vtrans; out written last):
    unsigned short* vh_hi = (unsigned short*)d_out;          // 16 MB region
    unsigned short* vh_lo = vh_hi + 4194304;

    float* out  = (float*)d_out;
    float* attn = (float*)d_out + 4194304;

    dim3 blk(256);
    wtrans_kernel<<<dim3(16, 16, 4), blk, 0, stream>>>(Wq, Wk, Wv, Wo, wt_hi, wt_lo);
    proj_qkv_kernel<<<dim3(32, 8, 3), blk, 0, stream>>>(query, key_, value, wt_hi, wt_lo,
                                                        bq, bk, bv, qh_hi, qh_lo,
                                                        kh_hi, kh_lo, vh_hi, vh_lo);
    maskbits_kernel<<<dim3(256), blk, 0, stream>>>(mask, mb);   // after proj (mb overlays Wq^T)
    vtrans_kernel<<<dim3(16, 64, 2), blk, 0, stream>>>(vh_hi, vh_lo, vt_hi, vt_lo);
    attn_fused_kernel<<<dim3(64, 8), dim3(512), 0, stream>>>(qh_hi, qh_lo, kh_hi, kh_lo,
                                                             vt_hi, vt_lo, emb, mb,
                                                             attn, ctx_hi, ctx_lo);
    outproj_kernel<<<dim3(32, 8), blk, 0, stream>>>(ctx_hi, ctx_lo,
                                                    wt_hi + (size_t)3 * 1048576,
                                                    wt_lo + (size_t)3 * 1048576, bo, out);
}

// Round 13
// 583.753 us; speedup vs baseline: 1.0950x; 1.0950x over previous
//
#include <hip/hip_runtime.h>
#include <math.h>

#define BB 4
#define SS 1024
#define EE 1024
#define HH 16
#define DD 64
#define RR 129
#define PRELW 130   // Pr LDS row stride (ushorts)

typedef __attribute__((ext_vector_type(4))) float f32x4;
typedef __attribute__((ext_vector_type(4))) int   i32x4;
typedef __attribute__((ext_vector_type(8))) short bf8;   // 8 bf16 = 4 VGPR (MFMA A/B frag)
typedef __attribute__((ext_vector_type(4))) short s4v;   // 4 bf16 = 8B

#define MFMA(a, b, c) __builtin_amdgcn_mfma_f32_16x16x32_bf16(a, b, c, 0, 0, 0)

__device__ __forceinline__ float bf2f(unsigned short u) {
    return __uint_as_float(((unsigned)u) << 16);
}
__device__ __forceinline__ unsigned short f2bf(float x) {  // RNE
    unsigned u = __float_as_uint(x);
    return (unsigned short)((u + 0x7fffu + ((u >> 16) & 1u)) >> 16);
}

// ---------------------------------------------------------------------------
// Weight transpose+split: W[K][N] fp32 -> Wt_hi/lo[N][K] bf16.
// ---------------------------------------------------------------------------
__global__ __launch_bounds__(256, 4)
void wtrans_kernel(const float* __restrict__ Wq, const float* __restrict__ Wk,
                   const float* __restrict__ Wv, const float* __restrict__ Wo,
                   unsigned short* __restrict__ wt_hi, unsigned short* __restrict__ wt_lo)
{
    __shared__ float T[64][65];
    const int w = blockIdx.z;
    const float* W = w == 0 ? Wq : (w == 1 ? Wk : (w == 2 ? Wv : Wo));
    const int n0 = blockIdx.x * 64, k0 = blockIdx.y * 64;
    const int tid = threadIdx.x;
#pragma unroll
    for (int i = 0; i < 4; ++i) {
        int c = tid + 256 * i; int r = c >> 4, c4 = c & 15;
        f32x4 v = *(const f32x4*)(W + (size_t)(k0 + r) * EE + n0 + c4 * 4);
        T[r][c4 * 4 + 0] = v.x; T[r][c4 * 4 + 1] = v.y;
        T[r][c4 * 4 + 2] = v.z; T[r][c4 * 4 + 3] = v.w;
    }
    __syncthreads();
#pragma unroll
    for (int i = 0; i < 4; ++i) {
        int c = tid + 256 * i; int r = c >> 4, c4 = c & 15;   // r = n_local, c4 = k group
        float x0 = T[c4 * 4 + 0][r], x1 = T[c4 * 4 + 1][r];
        float x2 = T[c4 * 4 + 2][r], x3 = T[c4 * 4 + 3][r];
        unsigned short h0 = f2bf(x0), h1 = f2bf(x1), h2 = f2bf(x2), h3 = f2bf(x3);
        unsigned short l0 = f2bf(x0 - bf2f(h0)), l1 = f2bf(x1 - bf2f(h1));
        unsigned short l2 = f2bf(x2 - bf2f(h2)), l3 = f2bf(x3 - bf2f(h3));
        size_t o = (size_t)w * 1048576 + (size_t)(n0 + r) * 1024 + k0 + c4 * 4;
        *(s4v*)&wt_hi[o] = (s4v){(short)h0, (short)h1, (short)h2, (short)h3};
        *(s4v*)&wt_lo[o] = (s4v){(short)l0, (short)l1, (short)l2, (short)l3};
    }
}

// ---------------------------------------------------------------------------
// Pack attn_mask int32 -> bitmask u64 words. One thread per word (64 ints).
// ---------------------------------------------------------------------------
__global__ __launch_bounds__(256)
void maskbits_kernel(const int* __restrict__ mask, unsigned long long* __restrict__ mb)
{
    const int w = blockIdx.x * 256 + threadIdx.x;   // 65536 words
    const int* p = mask + (size_t)w * 64;
    unsigned long long bits = 0;
#pragma unroll
    for (int i = 0; i < 16; ++i) {
        int4 v = *(const int4*)(p + i * 4);
        bits |= (unsigned long long)(v.x != 0) << (i * 4 + 0);
        bits |= (unsigned long long)(v.y != 0) << (i * 4 + 1);
        bits |= (unsigned long long)(v.z != 0) << (i * 4 + 2);
        bits |= (unsigned long long)(v.w != 0) << (i * 4 + 3);
    }
    mb[w] = bits;
}

// ---------------------------------------------------------------------------
// Split-bf16 MFMA GEMM body (projections / out-proj).
// ---------------------------------------------------------------------------
template<int ASRC, int EPI>
__device__ __forceinline__ void gemm_body(
    const float* __restrict__ Af,
    const unsigned short* __restrict__ Ah_g, const unsigned short* __restrict__ Al_g,
    const unsigned short* __restrict__ Bh_g, const unsigned short* __restrict__ Bl_g,
    const float* __restrict__ bias,
    float* __restrict__ Yf, unsigned short* __restrict__ Yh, unsigned short* __restrict__ Yl,
    unsigned short* As_h, unsigned short* As_l, unsigned short* Bs_h, unsigned short* Bs_l,
    int m0, int n0)
{
    const int tid = threadIdx.x, lane = tid & 63, wid = tid >> 6;
    const int wm = (wid >> 1) * 64, wn = (wid & 1) * 64;
    f32x4 zero4 = {0.f, 0.f, 0.f, 0.f};
    f32x4 acc[4][4];
#pragma unroll
    for (int a = 0; a < 4; ++a)
#pragma unroll
        for (int b = 0; b < 4; ++b) acc[a][b] = zero4;

    for (int kt = 0; kt < 1024; kt += 64) {
        __syncthreads();
        if (ASRC == 0) {
#pragma unroll
            for (int i = 0; i < 8; ++i) {
                int c = tid + 256 * i; int r = c >> 4, c4 = c & 15;
                f32x4 v = *(const f32x4*)(Af + (size_t)(m0 + r) * 1024 + kt + c4 * 4);
                unsigned short h0 = f2bf(v.x), h1 = f2bf(v.y), h2 = f2bf(v.z), h3 = f2bf(v.w);
                unsigned short l0 = f2bf(v.x - bf2f(h0)), l1 = f2bf(v.y - bf2f(h1));
                unsigned short l2 = f2bf(v.z - bf2f(h2)), l3 = f2bf(v.w - bf2f(h3));
                int off = r * 64 + (((c4 >> 1) ^ (r & 7)) * 8) + (c4 & 1) * 4;
                *(s4v*)&As_h[off] = (s4v){(short)h0, (short)h1, (short)h2, (short)h3};
                *(s4v*)&As_l[off] = (s4v){(short)l0, (short)l1, (short)l2, (short)l3};
            }
        } else {
#pragma unroll
            for (int i = 0; i < 4; ++i) {
                int c = tid + 256 * i; int r = c >> 3, cc = c & 7;
                int off = r * 64 + ((cc ^ (r & 7)) * 8);
                *(bf8*)&As_h[off] = *(const bf8*)(Ah_g + (size_t)(m0 + r) * 1024 + kt + cc * 8);
                *(bf8*)&As_l[off] = *(const bf8*)(Al_g + (size_t)(m0 + r) * 1024 + kt + cc * 8);
            }
        }
#pragma unroll
        for (int i = 0; i < 4; ++i) {
            int c = tid + 256 * i; int r = c >> 3, cc = c & 7;
            int off = r * 64 + ((cc ^ (r & 7)) * 8);
            *(bf8*)&Bs_h[off] = *(const bf8*)(Bh_g + (size_t)(n0 + r) * 1024 + kt + cc * 8);
            *(bf8*)&Bs_l[off] = *(const bf8*)(Bl_g + (size_t)(n0 + r) * 1024 + kt + cc * 8);
        }
        __syncthreads();
#pragma unroll
        for (int ks = 0; ks < 2; ++ks) {
            bf8 ah[4], al[4], bh[4], bl[4];
#pragma unroll
            for (int f = 0; f < 4; ++f) {
                int ra = wm + f * 16 + (lane & 15);
                int ca = (ks * 4 + (lane >> 4)) ^ (ra & 7);
                ah[f] = *(const bf8*)&As_h[ra * 64 + ca * 8];
                al[f] = *(const bf8*)&As_l[ra * 64 + ca * 8];
                int rb = wn + f * 16 + (lane & 15);
                int cb = (ks * 4 + (lane >> 4)) ^ (rb & 7);
                bh[f] = *(const bf8*)&Bs_h[rb * 64 + cb * 8];
                bl[f] = *(const bf8*)&Bs_l[rb * 64 + cb * 8];
            }
#pragma unroll
            for (int fi = 0; fi < 4; ++fi)
#pragma unroll
                for (int fj = 0; fj < 4; ++fj) {
                    acc[fi][fj] = MFMA(ah[fi], bh[fj], acc[fi][fj]);
                    acc[fi][fj] = MFMA(al[fi], bh[fj], acc[fi][fj]);
                    acc[fi][fj] = MFMA(ah[fi], bl[fj], acc[fi][fj]);
                }
        }
    }
    // epilogue: C/D layout (m89): col = lane&15, row = (lane>>4)*4 + reg
#pragma unroll
    for (int fi = 0; fi < 4; ++fi)
#pragma unroll
        for (int fj = 0; fj < 4; ++fj)
#pragma unroll
            for (int rg = 0; rg < 4; ++rg) {
                int m = m0 + wm + fi * 16 + ((lane >> 4) << 2) + rg;
                int n = n0 + wn + fj * 16 + (lane & 15);
                float val = acc[fi][fj][rg] + bias[n];
                if (EPI == 0) {
                    int b = m >> 10, s = m & 1023, h = n >> 6, d = n & 63;
                    size_t o = (((size_t)(b * 16 + h)) * 1024 + s) * 64 + d;
                    unsigned short hv = f2bf(val);
                    unsigned short lv = f2bf(val - bf2f(hv));
                    Yh[o] = hv; Yl[o] = lv;
                } else {
                    Yf[(size_t)m * 1024 + n] = val;
                }
            }
}

__global__ __launch_bounds__(256, 2)
void proj_qkv_kernel(const float* __restrict__ q_in, const float* __restrict__ k_in,
                     const float* __restrict__ v_in,
                     const unsigned short* __restrict__ wt_hi, const unsigned short* __restrict__ wt_lo,
                     const float* __restrict__ bq, const float* __restrict__ bk,
                     const float* __restrict__ bv,
                     unsigned short* qh_hi, unsigned short* qh_lo,
                     unsigned short* kh_hi, unsigned short* kh_lo,
                     unsigned short* vh_hi, unsigned short* vh_lo)
{
    __shared__ __align__(16) unsigned short As_h[128 * 64], As_l[128 * 64];
    __shared__ __align__(16) unsigned short Bs_h[128 * 64], Bs_l[128 * 64];
    const int z = blockIdx.z;
    const float* X = z == 0 ? q_in : (z == 1 ? k_in : v_in);
    const float* bias = z == 0 ? bq : (z == 1 ? bk : bv);
    unsigned short* Yh = z == 0 ? qh_hi : (z == 1 ? kh_hi : vh_hi);
    unsigned short* Yl = z == 0 ? qh_lo : (z == 1 ? kh_lo : vh_lo);
    gemm_body<0, 0>(X, nullptr, nullptr,
                    wt_hi + (size_t)z * 1048576, wt_lo + (size_t)z * 1048576,
                    bias, nullptr, Yh, Yl, As_h, As_l, Bs_h, Bs_l,
                    blockIdx.x * 128, blockIdx.y * 128);
}

__global__ __launch_bounds__(256, 2)
void outproj_kernel(const unsigned short* __restrict__ ctx_hi, const unsigned short* __restrict__ ctx_lo,
                    const unsigned short* __restrict__ wo_hi, const unsigned short* __restrict__ wo_lo,
                    const float* __restrict__ bo, float* __restrict__ out)
{
    __shared__ __align__(16) unsigned short As_h[128 * 64], As_l[128 * 64];
    __shared__ __align__(16) unsigned short Bs_h[128 * 64], Bs_l[128 * 64];
    gemm_body<1, 1>(nullptr, ctx_hi, ctx_lo, wo_hi, wo_lo, bo, out, nullptr, nullptr,
                    As_h, As_l, Bs_h, Bs_l, blockIdx.x * 128, blockIdx.y * 128);
}

// ---------------------------------------------------------------------------
// V transpose: vh[bh][s][d] (ushort) -> vt[bh][d][s]. z: 0=hi,1=lo buffers.
// ---------------------------------------------------------------------------
__global__ __launch_bounds__(256, 4)
void vtrans_kernel(const unsigned short* __restrict__ vh_hi, const unsigned short* __restrict__ vh_lo,
                   unsigned short* __restrict__ vt_hi, unsigned short* __restrict__ vt_lo)
{
    __shared__ unsigned short T[64][72];
    const unsigned short* src = blockIdx.z ? vh_lo : vh_hi;
    unsigned short* dst = blockIdx.z ? vt_lo : vt_hi;
    const int st = blockIdx.x * 64, bh = blockIdx.y, tid = threadIdx.x;
#pragma unroll
    for (int i = 0; i < 4; ++i) {
        int c = tid + 256 * i; int r = c >> 4, d4 = c & 15;
        s4v v = *(const s4v*)(src + ((size_t)bh * 1024 + st + r) * 64 + d4 * 4);
        T[r][d4 * 4 + 0] = (unsigned short)v.x; T[r][d4 * 4 + 1] = (unsigned short)v.y;
        T[r][d4 * 4 + 2] = (unsigned short)v.z; T[r][d4 * 4 + 3] = (unsigned short)v.w;
    }
    __syncthreads();
#pragma unroll
    for (int i = 0; i < 4; ++i) {
        int c = tid + 256 * i; int r = c >> 4, s4_ = c & 15;  // r = d row
        s4v o = {(short)T[s4_ * 4 + 0][r], (short)T[s4_ * 4 + 1][r],
                 (short)T[s4_ * 4 + 2][r], (short)T[s4_ * 4 + 3][r]};
        *(s4v*)(dst + ((size_t)bh * 64 + r) * 1024 + st + s4_ * 4) = o;
    }
}

// ---------------------------------------------------------------------------
// Fused attention (r8 structure + T14 async-STAGE split): per block 128
// i-rows x one head. Grid (x=head, y=i-block) for per-XCD K/V L2 reuse;
// nt stores (fastest measured, r8). K tiles are prefetched into registers
// one jt ahead: regs->LDS right after the barrier, next-tile global loads
// issue before the MFMA block so HBM latency hides under compute (T14).
// ---------------------------------------------------------------------------
__global__ __launch_bounds__(256, 2)
void attn_fused_kernel(const unsigned short* __restrict__ qh_hi, const unsigned short* __restrict__ qh_lo,
                       const unsigned short* __restrict__ kh_hi, const unsigned short* __restrict__ kh_lo,
                       const unsigned short* __restrict__ vt_hi, const unsigned short* __restrict__ vt_lo,
                       const float* __restrict__ emb, const unsigned long long* __restrict__ mb,
                       float* __restrict__ attn,
                       unsigned short* __restrict__ ctx_hi, unsigned short* __restrict__ ctx_lo)
{
    __shared__ __align__(16) unsigned short Sh[128 * 64], Sl[128 * 64];  // Q then K tiles
    __shared__ __align__(16) unsigned short Pr[128 * PRELW];
    __shared__ float Sm[2][128], Ss[2][128], SmF[128], SsF[128];
    const int tid = threadIdx.x, lane = tid & 63, wid = tid >> 6;
    const int wi = wid >> 1, wj = wid & 1;
    const int g = lane >> 4, li = lane & 15;
    const int bh = blockIdx.x, i0 = blockIdx.y * 128, b = bh >> 4;
    const f32x4 zero4 = {0.f, 0.f, 0.f, 0.f};

    // per-thread staging coordinates (constant across tiles)
    const int sr0 = tid >> 3, sc0 = tid & 7;                 // chunk i=0
    const int sr1 = (tid + 256) >> 3, sc1 = (tid + 256) & 7; // chunk i=1
    const int sr2 = (tid + 512) >> 3, sc2 = (tid + 512) & 7;
    const int sr3 = (tid + 768) >> 3, sc3 = (tid + 768) & 7;
    const int so0 = sr0 * 64 + ((sc0 ^ (sr0 & 7)) * 8);
    const int so1 = sr1 * 64 + ((sc1 ^ (sr1 & 7)) * 8);
    const int so2 = sr2 * 64 + ((sc2 ^ (sr2 & 7)) * 8);
    const int so3 = sr3 * 64 + ((sc3 ^ (sr3 & 7)) * 8);

    // ---- stage Q tile (swizzled rows = i) ----
    const unsigned short* qbh = qh_hi + ((size_t)bh * 1024 + i0) * 64;
    const unsigned short* qbl = qh_lo + ((size_t)bh * 1024 + i0) * 64;
    *(bf8*)&Sh[so0] = *(const bf8*)(qbh + sr0 * 64 + sc0 * 8);
    *(bf8*)&Sl[so0] = *(const bf8*)(qbl + sr0 * 64 + sc0 * 8);
    *(bf8*)&Sh[so1] = *(const bf8*)(qbh + sr1 * 64 + sc1 * 8);
    *(bf8*)&Sl[so1] = *(const bf8*)(qbl + sr1 * 64 + sc1 * 8);
    *(bf8*)&Sh[so2] = *(const bf8*)(qbh + sr2 * 64 + sc2 * 8);
    *(bf8*)&Sl[so2] = *(const bf8*)(qbl + sr2 * 64 + sc2 * 8);
    *(bf8*)&Sh[so3] = *(const bf8*)(qbh + sr3 * 64 + sc3 * 8);
    *(bf8*)&Sl[so3] = *(const bf8*)(qbl + sr3 * 64 + sc3 * 8);
    __syncthreads();

    // ---- Q fragments to registers ----
    bf8 qfh[4][2], qfl[4][2];
#pragma unroll
    for (int fi = 0; fi < 4; ++fi)
#pragma unroll
        for (int ks = 0; ks < 2; ++ks) {
            int rb = wi * 64 + fi * 16 + li;
            int cb = (ks * 4 + g) ^ (rb & 7);
            qfh[fi][ks] = *(const bf8*)&Sh[rb * 64 + cb * 8];
            qfl[fi][ks] = *(const bf8*)&Sl[rb * 64 + cb * 8];
        }

    // ---- rel-bias Pr[i][r] = q_hi[i]. emb[r] via MFMA, stored bf16 ----
    for (int t = wid; t < 72; t += 4) {       // 8 i-tiles x 9 r-tiles
        const int it = t / 9, rt = t % 9;
        f32x4 pc = zero4;
#pragma unroll
        for (int ks = 0; ks < 2; ++ks) {
            int ra = it * 16 + li;
            int ca = (ks * 4 + g) ^ (ra & 7);
            bf8 aq = *(const bf8*)&Sh[ra * 64 + ca * 8];
            int er = rt * 16 + li; if (er > 128) er = 128;   // clamp OOB rows
            const float* ep = emb + (size_t)er * 64 + ks * 32 + g * 8;
            f32x4 e0 = *(const f32x4*)ep;
            f32x4 e1 = *(const f32x4*)(ep + 4);
            bf8 be = {(short)f2bf(e0.x), (short)f2bf(e0.y), (short)f2bf(e0.z), (short)f2bf(e0.w),
                      (short)f2bf(e1.x), (short)f2bf(e1.y), (short)f2bf(e1.z), (short)f2bf(e1.w)};
            pc = MFMA(aq, be, pc);
        }
        const int rcol = rt * 16 + li;
        if (rcol < RR) {
#pragma unroll
            for (int rg = 0; rg < 4; ++rg)
                Pr[(it * 16 + g * 4 + rg) * PRELW + rcol] = f2bf(pc[rg]);
        }
    }

    const unsigned short* kb_hi = kh_hi + (size_t)bh * 65536;
    const unsigned short* kb_lo = kh_lo + (size_t)bh * 65536;
    bf8 pfh[4], pfl[4];
    // prologue prefetch: K tile jt=0 into regs
    pfh[0] = *(const bf8*)(kb_hi + sr0 * 64 + sc0 * 8);
    pfl[0] = *(const bf8*)(kb_lo + sr0 * 64 + sc0 * 8);
    pfh[1] = *(const bf8*)(kb_hi + sr1 * 64 + sc1 * 8);
    pfl[1] = *(const bf8*)(kb_lo + sr1 * 64 + sc1 * 8);
    pfh[2] = *(const bf8*)(kb_hi + sr2 * 64 + sc2 * 8);
    pfl[2] = *(const bf8*)(kb_lo + sr2 * 64 + sc2 * 8);
    pfh[3] = *(const bf8*)(kb_hi + sr3 * 64 + sc3 * 8);
    pfl[3] = *(const bf8*)(kb_lo + sr3 * 64 + sc3 * 8);

    float rm[4], rs[4];
#pragma unroll
    for (int i = 0; i < 4; ++i) { rm[i] = -3.0e38f; rs[i] = 0.f; }

    // ================= PASS 1: stats only =================
    for (int jt = 0; jt < 8; ++jt) {
        __syncthreads();   // Pr writes done (jt=0); prior frag reads done (jt>0)
        // write prefetched K tile to LDS
        *(bf8*)&Sh[so0] = pfh[0]; *(bf8*)&Sl[so0] = pfl[0];
        *(bf8*)&Sh[so1] = pfh[1]; *(bf8*)&Sl[so1] = pfl[1];
        *(bf8*)&Sh[so2] = pfh[2]; *(bf8*)&Sl[so2] = pfl[2];
        *(bf8*)&Sh[so3] = pfh[3]; *(bf8*)&Sl[so3] = pfl[3];
        // issue next-tile loads early: latency hides under MFMA + stats below
        if (jt < 7) {
            const unsigned short* nh = kb_hi + (size_t)(jt + 1) * 8192;
            const unsigned short* nl = kb_lo + (size_t)(jt + 1) * 8192;
            pfh[0] = *(const bf8*)(nh + sr0 * 64 + sc0 * 8);
            pfl[0] = *(const bf8*)(nl + sr0 * 64 + sc0 * 8);
            pfh[1] = *(const bf8*)(nh + sr1 * 64 + sc1 * 8);
            pfl[1] = *(const bf8*)(nl + sr1 * 64 + sc1 * 8);
            pfh[2] = *(const bf8*)(nh + sr2 * 64 + sc2 * 8);
            pfl[2] = *(const bf8*)(nl + sr2 * 64 + sc2 * 8);
            pfh[3] = *(const bf8*)(nh + sr3 * 64 + sc3 * 8);
            pfl[3] = *(const bf8*)(nl + sr3 * 64 + sc3 * 8);
        }
        __syncthreads();
        f32x4 acc[4][4];  // [fj][fi]
#pragma unroll
        for (int a = 0; a < 4; ++a)
#pragma unroll
            for (int c = 0; c < 4; ++c) acc[a][c] = zero4;
#pragma unroll
        for (int ks = 0; ks < 2; ++ks) {
            bf8 kfh[4], kfl[4];
#pragma unroll
            for (int fj = 0; fj < 4; ++fj) {
                int ra = wj * 64 + fj * 16 + li;
                int ca = (ks * 4 + g) ^ (ra & 7);
                kfh[fj] = *(const bf8*)&Sh[ra * 64 + ca * 8];
                kfl[fj] = *(const bf8*)&Sl[ra * 64 + ca * 8];
            }
#pragma unroll
            for (int fj = 0; fj < 4; ++fj)
#pragma unroll
                for (int fi = 0; fi < 4; ++fi) {
                    acc[fj][fi] = MFMA(kfh[fj], qfh[fi][ks], acc[fj][fi]);
                    acc[fj][fi] = MFMA(kfl[fj], qfh[fi][ks], acc[fj][fi]);
                    acc[fj][fi] = MFMA(kfh[fj], qfl[fi][ks], acc[fj][fi]);
                }
        }
#pragma unroll
        for (int fi = 0; fi < 4; ++fi) {
            const int rowL = wi * 64 + fi * 16 + li;
            const int ii = i0 + rowL;
            const unsigned long long mw = mb[((size_t)b * 1024 + ii) * 16 + jt * 2 + wj];
            float p16[4][4];
            float tmax = -3.0e38f;
#pragma unroll
            for (int fj = 0; fj < 4; ++fj)
#pragma unroll
                for (int rg = 0; rg < 4; ++rg) {
                    int jloc = fj * 16 + g * 4 + rg;
                    int jj = jt * 128 + wj * 64 + jloc;
                    int dd = ii - jj; dd = dd < -64 ? -64 : (dd > 64 ? 64 : dd);
                    float s = acc[fj][fi][rg] * 0.125f + bf2f(Pr[rowL * PRELW + dd + 64]);
                    if (!((mw >> jloc) & 1ull)) s = -1.0e30f;
                    p16[fj][rg] = s;
                    tmax = fmaxf(tmax, s);
                }
            tmax = fmaxf(tmax, __shfl_xor(tmax, 16, 64));
            tmax = fmaxf(tmax, __shfl_xor(tmax, 32, 64));
            float nm = fmaxf(rm[fi], tmax);
            float ps = 0.f;
#pragma unroll
            for (int fj = 0; fj < 4; ++fj)
#pragma unroll
                for (int rg = 0; rg < 4; ++rg) ps += __expf(p16[fj][rg] - nm);
            ps += __shfl_xor(ps, 16, 64);
            ps += __shfl_xor(ps, 32, 64);
            rs[fi] = rs[fi] * __expf(rm[fi] - nm) + ps;
            rm[fi] = nm;
        }
    }
    // combine the two j-half waves per i-row
#pragma unroll
    for (int fi = 0; fi < 4; ++fi) {
        if (lane < 16) {
            Sm[wj][wi * 64 + fi * 16 + li] = rm[fi];
            Ss[wj][wi * 64 + fi * 16 + li] = rs[fi];
        }
    }
    __syncthreads();
    if (tid < 128) {
        float m0_ = Sm[0][tid], m1_ = Sm[1][tid];
        float mmx = fmaxf(m0_, m1_);
        SmF[tid] = mmx;
        SsF[tid] = Ss[0][tid] * __expf(m0_ - mmx) + Ss[1][tid] * __expf(m1_ - mmx);
    }
    __syncthreads();
    float mm4[4], iv4[4];
#pragma unroll
    for (int fi = 0; fi < 4; ++fi) {
        mm4[fi] = SmF[wi * 64 + fi * 16 + li];
        iv4[fi] = 1.f / SsF[wi * 64 + fi * 16 + li];
    }

    f32x4 ctx_acc[4][4];  // [fi][fd]
#pragma unroll
    for (int a = 0; a < 4; ++a)
#pragma unroll
        for (int c = 0; c < 4; ++c) ctx_acc[a][c] = zero4;

    // prologue prefetch for pass 2 (jt=0)
    pfh[0] = *(const bf8*)(kb_hi + sr0 * 64 + sc0 * 8);
    pfl[0] = *(const bf8*)(kb_lo + sr0 * 64 + sc0 * 8);
    pfh[1] = *(const bf8*)(kb_hi + sr1 * 64 + sc1 * 8);
    pfl[1] = *(const bf8*)(kb_lo + sr1 * 64 + sc1 * 8);
    pfh[2] = *(const bf8*)(kb_hi + sr2 * 64 + sc2 * 8);
    pfl[2] = *(const bf8*)(kb_lo + sr2 * 64 + sc2 * 8);
    pfh[3] = *(const bf8*)(kb_hi + sr3 * 64 + sc3 * 8);
    pfl[3] = *(const bf8*)(kb_lo + sr3 * 64 + sc3 * 8);

    // ================= PASS 2: weights write + PV =================
    for (int jt = 0; jt < 8; ++jt) {
        __syncthreads();
        *(bf8*)&Sh[so0] = pfh[0]; *(bf8*)&Sl[so0] = pfl[0];
        *(bf8*)&Sh[so1] = pfh[1]; *(bf8*)&Sl[so1] = pfl[1];
        *(bf8*)&Sh[so2] = pfh[2]; *(bf8*)&Sl[so2] = pfl[2];
        *(bf8*)&Sh[so3] = pfh[3]; *(bf8*)&Sl[so3] = pfl[3];
        if (jt < 7) {
            const unsigned short* nh = kb_hi + (size_t)(jt + 1) * 8192;
            const unsigned short* nl = kb_lo + (size_t)(jt + 1) * 8192;
            pfh[0] = *(const bf8*)(nh + sr0 * 64 + sc0 * 8);
            pfl[0] = *(const bf8*)(nl + sr0 * 64 + sc0 * 8);
            pfh[1] = *(const bf8*)(nh + sr1 * 64 + sc1 * 8);
            pfl[1] = *(const bf8*)(nl + sr1 * 64 + sc1 * 8);
            pfh[2] = *(const bf8*)(nh + sr2 * 64 + sc2 * 8);
            pfl[2] = *(const bf8*)(nl + sr2 * 64 + sc2 * 8);
            pfh[3] = *(const bf8*)(nh + sr3 * 64 + sc3 * 8);
            pfl[3] = *(const bf8*)(nl + sr3 * 64 + sc3 * 8);
        }
        __syncthreads();
        f32x4 acc[4][4];  // identical recompute -> identical s values
#pragma unroll
        for (int a = 0; a < 4; ++a)
#pragma unroll
            for (int c = 0; c < 4; ++c) acc[a][c] = zero4;
#pragma unroll
        for (int ks = 0; ks < 2; ++ks) {
            bf8 kfh[4], kfl[4];
#pragma unroll
            for (int fj = 0; fj < 4; ++fj) {
                int ra = wj * 64 + fj * 16 + li;
                int ca = (ks * 4 + g) ^ (ra & 7);
                kfh[fj] = *(const bf8*)&Sh[ra * 64 + ca * 8];
                kfl[fj] = *(const bf8*)&Sl[ra * 64 + ca * 8];
            }
#pragma unroll
            for (int fj = 0; fj < 4; ++fj)
#pragma unroll
                for (int fi = 0; fi < 4; ++fi) {
                    acc[fj][fi] = MFMA(kfh[fj], qfh[fi][ks], acc[fj][fi]);
                    acc[fj][fi] = MFMA(kfl[fj], qfh[fi][ks], acc[fj][fi]);
                    acc[fj][fi] = MFMA(kfh[fj], qfl[fi][ks], acc[fj][fi]);
                }
        }
        // per 32-j chunk: V frags from global vt, p+store+pack, shfl, PV MFMA
#pragma unroll
        for (int c = 0; c < 2; ++c) {
            bf8 vfh[4], vfl[4];
#pragma unroll
            for (int fd = 0; fd < 4; ++fd) {
                size_t vb = (size_t)bh * 65536 + (size_t)(fd * 16 + li) * 1024
                          + jt * 128 + wj * 64 + c * 32 + g * 8;
                vfh[fd] = *(const bf8*)(vt_hi + vb);
                vfl[fd] = *(const bf8*)(vt_lo + vb);
            }
#pragma unroll
            for (int fi = 0; fi < 4; ++fi) {
                const int rowL = wi * 64 + fi * 16 + li;
                const int ii = i0 + rowL;
                const unsigned long long mw = mb[((size_t)b * 1024 + ii) * 16 + jt * 2 + wj];
                const float mmf = mm4[fi], ivf = iv4[fi];
                float* arow = attn + ((size_t)bh * 1024 + ii) * 1024 + jt * 128 + wj * 64 + g * 4;
                unsigned wh[2][2], wl[2][2];
#pragma unroll
                for (int t = 0; t < 2; ++t) {
                    const int fj = c * 2 + t;
                    f32x4 pv;
#pragma unroll
                    for (int rg = 0; rg < 4; ++rg) {
                        int jloc = fj * 16 + g * 4 + rg;
                        int jj = jt * 128 + wj * 64 + jloc;
                        int dd = ii - jj; dd = dd < -64 ? -64 : (dd > 64 ? 64 : dd);
                        float s = acc[fj][fi][rg] * 0.125f + bf2f(Pr[rowL * PRELW + dd + 64]);
                        if (!((mw >> jloc) & 1ull)) s = -1.0e30f;
                        pv[rg] = __expf(s - mmf) * ivf;
                    }
                    __builtin_nontemporal_store(pv, (f32x4*)(arow + fj * 16));  // final weights
                    unsigned short h0 = f2bf(pv.x), h1 = f2bf(pv.y), h2 = f2bf(pv.z), h3 = f2bf(pv.w);
                    wh[t][0] = (unsigned)h0 | ((unsigned)h1 << 16);
                    wh[t][1] = (unsigned)h2 | ((unsigned)h3 << 16);
                    unsigned short l0 = f2bf(pv.x - bf2f(h0)), l1 = f2bf(pv.y - bf2f(h1));
                    unsigned short l2 = f2bf(pv.z - bf2f(h2)), l3 = f2bf(pv.w - bf2f(h3));
                    wl[t][0] = (unsigned)l0 | ((unsigned)l1 << 16);
                    wl[t][1] = (unsigned)l2 | ((unsigned)l3 << 16);
                }
                // redistribute: dest lane g needs tile (g>>1), source groups (g&1)*2, +1
                const int src0 = ((g & 1) * 2) * 16 + li;
                const int src1 = src0 + 16;
                const bool hiT = (g >> 1) & 1;
                int x0A = __shfl((int)wh[0][0], src0, 64), x0B = __shfl((int)wh[1][0], src0, 64);
                int x1A = __shfl((int)wh[0][1], src0, 64), x1B = __shfl((int)wh[1][1], src0, 64);
                int x2A = __shfl((int)wh[0][0], src1, 64), x2B = __shfl((int)wh[1][0], src1, 64);
                int x3A = __shfl((int)wh[0][1], src1, 64), x3B = __shfl((int)wh[1][1], src1, 64);
                i32x4 awh = {hiT ? x0B : x0A, hiT ? x1B : x1A, hiT ? x2B : x2A, hiT ? x3B : x3A};
                bf8 pah = *(bf8*)&awh;
                int y0A = __shfl((int)wl[0][0], src0, 64), y0B = __shfl((int)wl[1][0], src0, 64);
                int y1A = __shfl((int)wl[0][1], src0, 64), y1B = __shfl((int)wl[1][1], src0, 64);
                int y2A = __shfl((int)wl[0][0], src1, 64), y2B = __shfl((int)wl[1][0], src1, 64);
                int y3A = __shfl((int)wl[0][1], src1, 64), y3B = __shfl((int)wl[1][1], src1, 64);
                i32x4 awl = {hiT ? y0B : y0A, hiT ? y1B : y1A, hiT ? y2B : y2A, hiT ? y3B : y3A};
                bf8 pal = *(bf8*)&awl;
#pragma unroll
                for (int fd = 0; fd < 4; ++fd) {
                    ctx_acc[fi][fd] = MFMA(pah, vfh[fd], ctx_acc[fi][fd]);
                    ctx_acc[fi][fd] = MFMA(pal, vfh[fd], ctx_acc[fi][fd]);
                    ctx_acc[fi][fd] = MFMA(pah, vfl[fd], ctx_acc[fi][fd]);
                }
            }
        }
    }

    // ---- reduce ctx_acc across the wj wave pair (Sh/Sl reused as scratch) ----
    __syncthreads();                         // all waves done reading Sh/Sl
    float* red = (wi == 0) ? (float*)Sh : (float*)Sl;   // 4096 floats each
    if (wj == 1) {
#pragma unroll
        for (int fi = 0; fi < 4; ++fi)
#pragma unroll
            for (int fd = 0; fd < 4; ++fd)
#pragma unroll
                for (int rg = 0; rg < 4; ++rg) {
                    int idx = (fi * 4 + fd) * 4 + rg;
                    red[lane * 64 + ((idx + lane) & 63)] = ctx_acc[fi][fd][rg];
                }
    }
    __syncthreads();
    if (wj == 0) {
        const int b_ = bh >> 4, h = bh & 15;
#pragma unroll
        for (int fi = 0; fi < 4; ++fi)
#pragma unroll
            for (int fd = 0; fd < 4; ++fd)
#pragma unroll
                for (int rg = 0; rg < 4; ++rg) {
                    int idx = (fi * 4 + fd) * 4 + rg;
                    float val = ctx_acc[fi][fd][rg] + red[lane * 64 + ((idx + lane) & 63)];
                    int ii = i0 + wi * 64 + fi * 16 + g * 4 + rg;
                    int d = fd * 16 + li;
                    size_t o = ((size_t)b_ * 1024 + ii) * 1024 + h * 64 + d;
                    unsigned short hv = f2bf(val);
                    unsigned short lv = f2bf(val - bf2f(hv));
                    __builtin_nontemporal_store(hv, &ctx_hi[o]);
                    __builtin_nontemporal_store(lv, &ctx_lo[o]);
                }
    }
}

extern "C" void kernel_launch(void* const* d_in, const int* in_sizes, int n_in,
                              void* d_out, int out_size, void* d_ws, size_t ws_size,
                              hipStream_t stream)
{
    const float* query = (const float*)d_in[0];
    const float* key_  = (const float*)d_in[1];
    const float* value = (const float*)d_in[2];
    const int*   mask  = (const int*)d_in[3];
    const float* Wq = (const float*)d_in[4];
    const float* bq = (const float*)d_in[5];
    const float* Wk = (const float*)d_in[6];
    const float* bk = (const float*)d_in[7];
    const float* Wv = (const float*)d_in[8];
    const float* bv = (const float*)d_in[9];
    const float* Wo = (const float*)d_in[10];
    const float* bo = (const float*)d_in[11];
    const float* emb = (const float*)d_in[12];

    // workspace: 80.0 MB (<= 84.1 MB proven in earlier rounds)
    unsigned short* wt_hi = (unsigned short*)d_ws;           // [4][1024][1024]
    unsigned short* wt_lo = wt_hi + (size_t)4 * 1048576;
    unsigned short* qh_hi = wt_lo + (size_t)4 * 1048576;     // [64][1024][64]
    unsigned short* qh_lo = qh_hi + 4194304;
    unsigned short* kh_hi = qh_lo + 4194304;
    unsigned short* kh_lo = kh_hi + 4194304;
    unsigned short* vt_hi = kh_lo + 4194304;                 // [64][64][1024]
    unsigned short* vt_lo = vt_hi + 4194304;
    unsigned short* ctx_hi = vt_lo + 4194304;                // [4][1024][1024]
    unsigned short* ctx_lo = ctx_hi + 4194304;
    // bitmask overlays the (dead-after-projection) Wq^T-hi region:
    unsigned long long* mb = (unsigned long long*)d_ws;      // [65536] = 512 KB
    // v-heads scratch lives in the out region (dead after vtrans; out written last):
    unsigned short* vh_hi = (unsigned short*)d_out;          // 16 MB region
    unsigned short* vh_lo = vh_hi + 4194304;

    float* out  = (float*)d_out;
    float* attn = (float*)d_out + 4194304;

    dim3 blk(256);
    wtrans_kernel<<<dim3(16, 16, 4), blk, 0, stream>>>(Wq, Wk, Wv, Wo, wt_hi, wt_lo);
    proj_qkv_kernel<<<dim3(32, 8, 3), blk, 0, stream>>>(query, key_, value, wt_hi, wt_lo,
                                                        bq, bk, bv, qh_hi, qh_lo,
                                                        kh_hi, kh_lo, vh_hi, vh_lo);
    maskbits_kernel<<<dim3(256), blk, 0, stream>>>(mask, mb);   // after proj (mb overlays Wq^T)
    vtrans_kernel<<<dim3(16, 64, 2), blk, 0, stream>>>(vh_hi, vh_lo, vt_hi, vt_lo);
    attn_fused_kernel<<<dim3(64, 8), blk, 0, stream>>>(qh_hi, qh_lo, kh_hi, kh_lo,
                                                       vt_hi, vt_lo, emb, mb,
                                                       attn, ctx_hi, ctx_lo);
    outproj_kernel<<<dim3(32, 8), blk, 0, stream>>>(ctx_hi, ctx_lo,
                                                    wt_hi + (size_t)3 * 1048576,
                                                    wt_lo + (size_t)3 * 1048576, bo, out);
}

// Round 14
// 514.436 us; speedup vs baseline: 1.2425x; 1.1347x over previous
//
#include <hip/hip_runtime.h>
#include <math.h>

#define BB 4
#define SS 1024
#define EE 1024
#define HH 16
#define DD 64
#define RR 129
#define PRELW 130   // Pr LDS row stride (ushorts)

typedef __attribute__((ext_vector_type(4))) float f32x4;
typedef __attribute__((ext_vector_type(4))) int   i32x4;
typedef __attribute__((ext_vector_type(8))) short bf8;   // 8 bf16 = 4 VGPR (MFMA A/B frag)
typedef __attribute__((ext_vector_type(4))) short s4v;   // 4 bf16 = 8B

#define MFMA(a, b, c) __builtin_amdgcn_mfma_f32_16x16x32_bf16(a, b, c, 0, 0, 0)

__device__ __forceinline__ float bf2f(unsigned short u) {
    return __uint_as_float(((unsigned)u) << 16);
}
__device__ __forceinline__ unsigned short f2bf(float x) {  // RNE
    unsigned u = __float_as_uint(x);
    return (unsigned short)((u + 0x7fffu + ((u >> 16) & 1u)) >> 16);
}

// ---------------------------------------------------------------------------
// Weight transpose+split: W[K][N] fp32 -> Wt_hi/lo[N][K] bf16.
// ---------------------------------------------------------------------------
__global__ __launch_bounds__(256, 4)
void wtrans_kernel(const float* __restrict__ Wq, const float* __restrict__ Wk,
                   const float* __restrict__ Wv, const float* __restrict__ Wo,
                   unsigned short* __restrict__ wt_hi, unsigned short* __restrict__ wt_lo)
{
    __shared__ float T[64][65];
    const int w = blockIdx.z;
    const float* W = w == 0 ? Wq : (w == 1 ? Wk : (w == 2 ? Wv : Wo));
    const int n0 = blockIdx.x * 64, k0 = blockIdx.y * 64;
    const int tid = threadIdx.x;
#pragma unroll
    for (int i = 0; i < 4; ++i) {
        int c = tid + 256 * i; int r = c >> 4, c4 = c & 15;
        f32x4 v = *(const f32x4*)(W + (size_t)(k0 + r) * EE + n0 + c4 * 4);
        T[r][c4 * 4 + 0] = v.x; T[r][c4 * 4 + 1] = v.y;
        T[r][c4 * 4 + 2] = v.z; T[r][c4 * 4 + 3] = v.w;
    }
    __syncthreads();
#pragma unroll
    for (int i = 0; i < 4; ++i) {
        int c = tid + 256 * i; int r = c >> 4, c4 = c & 15;   // r = n_local, c4 = k group
        float x0 = T[c4 * 4 + 0][r], x1 = T[c4 * 4 + 1][r];
        float x2 = T[c4 * 4 + 2][r], x3 = T[c4 * 4 + 3][r];
        unsigned short h0 = f2bf(x0), h1 = f2bf(x1), h2 = f2bf(x2), h3 = f2bf(x3);
        unsigned short l0 = f2bf(x0 - bf2f(h0)), l1 = f2bf(x1 - bf2f(h1));
        unsigned short l2 = f2bf(x2 - bf2f(h2)), l3 = f2bf(x3 - bf2f(h3));
        size_t o = (size_t)w * 1048576 + (size_t)(n0 + r) * 1024 + k0 + c4 * 4;
        *(s4v*)&wt_hi[o] = (s4v){(short)h0, (short)h1, (short)h2, (short)h3};
        *(s4v*)&wt_lo[o] = (s4v){(short)l0, (short)l1, (short)l2, (short)l3};
    }
}

// ---------------------------------------------------------------------------
// Pack attn_mask int32 -> bitmask u64 words. One thread per word (64 ints).
// ---------------------------------------------------------------------------
__global__ __launch_bounds__(256)
void maskbits_kernel(const int* __restrict__ mask, unsigned long long* __restrict__ mb)
{
    const int w = blockIdx.x * 256 + threadIdx.x;   // 65536 words
    const int* p = mask + (size_t)w * 64;
    unsigned long long bits = 0;
#pragma unroll
    for (int i = 0; i < 16; ++i) {
        int4 v = *(const int4*)(p + i * 4);
        bits |= (unsigned long long)(v.x != 0) << (i * 4 + 0);
        bits |= (unsigned long long)(v.y != 0) << (i * 4 + 1);
        bits |= (unsigned long long)(v.z != 0) << (i * 4 + 2);
        bits |= (unsigned long long)(v.w != 0) << (i * 4 + 3);
    }
    mb[w] = bits;
}

// ---------------------------------------------------------------------------
// Split-bf16 MFMA GEMM body (projections / out-proj).
// ---------------------------------------------------------------------------
template<int ASRC, int EPI>
__device__ __forceinline__ void gemm_body(
    const float* __restrict__ Af,
    const unsigned short* __restrict__ Ah_g, const unsigned short* __restrict__ Al_g,
    const unsigned short* __restrict__ Bh_g, const unsigned short* __restrict__ Bl_g,
    const float* __restrict__ bias,
    float* __restrict__ Yf, unsigned short* __restrict__ Yh, unsigned short* __restrict__ Yl,
    unsigned short* As_h, unsigned short* As_l, unsigned short* Bs_h, unsigned short* Bs_l,
    int m0, int n0)
{
    const int tid = threadIdx.x, lane = tid & 63, wid = tid >> 6;
    const int wm = (wid >> 1) * 64, wn = (wid & 1) * 64;
    f32x4 zero4 = {0.f, 0.f, 0.f, 0.f};
    f32x4 acc[4][4];
#pragma unroll
    for (int a = 0; a < 4; ++a)
#pragma unroll
        for (int b = 0; b < 4; ++b) acc[a][b] = zero4;

    for (int kt = 0; kt < 1024; kt += 64) {
        __syncthreads();
        if (ASRC == 0) {
#pragma unroll
            for (int i = 0; i < 8; ++i) {
                int c = tid + 256 * i; int r = c >> 4, c4 = c & 15;
                f32x4 v = *(const f32x4*)(Af + (size_t)(m0 + r) * 1024 + kt + c4 * 4);
                unsigned short h0 = f2bf(v.x), h1 = f2bf(v.y), h2 = f2bf(v.z), h3 = f2bf(v.w);
                unsigned short l0 = f2bf(v.x - bf2f(h0)), l1 = f2bf(v.y - bf2f(h1));
                unsigned short l2 = f2bf(v.z - bf2f(h2)), l3 = f2bf(v.w - bf2f(h3));
                int off = r * 64 + (((c4 >> 1) ^ (r & 7)) * 8) + (c4 & 1) * 4;
                *(s4v*)&As_h[off] = (s4v){(short)h0, (short)h1, (short)h2, (short)h3};
                *(s4v*)&As_l[off] = (s4v){(short)l0, (short)l1, (short)l2, (short)l3};
            }
        } else {
#pragma unroll
            for (int i = 0; i < 4; ++i) {
                int c = tid + 256 * i; int r = c >> 3, cc = c & 7;
                int off = r * 64 + ((cc ^ (r & 7)) * 8);
                *(bf8*)&As_h[off] = *(const bf8*)(Ah_g + (size_t)(m0 + r) * 1024 + kt + cc * 8);
                *(bf8*)&As_l[off] = *(const bf8*)(Al_g + (size_t)(m0 + r) * 1024 + kt + cc * 8);
            }
        }
#pragma unroll
        for (int i = 0; i < 4; ++i) {
            int c = tid + 256 * i; int r = c >> 3, cc = c & 7;
            int off = r * 64 + ((cc ^ (r & 7)) * 8);
            *(bf8*)&Bs_h[off] = *(const bf8*)(Bh_g + (size_t)(n0 + r) * 1024 + kt + cc * 8);
            *(bf8*)&Bs_l[off] = *(const bf8*)(Bl_g + (size_t)(n0 + r) * 1024 + kt + cc * 8);
        }
        __syncthreads();
#pragma unroll
        for (int ks = 0; ks < 2; ++ks) {
            bf8 ah[4], al[4], bh[4], bl[4];
#pragma unroll
            for (int f = 0; f < 4; ++f) {
                int ra = wm + f * 16 + (lane & 15);
                int ca = (ks * 4 + (lane >> 4)) ^ (ra & 7);
                ah[f] = *(const bf8*)&As_h[ra * 64 + ca * 8];
                al[f] = *(const bf8*)&As_l[ra * 64 + ca * 8];
                int rb = wn + f * 16 + (lane & 15);
                int cb = (ks * 4 + (lane >> 4)) ^ (rb & 7);
                bh[f] = *(const bf8*)&Bs_h[rb * 64 + cb * 8];
                bl[f] = *(const bf8*)&Bs_l[rb * 64 + cb * 8];
            }
            __builtin_amdgcn_s_setprio(1);
#pragma unroll
            for (int fi = 0; fi < 4; ++fi)
#pragma unroll
                for (int fj = 0; fj < 4; ++fj) {
                    acc[fi][fj] = MFMA(ah[fi], bh[fj], acc[fi][fj]);
                    acc[fi][fj] = MFMA(al[fi], bh[fj], acc[fi][fj]);
                    acc[fi][fj] = MFMA(ah[fi], bl[fj], acc[fi][fj]);
                }
            __builtin_amdgcn_s_setprio(0);
        }
    }
    // epilogue: C/D layout (m89): col = lane&15, row = (lane>>4)*4 + reg
#pragma unroll
    for (int fi = 0; fi < 4; ++fi)
#pragma unroll
        for (int fj = 0; fj < 4; ++fj)
#pragma unroll
            for (int rg = 0; rg < 4; ++rg) {
                int m = m0 + wm + fi * 16 + ((lane >> 4) << 2) + rg;
                int n = n0 + wn + fj * 16 + (lane & 15);
                float val = acc[fi][fj][rg] + bias[n];
                if (EPI == 0) {
                    int b = m >> 10, s = m & 1023, h = n >> 6, d = n & 63;
                    size_t o = (((size_t)(b * 16 + h)) * 1024 + s) * 64 + d;
                    unsigned short hv = f2bf(val);
                    unsigned short lv = f2bf(val - bf2f(hv));
                    Yh[o] = hv; Yl[o] = lv;
                } else {
                    Yf[(size_t)m * 1024 + n] = val;
                }
            }
}

__global__ __launch_bounds__(256, 2)
void proj_qkv_kernel(const float* __restrict__ q_in, const float* __restrict__ k_in,
                     const float* __restrict__ v_in,
                     const unsigned short* __restrict__ wt_hi, const unsigned short* __restrict__ wt_lo,
                     const float* __restrict__ bq, const float* __restrict__ bk,
                     const float* __restrict__ bv,
                     unsigned short* qh_hi, unsigned short* qh_lo,
                     unsigned short* kh_hi, unsigned short* kh_lo,
                     unsigned short* vh_hi, unsigned short* vh_lo)
{
    __shared__ __align__(16) unsigned short As_h[128 * 64], As_l[128 * 64];
    __shared__ __align__(16) unsigned short Bs_h[128 * 64], Bs_l[128 * 64];
    const int z = blockIdx.z;
    const float* X = z == 0 ? q_in : (z == 1 ? k_in : v_in);
    const float* bias = z == 0 ? bq : (z == 1 ? bk : bv);
    unsigned short* Yh = z == 0 ? qh_hi : (z == 1 ? kh_hi : vh_hi);
    unsigned short* Yl = z == 0 ? qh_lo : (z == 1 ? kh_lo : vh_lo);
    gemm_body<0, 0>(X, nullptr, nullptr,
                    wt_hi + (size_t)z * 1048576, wt_lo + (size_t)z * 1048576,
                    bias, nullptr, Yh, Yl, As_h, As_l, Bs_h, Bs_l,
                    blockIdx.x * 128, blockIdx.y * 128);
}

__global__ __launch_bounds__(256, 2)
void outproj_kernel(const unsigned short* __restrict__ ctx_hi, const unsigned short* __restrict__ ctx_lo,
                    const unsigned short* __restrict__ wo_hi, const unsigned short* __restrict__ wo_lo,
                    const float* __restrict__ bo, float* __restrict__ out)
{
    __shared__ __align__(16) unsigned short As_h[128 * 64], As_l[128 * 64];
    __shared__ __align__(16) unsigned short Bs_h[128 * 64], Bs_l[128 * 64];
    gemm_body<1, 1>(nullptr, ctx_hi, ctx_lo, wo_hi, wo_lo, bo, out, nullptr, nullptr,
                    As_h, As_l, Bs_h, Bs_l, blockIdx.x * 128, blockIdx.y * 128);
}

// ---------------------------------------------------------------------------
// V transpose: vh[bh][s][d] (ushort) -> vt[bh][d][s]. z: 0=hi,1=lo buffers.
// ---------------------------------------------------------------------------
__global__ __launch_bounds__(256, 4)
void vtrans_kernel(const unsigned short* __restrict__ vh_hi, const unsigned short* __restrict__ vh_lo,
                   unsigned short* __restrict__ vt_hi, unsigned short* __restrict__ vt_lo)
{
    __shared__ unsigned short T[64][72];
    const unsigned short* src = blockIdx.z ? vh_lo : vh_hi;
    unsigned short* dst = blockIdx.z ? vt_lo : vt_hi;
    const int st = blockIdx.x * 64, bh = blockIdx.y, tid = threadIdx.x;
#pragma unroll
    for (int i = 0; i < 4; ++i) {
        int c = tid + 256 * i; int r = c >> 4, d4 = c & 15;
        s4v v = *(const s4v*)(src + ((size_t)bh * 1024 + st + r) * 64 + d4 * 4);
        T[r][d4 * 4 + 0] = (unsigned short)v.x; T[r][d4 * 4 + 1] = (unsigned short)v.y;
        T[r][d4 * 4 + 2] = (unsigned short)v.z; T[r][d4 * 4 + 3] = (unsigned short)v.w;
    }
    __syncthreads();
#pragma unroll
    for (int i = 0; i < 4; ++i) {
        int c = tid + 256 * i; int r = c >> 4, s4_ = c & 15;  // r = d row
        s4v o = {(short)T[s4_ * 4 + 0][r], (short)T[s4_ * 4 + 1][r],
                 (short)T[s4_ * 4 + 2][r], (short)T[s4_ * 4 + 3][r]};
        *(s4v*)(dst + ((size_t)bh * 64 + r) * 1024 + st + s4_ * 4) = o;
    }
}

// ---------------------------------------------------------------------------
// Fused attention (r8 structure + T5 setprio): per block 128 i-rows x one
// head. Grid (x=head, y=i-block): all i-blocks of a head on ONE XCD -> K/V
// L2 reuse. attn stream nt-stored (fastest measured r8/r10 A/B), ctx plain.
// s_setprio(1) wraps MFMA clusters: with 2 independent blocks/CU at
// different phases, the scheduler favors MFMA-issuing waves (T5 regime).
// ---------------------------------------------------------------------------
__global__ __launch_bounds__(256, 2)
void attn_fused_kernel(const unsigned short* __restrict__ qh_hi, const unsigned short* __restrict__ qh_lo,
                       const unsigned short* __restrict__ kh_hi, const unsigned short* __restrict__ kh_lo,
                       const unsigned short* __restrict__ vt_hi, const unsigned short* __restrict__ vt_lo,
                       const float* __restrict__ emb, const unsigned long long* __restrict__ mb,
                       float* __restrict__ attn,
                       unsigned short* __restrict__ ctx_hi, unsigned short* __restrict__ ctx_lo)
{
    __shared__ __align__(16) unsigned short Sh[128 * 64], Sl[128 * 64];  // Q then K tiles
    __shared__ __align__(16) unsigned short Pr[128 * PRELW];
    __shared__ float Sm[2][128], Ss[2][128], SmF[128], SsF[128];
    const int tid = threadIdx.x, lane = tid & 63, wid = tid >> 6;
    const int wi = wid >> 1, wj = wid & 1;
    const int g = lane >> 4, li = lane & 15;
    const int bh = blockIdx.x, i0 = blockIdx.y * 128, b = bh >> 4;
    const f32x4 zero4 = {0.f, 0.f, 0.f, 0.f};

    // ---- stage Q tile (swizzled rows = i) ----
    const unsigned short* qbh = qh_hi + ((size_t)bh * 1024 + i0) * 64;
    const unsigned short* qbl = qh_lo + ((size_t)bh * 1024 + i0) * 64;
#pragma unroll
    for (int i = 0; i < 4; ++i) {
        int c = tid + 256 * i; int r = c >> 3, cc = c & 7;
        int off = r * 64 + ((cc ^ (r & 7)) * 8);
        *(bf8*)&Sh[off] = *(const bf8*)(qbh + r * 64 + cc * 8);
        *(bf8*)&Sl[off] = *(const bf8*)(qbl + r * 64 + cc * 8);
    }
    __syncthreads();

    // ---- Q fragments to registers ----
    bf8 qfh[4][2], qfl[4][2];
#pragma unroll
    for (int fi = 0; fi < 4; ++fi)
#pragma unroll
        for (int ks = 0; ks < 2; ++ks) {
            int rb = wi * 64 + fi * 16 + li;
            int cb = (ks * 4 + g) ^ (rb & 7);
            qfh[fi][ks] = *(const bf8*)&Sh[rb * 64 + cb * 8];
            qfl[fi][ks] = *(const bf8*)&Sl[rb * 64 + cb * 8];
        }

    // ---- rel-bias Pr[i][r] = q_hi[i]. emb[r] via MFMA, stored bf16 ----
    for (int t = wid; t < 72; t += 4) {       // 8 i-tiles x 9 r-tiles
        const int it = t / 9, rt = t % 9;
        f32x4 pc = zero4;
#pragma unroll
        for (int ks = 0; ks < 2; ++ks) {
            int ra = it * 16 + li;
            int ca = (ks * 4 + g) ^ (ra & 7);
            bf8 aq = *(const bf8*)&Sh[ra * 64 + ca * 8];
            int er = rt * 16 + li; if (er > 128) er = 128;   // clamp OOB rows
            const float* ep = emb + (size_t)er * 64 + ks * 32 + g * 8;
            f32x4 e0 = *(const f32x4*)ep;
            f32x4 e1 = *(const f32x4*)(ep + 4);
            bf8 be = {(short)f2bf(e0.x), (short)f2bf(e0.y), (short)f2bf(e0.z), (short)f2bf(e0.w),
                      (short)f2bf(e1.x), (short)f2bf(e1.y), (short)f2bf(e1.z), (short)f2bf(e1.w)};
            pc = MFMA(aq, be, pc);
        }
        const int rcol = rt * 16 + li;
        if (rcol < RR) {
#pragma unroll
            for (int rg = 0; rg < 4; ++rg)
                Pr[(it * 16 + g * 4 + rg) * PRELW + rcol] = f2bf(pc[rg]);
        }
    }

    float rm[4], rs[4];
#pragma unroll
    for (int i = 0; i < 4; ++i) { rm[i] = -3.0e38f; rs[i] = 0.f; }

    // ================= PASS 1: stats only =================
    for (int jt = 0; jt < 8; ++jt) {
        __syncthreads();   // Pr writes done (jt=0); prior frag reads done (jt>0)
        const unsigned short* kbh = kh_hi + ((size_t)bh * 1024 + jt * 128) * 64;
        const unsigned short* kbl = kh_lo + ((size_t)bh * 1024 + jt * 128) * 64;
#pragma unroll
        for (int i = 0; i < 4; ++i) {
            int c = tid + 256 * i; int r = c >> 3, cc = c & 7;
            int off = r * 64 + ((cc ^ (r & 7)) * 8);
            *(bf8*)&Sh[off] = *(const bf8*)(kbh + r * 64 + cc * 8);
            *(bf8*)&Sl[off] = *(const bf8*)(kbl + r * 64 + cc * 8);
        }
        __syncthreads();
        f32x4 acc[4][4];  // [fj][fi]
#pragma unroll
        for (int a = 0; a < 4; ++a)
#pragma unroll
            for (int c = 0; c < 4; ++c) acc[a][c] = zero4;
#pragma unroll
        for (int ks = 0; ks < 2; ++ks) {
            bf8 kfh[4], kfl[4];
#pragma unroll
            for (int fj = 0; fj < 4; ++fj) {
                int ra = wj * 64 + fj * 16 + li;
                int ca = (ks * 4 + g) ^ (ra & 7);
                kfh[fj] = *(const bf8*)&Sh[ra * 64 + ca * 8];
                kfl[fj] = *(const bf8*)&Sl[ra * 64 + ca * 8];
            }
            __builtin_amdgcn_s_setprio(1);
#pragma unroll
            for (int fj = 0; fj < 4; ++fj)
#pragma unroll
                for (int fi = 0; fi < 4; ++fi) {
                    acc[fj][fi] = MFMA(kfh[fj], qfh[fi][ks], acc[fj][fi]);
                    acc[fj][fi] = MFMA(kfl[fj], qfh[fi][ks], acc[fj][fi]);
                    acc[fj][fi] = MFMA(kfh[fj], qfl[fi][ks], acc[fj][fi]);
                }
            __builtin_amdgcn_s_setprio(0);
        }
#pragma unroll
        for (int fi = 0; fi < 4; ++fi) {
            const int rowL = wi * 64 + fi * 16 + li;
            const int ii = i0 + rowL;
            const unsigned long long mw = mb[((size_t)b * 1024 + ii) * 16 + jt * 2 + wj];
            float p16[4][4];
            float tmax = -3.0e38f;
#pragma unroll
            for (int fj = 0; fj < 4; ++fj)
#pragma unroll
                for (int rg = 0; rg < 4; ++rg) {
                    int jloc = fj * 16 + g * 4 + rg;
                    int jj = jt * 128 + wj * 64 + jloc;
                    int dd = ii - jj; dd = dd < -64 ? -64 : (dd > 64 ? 64 : dd);
                    float s = acc[fj][fi][rg] * 0.125f + bf2f(Pr[rowL * PRELW + dd + 64]);
                    if (!((mw >> jloc) & 1ull)) s = -1.0e30f;
                    p16[fj][rg] = s;
                    tmax = fmaxf(tmax, s);
                }
            tmax = fmaxf(tmax, __shfl_xor(tmax, 16, 64));
            tmax = fmaxf(tmax, __shfl_xor(tmax, 32, 64));
            float nm = fmaxf(rm[fi], tmax);
            float ps = 0.f;
#pragma unroll
            for (int fj = 0; fj < 4; ++fj)
#pragma unroll
                for (int rg = 0; rg < 4; ++rg) ps += __expf(p16[fj][rg] - nm);
            ps += __shfl_xor(ps, 16, 64);
            ps += __shfl_xor(ps, 32, 64);
            rs[fi] = rs[fi] * __expf(rm[fi] - nm) + ps;
            rm[fi] = nm;
        }
    }
    // combine the two j-half waves per i-row
#pragma unroll
    for (int fi = 0; fi < 4; ++fi) {
        if (lane < 16) {
            Sm[wj][wi * 64 + fi * 16 + li] = rm[fi];
            Ss[wj][wi * 64 + fi * 16 + li] = rs[fi];
        }
    }
    __syncthreads();
    if (tid < 128) {
        float m0_ = Sm[0][tid], m1_ = Sm[1][tid];
        float mmx = fmaxf(m0_, m1_);
        SmF[tid] = mmx;
        SsF[tid] = Ss[0][tid] * __expf(m0_ - mmx) + Ss[1][tid] * __expf(m1_ - mmx);
    }
    __syncthreads();
    float mm4[4], iv4[4];
#pragma unroll
    for (int fi = 0; fi < 4; ++fi) {
        mm4[fi] = SmF[wi * 64 + fi * 16 + li];
        iv4[fi] = 1.f / SsF[wi * 64 + fi * 16 + li];
    }

    f32x4 ctx_acc[4][4];  // [fi][fd]
#pragma unroll
    for (int a = 0; a < 4; ++a)
#pragma unroll
        for (int c = 0; c < 4; ++c) ctx_acc[a][c] = zero4;

    // ================= PASS 2: weights write + PV =================
    for (int jt = 0; jt < 8; ++jt) {
        __syncthreads();
        const unsigned short* kbh = kh_hi + ((size_t)bh * 1024 + jt * 128) * 64;
        const unsigned short* kbl = kh_lo + ((size_t)bh * 1024 + jt * 128) * 64;
#pragma unroll
        for (int i = 0; i < 4; ++i) {
            int c = tid + 256 * i; int r = c >> 3, cc = c & 7;
            int off = r * 64 + ((cc ^ (r & 7)) * 8);
            *(bf8*)&Sh[off] = *(const bf8*)(kbh + r * 64 + cc * 8);
            *(bf8*)&Sl[off] = *(const bf8*)(kbl + r * 64 + cc * 8);
        }
        __syncthreads();
        f32x4 acc[4][4];  // identical recompute -> identical s values
#pragma unroll
        for (int a = 0; a < 4; ++a)
#pragma unroll
            for (int c = 0; c < 4; ++c) acc[a][c] = zero4;
#pragma unroll
        for (int ks = 0; ks < 2; ++ks) {
            bf8 kfh[4], kfl[4];
#pragma unroll
            for (int fj = 0; fj < 4; ++fj) {
                int ra = wj * 64 + fj * 16 + li;
                int ca = (ks * 4 + g) ^ (ra & 7);
                kfh[fj] = *(const bf8*)&Sh[ra * 64 + ca * 8];
                kfl[fj] = *(const bf8*)&Sl[ra * 64 + ca * 8];
            }
            __builtin_amdgcn_s_setprio(1);
#pragma unroll
            for (int fj = 0; fj < 4; ++fj)
#pragma unroll
                for (int fi = 0; fi < 4; ++fi) {
                    acc[fj][fi] = MFMA(kfh[fj], qfh[fi][ks], acc[fj][fi]);
                    acc[fj][fi] = MFMA(kfl[fj], qfh[fi][ks], acc[fj][fi]);
                    acc[fj][fi] = MFMA(kfh[fj], qfl[fi][ks], acc[fj][fi]);
                }
            __builtin_amdgcn_s_setprio(0);
        }
        // per 32-j chunk: V frags from global vt, p+store+pack, shfl, PV MFMA
#pragma unroll
        for (int c = 0; c < 2; ++c) {
            bf8 vfh[4], vfl[4];
#pragma unroll
            for (int fd = 0; fd < 4; ++fd) {
                size_t vb = (size_t)bh * 65536 + (size_t)(fd * 16 + li) * 1024
                          + jt * 128 + wj * 64 + c * 32 + g * 8;
                vfh[fd] = *(const bf8*)(vt_hi + vb);
                vfl[fd] = *(const bf8*)(vt_lo + vb);
            }
#pragma unroll
            for (int fi = 0; fi < 4; ++fi) {
                const int rowL = wi * 64 + fi * 16 + li;
                const int ii = i0 + rowL;
                const unsigned long long mw = mb[((size_t)b * 1024 + ii) * 16 + jt * 2 + wj];
                const float mmf = mm4[fi], ivf = iv4[fi];
                float* arow = attn + ((size_t)bh * 1024 + ii) * 1024 + jt * 128 + wj * 64 + g * 4;
                unsigned wh[2][2], wl[2][2];
#pragma unroll
                for (int t = 0; t < 2; ++t) {
                    const int fj = c * 2 + t;
                    f32x4 pv;
#pragma unroll
                    for (int rg = 0; rg < 4; ++rg) {
                        int jloc = fj * 16 + g * 4 + rg;
                        int jj = jt * 128 + wj * 64 + jloc;
                        int dd = ii - jj; dd = dd < -64 ? -64 : (dd > 64 ? 64 : dd);
                        float s = acc[fj][fi][rg] * 0.125f + bf2f(Pr[rowL * PRELW + dd + 64]);
                        if (!((mw >> jloc) & 1ull)) s = -1.0e30f;
                        pv[rg] = __expf(s - mmf) * ivf;
                    }
                    __builtin_nontemporal_store(pv, (f32x4*)(arow + fj * 16));  // final weights
                    unsigned short h0 = f2bf(pv.x), h1 = f2bf(pv.y), h2 = f2bf(pv.z), h3 = f2bf(pv.w);
                    wh[t][0] = (unsigned)h0 | ((unsigned)h1 << 16);
                    wh[t][1] = (unsigned)h2 | ((unsigned)h3 << 16);
                    unsigned short l0 = f2bf(pv.x - bf2f(h0)), l1 = f2bf(pv.y - bf2f(h1));
                    unsigned short l2 = f2bf(pv.z - bf2f(h2)), l3 = f2bf(pv.w - bf2f(h3));
                    wl[t][0] = (unsigned)l0 | ((unsigned)l1 << 16);
                    wl[t][1] = (unsigned)l2 | ((unsigned)l3 << 16);
                }
                // redistribute: dest lane g needs tile (g>>1), source groups (g&1)*2, +1
                const int src0 = ((g & 1) * 2) * 16 + li;
                const int src1 = src0 + 16;
                const bool hiT = (g >> 1) & 1;
                int x0A = __shfl((int)wh[0][0], src0, 64), x0B = __shfl((int)wh[1][0], src0, 64);
                int x1A = __shfl((int)wh[0][1], src0, 64), x1B = __shfl((int)wh[1][1], src0, 64);
                int x2A = __shfl((int)wh[0][0], src1, 64), x2B = __shfl((int)wh[1][0], src1, 64);
                int x3A = __shfl((int)wh[0][1], src1, 64), x3B = __shfl((int)wh[1][1], src1, 64);
                i32x4 awh = {hiT ? x0B : x0A, hiT ? x1B : x1A, hiT ? x2B : x2A, hiT ? x3B : x3A};
                bf8 pah = *(bf8*)&awh;
                int y0A = __shfl((int)wl[0][0], src0, 64), y0B = __shfl((int)wl[1][0], src0, 64);
                int y1A = __shfl((int)wl[0][1], src0, 64), y1B = __shfl((int)wl[1][1], src0, 64);
                int y2A = __shfl((int)wl[0][0], src1, 64), y2B = __shfl((int)wl[1][0], src1, 64);
                int y3A = __shfl((int)wl[0][1], src1, 64), y3B = __shfl((int)wl[1][1], src1, 64);
                i32x4 awl = {hiT ? y0B : y0A, hiT ? y1B : y1A, hiT ? y2B : y2A, hiT ? y3B : y3A};
                bf8 pal = *(bf8*)&awl;
                __builtin_amdgcn_s_setprio(1);
#pragma unroll
                for (int fd = 0; fd < 4; ++fd) {
                    ctx_acc[fi][fd] = MFMA(pah, vfh[fd], ctx_acc[fi][fd]);
                    ctx_acc[fi][fd] = MFMA(pal, vfh[fd], ctx_acc[fi][fd]);
                    ctx_acc[fi][fd] = MFMA(pah, vfl[fd], ctx_acc[fi][fd]);
                }
                __builtin_amdgcn_s_setprio(0);
            }
        }
    }

    // ---- reduce ctx_acc across the wj wave pair (Sh/Sl reused as scratch) ----
    __syncthreads();                         // all waves done reading Sh/Sl
    float* red = (wi == 0) ? (float*)Sh : (float*)Sl;   // 4096 floats each
    if (wj == 1) {
#pragma unroll
        for (int fi = 0; fi < 4; ++fi)
#pragma unroll
            for (int fd = 0; fd < 4; ++fd)
#pragma unroll
                for (int rg = 0; rg < 4; ++rg) {
                    int idx = (fi * 4 + fd) * 4 + rg;
                    red[lane * 64 + ((idx + lane) & 63)] = ctx_acc[fi][fd][rg];
                }
    }
    __syncthreads();
    if (wj == 0) {
        const int b_ = bh >> 4, h = bh & 15;
#pragma unroll
        for (int fi = 0; fi < 4; ++fi)
#pragma unroll
            for (int fd = 0; fd < 4; ++fd)
#pragma unroll
                for (int rg = 0; rg < 4; ++rg) {
                    int idx = (fi * 4 + fd) * 4 + rg;
                    float val = ctx_acc[fi][fd][rg] + red[lane * 64 + ((idx + lane) & 63)];
                    int ii = i0 + wi * 64 + fi * 16 + g * 4 + rg;
                    int d = fd * 16 + li;
                    size_t o = ((size_t)b_ * 1024 + ii) * 1024 + h * 64 + d;
                    unsigned short hv = f2bf(val);
                    unsigned short lv = f2bf(val - bf2f(hv));
                    ctx_hi[o] = hv;        // plain stores: L2 merges the 2B pieces
                    ctx_lo[o] = lv;
                }
    }
}

extern "C" void kernel_launch(void* const* d_in, const int* in_sizes, int n_in,
                              void* d_out, int out_size, void* d_ws, size_t ws_size,
                              hipStream_t stream)
{
    const float* query = (const float*)d_in[0];
    const float* key_  = (const float*)d_in[1];
    const float* value = (const float*)d_in[2];
    const int*   mask  = (const int*)d_in[3];
    const float* Wq = (const float*)d_in[4];
    const float* bq = (const float*)d_in[5];
    const float* Wk = (const float*)d_in[6];
    const float* bk = (const float*)d_in[7];
    const float* Wv = (const float*)d_in[8];
    const float* bv = (const float*)d_in[9];
    const float* Wo = (const float*)d_in[10];
    const float* bo = (const float*)d_in[11];
    const float* emb = (const float*)d_in[12];

    // workspace: 80.0 MB (<= 84.1 MB proven in earlier rounds)
    unsigned short* wt_hi = (unsigned short*)d_ws;           // [4][1024][1024]
    unsigned short* wt_lo = wt_hi + (size_t)4 * 1048576;
    unsigned short* qh_hi = wt_lo + (size_t)4 * 1048576;     // [64][1024][64]
    unsigned short* qh_lo = qh_hi + 4194304;
    unsigned short* kh_hi = qh_lo + 4194304;
    unsigned short* kh_lo = kh_hi + 4194304;
    unsigned short* vt_hi = kh_lo + 4194304;                 // [64][64][1024]
    unsigned short* vt_lo = vt_hi + 4194304;
    unsigned short* ctx_hi = vt_lo + 4194304;                // [4][1024][1024]
    unsigned short* ctx_lo = ctx_hi + 4194304;
    // bitmask overlays the (dead-after-projection) Wq^T-hi region:
    unsigned long long* mb = (unsigned long long*)d_ws;      // [65536] = 512 KB
    // v-heads scratch lives in the out region (dead after vtrans; out written last):
    unsigned short* vh_hi = (unsigned short*)d_out;          // 16 MB region
    unsigned short* vh_lo = vh_hi + 4194304;

    float* out  = (float*)d_out;
    float* attn = (float*)d_out + 4194304;

    dim3 blk(256);
    wtrans_kernel<<<dim3(16, 16, 4), blk, 0, stream>>>(Wq, Wk, Wv, Wo, wt_hi, wt_lo);
    proj_qkv_kernel<<<dim3(32, 8, 3), blk, 0, stream>>>(query, key_, value, wt_hi, wt_lo,
                                                        bq, bk, bv, qh_hi, qh_lo,
                                                        kh_hi, kh_lo, vh_hi, vh_lo);
    maskbits_kernel<<<dim3(256), blk, 0, stream>>>(mask, mb);   // after proj (mb overlays Wq^T)
    vtrans_kernel<<<dim3(16, 64, 2), blk, 0, stream>>>(vh_hi, vh_lo, vt_hi, vt_lo);
    attn_fused_kernel<<<dim3(64, 8), blk, 0, stream>>>(qh_hi, qh_lo, kh_hi, kh_lo,
                                                       vt_hi, vt_lo, emb, mb,
                                                       attn, ctx_hi, ctx_lo);
    outproj_kernel<<<dim3(32, 8), blk, 0, stream>>>(ctx_hi, ctx_lo,
                                                    wt_hi + (size_t)3 * 1048576,
                                                    wt_lo + (size_t)3 * 1048576, bo, out);
}

// Round 15
// 482.597 us; speedup vs baseline: 1.3245x; 1.0660x over previous
//
#include <hip/hip_runtime.h>
#include <math.h>

#define BB 4
#define SS 1024
#define EE 1024
#define HH 16
#define DD 64
#define RR 129
#define PRELW 130   // Pr LDS row stride (ushorts)

typedef __attribute__((ext_vector_type(4))) float f32x4;
typedef __attribute__((ext_vector_type(4))) int   i32x4;
typedef __attribute__((ext_vector_type(8))) short bf8;   // 8 bf16 = 4 VGPR (MFMA A/B frag)
typedef __attribute__((ext_vector_type(4))) short s4v;   // 4 bf16 = 8B

#define MFMA(a, b, c) __builtin_amdgcn_mfma_f32_16x16x32_bf16(a, b, c, 0, 0, 0)

__device__ __forceinline__ float bf2f(unsigned short u) {
    return __uint_as_float(((unsigned)u) << 16);
}
__device__ __forceinline__ unsigned short f2bf(float x) {  // RNE
    unsigned u = __float_as_uint(x);
    return (unsigned short)((u + 0x7fffu + ((u >> 16) & 1u)) >> 16);
}

// ---------------------------------------------------------------------------
// Weight transpose+split: W[K][N] fp32 -> Wt_hi/lo[N][K] bf16.
// ---------------------------------------------------------------------------
__global__ __launch_bounds__(256, 4)
void wtrans_kernel(const float* __restrict__ Wq, const float* __restrict__ Wk,
                   const float* __restrict__ Wv, const float* __restrict__ Wo,
                   unsigned short* __restrict__ wt_hi, unsigned short* __restrict__ wt_lo)
{
    __shared__ float T[64][65];
    const int w = blockIdx.z;
    const float* W = w == 0 ? Wq : (w == 1 ? Wk : (w == 2 ? Wv : Wo));
    const int n0 = blockIdx.x * 64, k0 = blockIdx.y * 64;
    const int tid = threadIdx.x;
#pragma unroll
    for (int i = 0; i < 4; ++i) {
        int c = tid + 256 * i; int r = c >> 4, c4 = c & 15;
        f32x4 v = *(const f32x4*)(W + (size_t)(k0 + r) * EE + n0 + c4 * 4);
        T[r][c4 * 4 + 0] = v.x; T[r][c4 * 4 + 1] = v.y;
        T[r][c4 * 4 + 2] = v.z; T[r][c4 * 4 + 3] = v.w;
    }
    __syncthreads();
#pragma unroll
    for (int i = 0; i < 4; ++i) {
        int c = tid + 256 * i; int r = c >> 4, c4 = c & 15;   // r = n_local, c4 = k group
        float x0 = T[c4 * 4 + 0][r], x1 = T[c4 * 4 + 1][r];
        float x2 = T[c4 * 4 + 2][r], x3 = T[c4 * 4 + 3][r];
        unsigned short h0 = f2bf(x0), h1 = f2bf(x1), h2 = f2bf(x2), h3 = f2bf(x3);
        unsigned short l0 = f2bf(x0 - bf2f(h0)), l1 = f2bf(x1 - bf2f(h1));
        unsigned short l2 = f2bf(x2 - bf2f(h2)), l3 = f2bf(x3 - bf2f(h3));
        size_t o = (size_t)w * 1048576 + (size_t)(n0 + r) * 1024 + k0 + c4 * 4;
        *(s4v*)&wt_hi[o] = (s4v){(short)h0, (short)h1, (short)h2, (short)h3};
        *(s4v*)&wt_lo[o] = (s4v){(short)l0, (short)l1, (short)l2, (short)l3};
    }
}

// ---------------------------------------------------------------------------
// Pack attn_mask int32 -> bitmask u64 words. One thread per word (64 ints).
// ---------------------------------------------------------------------------
__global__ __launch_bounds__(256)
void maskbits_kernel(const int* __restrict__ mask, unsigned long long* __restrict__ mb)
{
    const int w = blockIdx.x * 256 + threadIdx.x;   // 65536 words
    const int* p = mask + (size_t)w * 64;
    unsigned long long bits = 0;
#pragma unroll
    for (int i = 0; i < 16; ++i) {
        int4 v = *(const int4*)(p + i * 4);
        bits |= (unsigned long long)(v.x != 0) << (i * 4 + 0);
        bits |= (unsigned long long)(v.y != 0) << (i * 4 + 1);
        bits |= (unsigned long long)(v.z != 0) << (i * 4 + 2);
        bits |= (unsigned long long)(v.w != 0) << (i * 4 + 3);
    }
    mb[w] = bits;
}

// ---------------------------------------------------------------------------
// Split-bf16 MFMA GEMM body (projections / out-proj).
// ---------------------------------------------------------------------------
template<int ASRC, int EPI>
__device__ __forceinline__ void gemm_body(
    const float* __restrict__ Af,
    const unsigned short* __restrict__ Ah_g, const unsigned short* __restrict__ Al_g,
    const unsigned short* __restrict__ Bh_g, const unsigned short* __restrict__ Bl_g,
    const float* __restrict__ bias,
    float* __restrict__ Yf, unsigned short* __restrict__ Yh, unsigned short* __restrict__ Yl,
    unsigned short* As_h, unsigned short* As_l, unsigned short* Bs_h, unsigned short* Bs_l,
    int m0, int n0)
{
    const int tid = threadIdx.x, lane = tid & 63, wid = tid >> 6;
    const int wm = (wid >> 1) * 64, wn = (wid & 1) * 64;
    f32x4 zero4 = {0.f, 0.f, 0.f, 0.f};
    f32x4 acc[4][4];
#pragma unroll
    for (int a = 0; a < 4; ++a)
#pragma unroll
        for (int b = 0; b < 4; ++b) acc[a][b] = zero4;

    for (int kt = 0; kt < 1024; kt += 64) {
        __syncthreads();
        if (ASRC == 0) {
#pragma unroll
            for (int i = 0; i < 8; ++i) {
                int c = tid + 256 * i; int r = c >> 4, c4 = c & 15;
                f32x4 v = *(const f32x4*)(Af + (size_t)(m0 + r) * 1024 + kt + c4 * 4);
                unsigned short h0 = f2bf(v.x), h1 = f2bf(v.y), h2 = f2bf(v.z), h3 = f2bf(v.w);
                unsigned short l0 = f2bf(v.x - bf2f(h0)), l1 = f2bf(v.y - bf2f(h1));
                unsigned short l2 = f2bf(v.z - bf2f(h2)), l3 = f2bf(v.w - bf2f(h3));
                int off = r * 64 + (((c4 >> 1) ^ (r & 7)) * 8) + (c4 & 1) * 4;
                *(s4v*)&As_h[off] = (s4v){(short)h0, (short)h1, (short)h2, (short)h3};
                *(s4v*)&As_l[off] = (s4v){(short)l0, (short)l1, (short)l2, (short)l3};
            }
        } else {
#pragma unroll
            for (int i = 0; i < 4; ++i) {
                int c = tid + 256 * i; int r = c >> 3, cc = c & 7;
                int off = r * 64 + ((cc ^ (r & 7)) * 8);
                *(bf8*)&As_h[off] = *(const bf8*)(Ah_g + (size_t)(m0 + r) * 1024 + kt + cc * 8);
                *(bf8*)&As_l[off] = *(const bf8*)(Al_g + (size_t)(m0 + r) * 1024 + kt + cc * 8);
            }
        }
#pragma unroll
        for (int i = 0; i < 4; ++i) {
            int c = tid + 256 * i; int r = c >> 3, cc = c & 7;
            int off = r * 64 + ((cc ^ (r & 7)) * 8);
            *(bf8*)&Bs_h[off] = *(const bf8*)(Bh_g + (size_t)(n0 + r) * 1024 + kt + cc * 8);
            *(bf8*)&Bs_l[off] = *(const bf8*)(Bl_g + (size_t)(n0 + r) * 1024 + kt + cc * 8);
        }
        __syncthreads();
#pragma unroll
        for (int ks = 0; ks < 2; ++ks) {
            bf8 ah[4], al[4], bh[4], bl[4];
#pragma unroll
            for (int f = 0; f < 4; ++f) {
                int ra = wm + f * 16 + (lane & 15);
                int ca = (ks * 4 + (lane >> 4)) ^ (ra & 7);
                ah[f] = *(const bf8*)&As_h[ra * 64 + ca * 8];
                al[f] = *(const bf8*)&As_l[ra * 64 + ca * 8];
                int rb = wn + f * 16 + (lane & 15);
                int cb = (ks * 4 + (lane >> 4)) ^ (rb & 7);
                bh[f] = *(const bf8*)&Bs_h[rb * 64 + cb * 8];
                bl[f] = *(const bf8*)&Bs_l[rb * 64 + cb * 8];
            }
#pragma unroll
            for (int fi = 0; fi < 4; ++fi)
#pragma unroll
                for (int fj = 0; fj < 4; ++fj) {
                    acc[fi][fj] = MFMA(ah[fi], bh[fj], acc[fi][fj]);
                    acc[fi][fj] = MFMA(al[fi], bh[fj], acc[fi][fj]);
                    acc[fi][fj] = MFMA(ah[fi], bl[fj], acc[fi][fj]);
                }
        }
    }
    // epilogue: C/D layout (m89): col = lane&15, row = (lane>>4)*4 + reg
#pragma unroll
    for (int fi = 0; fi < 4; ++fi)
#pragma unroll
        for (int fj = 0; fj < 4; ++fj)
#pragma unroll
            for (int rg = 0; rg < 4; ++rg) {
                int m = m0 + wm + fi * 16 + ((lane >> 4) << 2) + rg;
                int n = n0 + wn + fj * 16 + (lane & 15);
                float val = acc[fi][fj][rg] + bias[n];
                if (EPI == 0) {
                    int b = m >> 10, s = m & 1023, h = n >> 6, d = n & 63;
                    size_t o = (((size_t)(b * 16 + h)) * 1024 + s) * 64 + d;
                    unsigned short hv = f2bf(val);
                    unsigned short lv = f2bf(val - bf2f(hv));
                    Yh[o] = hv; Yl[o] = lv;
                } else {
                    Yf[(size_t)m * 1024 + n] = val;
                }
            }
}

__global__ __launch_bounds__(256, 2)
void proj_qkv_kernel(const float* __restrict__ q_in, const float* __restrict__ k_in,
                     const float* __restrict__ v_in,
                     const unsigned short* __restrict__ wt_hi, const unsigned short* __restrict__ wt_lo,
                     const float* __restrict__ bq, const float* __restrict__ bk,
                     const float* __restrict__ bv,
                     unsigned short* qh_hi, unsigned short* qh_lo,
                     unsigned short* kh_hi, unsigned short* kh_lo,
                     unsigned short* vh_hi, unsigned short* vh_lo)
{
    __shared__ __align__(16) unsigned short As_h[128 * 64], As_l[128 * 64];
    __shared__ __align__(16) unsigned short Bs_h[128 * 64], Bs_l[128 * 64];
    const int z = blockIdx.z;
    const float* X = z == 0 ? q_in : (z == 1 ? k_in : v_in);
    const float* bias = z == 0 ? bq : (z == 1 ? bk : bv);
    unsigned short* Yh = z == 0 ? qh_hi : (z == 1 ? kh_hi : vh_hi);
    unsigned short* Yl = z == 0 ? qh_lo : (z == 1 ? kh_lo : vh_lo);
    gemm_body<0, 0>(X, nullptr, nullptr,
                    wt_hi + (size_t)z * 1048576, wt_lo + (size_t)z * 1048576,
                    bias, nullptr, Yh, Yl, As_h, As_l, Bs_h, Bs_l,
                    blockIdx.x * 128, blockIdx.y * 128);
}

__global__ __launch_bounds__(256, 2)
void outproj_kernel(const unsigned short* __restrict__ ctx_hi, const unsigned short* __restrict__ ctx_lo,
                    const unsigned short* __restrict__ wo_hi, const unsigned short* __restrict__ wo_lo,
                    const float* __restrict__ bo, float* __restrict__ out)
{
    __shared__ __align__(16) unsigned short As_h[128 * 64], As_l[128 * 64];
    __shared__ __align__(16) unsigned short Bs_h[128 * 64], Bs_l[128 * 64];
    gemm_body<1, 1>(nullptr, ctx_hi, ctx_lo, wo_hi, wo_lo, bo, out, nullptr, nullptr,
                    As_h, As_l, Bs_h, Bs_l, blockIdx.x * 128, blockIdx.y * 128);
}

// ---------------------------------------------------------------------------
// V transpose: vh[bh][s][d] (ushort) -> vt[bh][d][s]. z: 0=hi,1=lo buffers.
// ---------------------------------------------------------------------------
__global__ __launch_bounds__(256, 4)
void vtrans_kernel(const unsigned short* __restrict__ vh_hi, const unsigned short* __restrict__ vh_lo,
                   unsigned short* __restrict__ vt_hi, unsigned short* __restrict__ vt_lo)
{
    __shared__ unsigned short T[64][72];
    const unsigned short* src = blockIdx.z ? vh_lo : vh_hi;
    unsigned short* dst = blockIdx.z ? vt_lo : vt_hi;
    const int st = blockIdx.x * 64, bh = blockIdx.y, tid = threadIdx.x;
#pragma unroll
    for (int i = 0; i < 4; ++i) {
        int c = tid + 256 * i; int r = c >> 4, d4 = c & 15;
        s4v v = *(const s4v*)(src + ((size_t)bh * 1024 + st + r) * 64 + d4 * 4);
        T[r][d4 * 4 + 0] = (unsigned short)v.x; T[r][d4 * 4 + 1] = (unsigned short)v.y;
        T[r][d4 * 4 + 2] = (unsigned short)v.z; T[r][d4 * 4 + 3] = (unsigned short)v.w;
    }
    __syncthreads();
#pragma unroll
    for (int i = 0; i < 4; ++i) {
        int c = tid + 256 * i; int r = c >> 4, s4_ = c & 15;  // r = d row
        s4v o = {(short)T[s4_ * 4 + 0][r], (short)T[s4_ * 4 + 1][r],
                 (short)T[s4_ * 4 + 2][r], (short)T[s4_ * 4 + 3][r]};
        *(s4v*)(dst + ((size_t)bh * 64 + r) * 1024 + st + s4_ * 4) = o;
    }
}

// ---------------------------------------------------------------------------
// Fused attention (r8 config — best measured: attn 349 us / total 482 us).
// Per block 128 i-rows x one head. Grid (x=head, y=i-block): all i-blocks of
// a head on ONE XCD -> K/V L2 reuse. attn stream + ctx stored nontemporal
// (fastest measured; plain stores were slower despite less HBM traffic, r10).
// ---------------------------------------------------------------------------
__global__ __launch_bounds__(256, 2)
void attn_fused_kernel(const unsigned short* __restrict__ qh_hi, const unsigned short* __restrict__ qh_lo,
                       const unsigned short* __restrict__ kh_hi, const unsigned short* __restrict__ kh_lo,
                       const unsigned short* __restrict__ vt_hi, const unsigned short* __restrict__ vt_lo,
                       const float* __restrict__ emb, const unsigned long long* __restrict__ mb,
                       float* __restrict__ attn,
                       unsigned short* __restrict__ ctx_hi, unsigned short* __restrict__ ctx_lo)
{
    __shared__ __align__(16) unsigned short Sh[128 * 64], Sl[128 * 64];  // Q then K tiles
    __shared__ __align__(16) unsigned short Pr[128 * PRELW];
    __shared__ float Sm[2][128], Ss[2][128], SmF[128], SsF[128];
    const int tid = threadIdx.x, lane = tid & 63, wid = tid >> 6;
    const int wi = wid >> 1, wj = wid & 1;
    const int g = lane >> 4, li = lane & 15;
    const int bh = blockIdx.x, i0 = blockIdx.y * 128, b = bh >> 4;
    const f32x4 zero4 = {0.f, 0.f, 0.f, 0.f};

    // ---- stage Q tile (swizzled rows = i) ----
    const unsigned short* qbh = qh_hi + ((size_t)bh * 1024 + i0) * 64;
    const unsigned short* qbl = qh_lo + ((size_t)bh * 1024 + i0) * 64;
#pragma unroll
    for (int i = 0; i < 4; ++i) {
        int c = tid + 256 * i; int r = c >> 3, cc = c & 7;
        int off = r * 64 + ((cc ^ (r & 7)) * 8);
        *(bf8*)&Sh[off] = *(const bf8*)(qbh + r * 64 + cc * 8);
        *(bf8*)&Sl[off] = *(const bf8*)(qbl + r * 64 + cc * 8);
    }
    __syncthreads();

    // ---- Q fragments to registers ----
    bf8 qfh[4][2], qfl[4][2];
#pragma unroll
    for (int fi = 0; fi < 4; ++fi)
#pragma unroll
        for (int ks = 0; ks < 2; ++ks) {
            int rb = wi * 64 + fi * 16 + li;
            int cb = (ks * 4 + g) ^ (rb & 7);
            qfh[fi][ks] = *(const bf8*)&Sh[rb * 64 + cb * 8];
            qfl[fi][ks] = *(const bf8*)&Sl[rb * 64 + cb * 8];
        }

    // ---- rel-bias Pr[i][r] = q_hi[i]. emb[r] via MFMA, stored bf16 ----
    for (int t = wid; t < 72; t += 4) {       // 8 i-tiles x 9 r-tiles
        const int it = t / 9, rt = t % 9;
        f32x4 pc = zero4;
#pragma unroll
        for (int ks = 0; ks < 2; ++ks) {
            int ra = it * 16 + li;
            int ca = (ks * 4 + g) ^ (ra & 7);
            bf8 aq = *(const bf8*)&Sh[ra * 64 + ca * 8];
            int er = rt * 16 + li; if (er > 128) er = 128;   // clamp OOB rows
            const float* ep = emb + (size_t)er * 64 + ks * 32 + g * 8;
            f32x4 e0 = *(const f32x4*)ep;
            f32x4 e1 = *(const f32x4*)(ep + 4);
            bf8 be = {(short)f2bf(e0.x), (short)f2bf(e0.y), (short)f2bf(e0.z), (short)f2bf(e0.w),
                      (short)f2bf(e1.x), (short)f2bf(e1.y), (short)f2bf(e1.z), (short)f2bf(e1.w)};
            pc = MFMA(aq, be, pc);
        }
        const int rcol = rt * 16 + li;
        if (rcol < RR) {
#pragma unroll
            for (int rg = 0; rg < 4; ++rg)
                Pr[(it * 16 + g * 4 + rg) * PRELW + rcol] = f2bf(pc[rg]);
        }
    }

    float rm[4], rs[4];
#pragma unroll
    for (int i = 0; i < 4; ++i) { rm[i] = -3.0e38f; rs[i] = 0.f; }

    // ================= PASS 1: stats only =================
    for (int jt = 0; jt < 8; ++jt) {
        __syncthreads();   // Pr writes done (jt=0); prior frag reads done (jt>0)
        const unsigned short* kbh = kh_hi + ((size_t)bh * 1024 + jt * 128) * 64;
        const unsigned short* kbl = kh_lo + ((size_t)bh * 1024 + jt * 128) * 64;
#pragma unroll
        for (int i = 0; i < 4; ++i) {
            int c = tid + 256 * i; int r = c >> 3, cc = c & 7;
            int off = r * 64 + ((cc ^ (r & 7)) * 8);
            *(bf8*)&Sh[off] = *(const bf8*)(kbh + r * 64 + cc * 8);
            *(bf8*)&Sl[off] = *(const bf8*)(kbl + r * 64 + cc * 8);
        }
        __syncthreads();
        f32x4 acc[4][4];  // [fj][fi]
#pragma unroll
        for (int a = 0; a < 4; ++a)
#pragma unroll
            for (int c = 0; c < 4; ++c) acc[a][c] = zero4;
#pragma unroll
        for (int ks = 0; ks < 2; ++ks) {
            bf8 kfh[4], kfl[4];
#pragma unroll
            for (int fj = 0; fj < 4; ++fj) {
                int ra = wj * 64 + fj * 16 + li;
                int ca = (ks * 4 + g) ^ (ra & 7);
                kfh[fj] = *(const bf8*)&Sh[ra * 64 + ca * 8];
                kfl[fj] = *(const bf8*)&Sl[ra * 64 + ca * 8];
            }
#pragma unroll
            for (int fj = 0; fj < 4; ++fj)
#pragma unroll
                for (int fi = 0; fi < 4; ++fi) {
                    acc[fj][fi] = MFMA(kfh[fj], qfh[fi][ks], acc[fj][fi]);
                    acc[fj][fi] = MFMA(kfl[fj], qfh[fi][ks], acc[fj][fi]);
                    acc[fj][fi] = MFMA(kfh[fj], qfl[fi][ks], acc[fj][fi]);
                }
        }
#pragma unroll
        for (int fi = 0; fi < 4; ++fi) {
            const int rowL = wi * 64 + fi * 16 + li;
            const int ii = i0 + rowL;
            const unsigned long long mw = mb[((size_t)b * 1024 + ii) * 16 + jt * 2 + wj];
            float p16[4][4];
            float tmax = -3.0e38f;
#pragma unroll
            for (int fj = 0; fj < 4; ++fj)
#pragma unroll
                for (int rg = 0; rg < 4; ++rg) {
                    int jloc = fj * 16 + g * 4 + rg;
                    int jj = jt * 128 + wj * 64 + jloc;
                    int dd = ii - jj; dd = dd < -64 ? -64 : (dd > 64 ? 64 : dd);
                    float s = acc[fj][fi][rg] * 0.125f + bf2f(Pr[rowL * PRELW + dd + 64]);
                    if (!((mw >> jloc) & 1ull)) s = -1.0e30f;
                    p16[fj][rg] = s;
                    tmax = fmaxf(tmax, s);
                }
            tmax = fmaxf(tmax, __shfl_xor(tmax, 16, 64));
            tmax = fmaxf(tmax, __shfl_xor(tmax, 32, 64));
            float nm = fmaxf(rm[fi], tmax);
            float ps = 0.f;
#pragma unroll
            for (int fj = 0; fj < 4; ++fj)
#pragma unroll
                for (int rg = 0; rg < 4; ++rg) ps += __expf(p16[fj][rg] - nm);
            ps += __shfl_xor(ps, 16, 64);
            ps += __shfl_xor(ps, 32, 64);
            rs[fi] = rs[fi] * __expf(rm[fi] - nm) + ps;
            rm[fi] = nm;
        }
    }
    // combine the two j-half waves per i-row
#pragma unroll
    for (int fi = 0; fi < 4; ++fi) {
        if (lane < 16) {
            Sm[wj][wi * 64 + fi * 16 + li] = rm[fi];
            Ss[wj][wi * 64 + fi * 16 + li] = rs[fi];
        }
    }
    __syncthreads();
    if (tid < 128) {
        float m0_ = Sm[0][tid], m1_ = Sm[1][tid];
        float mmx = fmaxf(m0_, m1_);
        SmF[tid] = mmx;
        SsF[tid] = Ss[0][tid] * __expf(m0_ - mmx) + Ss[1][tid] * __expf(m1_ - mmx);
    }
    __syncthreads();
    float mm4[4], iv4[4];
#pragma unroll
    for (int fi = 0; fi < 4; ++fi) {
        mm4[fi] = SmF[wi * 64 + fi * 16 + li];
        iv4[fi] = 1.f / SsF[wi * 64 + fi * 16 + li];
    }

    f32x4 ctx_acc[4][4];  // [fi][fd]
#pragma unroll
    for (int a = 0; a < 4; ++a)
#pragma unroll
        for (int c = 0; c < 4; ++c) ctx_acc[a][c] = zero4;

    // ================= PASS 2: weights write + PV =================
    for (int jt = 0; jt < 8; ++jt) {
        __syncthreads();
        const unsigned short* kbh = kh_hi + ((size_t)bh * 1024 + jt * 128) * 64;
        const unsigned short* kbl = kh_lo + ((size_t)bh * 1024 + jt * 128) * 64;
#pragma unroll
        for (int i = 0; i < 4; ++i) {
            int c = tid + 256 * i; int r = c >> 3, cc = c & 7;
            int off = r * 64 + ((cc ^ (r & 7)) * 8);
            *(bf8*)&Sh[off] = *(const bf8*)(kbh + r * 64 + cc * 8);
            *(bf8*)&Sl[off] = *(const bf8*)(kbl + r * 64 + cc * 8);
        }
        __syncthreads();
        f32x4 acc[4][4];  // identical recompute -> identical s values
#pragma unroll
        for (int a = 0; a < 4; ++a)
#pragma unroll
            for (int c = 0; c < 4; ++c) acc[a][c] = zero4;
#pragma unroll
        for (int ks = 0; ks < 2; ++ks) {
            bf8 kfh[4], kfl[4];
#pragma unroll
            for (int fj = 0; fj < 4; ++fj) {
                int ra = wj * 64 + fj * 16 + li;
                int ca = (ks * 4 + g) ^ (ra & 7);
                kfh[fj] = *(const bf8*)&Sh[ra * 64 + ca * 8];
                kfl[fj] = *(const bf8*)&Sl[ra * 64 + ca * 8];
            }
#pragma unroll
            for (int fj = 0; fj < 4; ++fj)
#pragma unroll
                for (int fi = 0; fi < 4; ++fi) {
                    acc[fj][fi] = MFMA(kfh[fj], qfh[fi][ks], acc[fj][fi]);
                    acc[fj][fi] = MFMA(kfl[fj], qfh[fi][ks], acc[fj][fi]);
                    acc[fj][fi] = MFMA(kfh[fj], qfl[fi][ks], acc[fj][fi]);
                }
        }
        // per 32-j chunk: V frags from global vt, p+store+pack, shfl, PV MFMA
#pragma unroll
        for (int c = 0; c < 2; ++c) {
            bf8 vfh[4], vfl[4];
#pragma unroll
            for (int fd = 0; fd < 4; ++fd) {
                size_t vb = (size_t)bh * 65536 + (size_t)(fd * 16 + li) * 1024
                          + jt * 128 + wj * 64 + c * 32 + g * 8;
                vfh[fd] = *(const bf8*)(vt_hi + vb);
                vfl[fd] = *(const bf8*)(vt_lo + vb);
            }
#pragma unroll
            for (int fi = 0; fi < 4; ++fi) {
                const int rowL = wi * 64 + fi * 16 + li;
                const int ii = i0 + rowL;
                const unsigned long long mw = mb[((size_t)b * 1024 + ii) * 16 + jt * 2 + wj];
                const float mmf = mm4[fi], ivf = iv4[fi];
                float* arow = attn + ((size_t)bh * 1024 + ii) * 1024 + jt * 128 + wj * 64 + g * 4;
                unsigned wh[2][2], wl[2][2];
#pragma unroll
                for (int t = 0; t < 2; ++t) {
                    const int fj = c * 2 + t;
                    f32x4 pv;
#pragma unroll
                    for (int rg = 0; rg < 4; ++rg) {
                        int jloc = fj * 16 + g * 4 + rg;
                        int jj = jt * 128 + wj * 64 + jloc;
                        int dd = ii - jj; dd = dd < -64 ? -64 : (dd > 64 ? 64 : dd);
                        float s = acc[fj][fi][rg] * 0.125f + bf2f(Pr[rowL * PRELW + dd + 64]);
                        if (!((mw >> jloc) & 1ull)) s = -1.0e30f;
                        pv[rg] = __expf(s - mmf) * ivf;
                    }
                    __builtin_nontemporal_store(pv, (f32x4*)(arow + fj * 16));  // final weights
                    unsigned short h0 = f2bf(pv.x), h1 = f2bf(pv.y), h2 = f2bf(pv.z), h3 = f2bf(pv.w);
                    wh[t][0] = (unsigned)h0 | ((unsigned)h1 << 16);
                    wh[t][1] = (unsigned)h2 | ((unsigned)h3 << 16);
                    unsigned short l0 = f2bf(pv.x - bf2f(h0)), l1 = f2bf(pv.y - bf2f(h1));
                    unsigned short l2 = f2bf(pv.z - bf2f(h2)), l3 = f2bf(pv.w - bf2f(h3));
                    wl[t][0] = (unsigned)l0 | ((unsigned)l1 << 16);
                    wl[t][1] = (unsigned)l2 | ((unsigned)l3 << 16);
                }
                // redistribute: dest lane g needs tile (g>>1), source groups (g&1)*2, +1
                const int src0 = ((g & 1) * 2) * 16 + li;
                const int src1 = src0 + 16;
                const bool hiT = (g >> 1) & 1;
                int x0A = __shfl((int)wh[0][0], src0, 64), x0B = __shfl((int)wh[1][0], src0, 64);
                int x1A = __shfl((int)wh[0][1], src0, 64), x1B = __shfl((int)wh[1][1], src0, 64);
                int x2A = __shfl((int)wh[0][0], src1, 64), x2B = __shfl((int)wh[1][0], src1, 64);
                int x3A = __shfl((int)wh[0][1], src1, 64), x3B = __shfl((int)wh[1][1], src1, 64);
                i32x4 awh = {hiT ? x0B : x0A, hiT ? x1B : x1A, hiT ? x2B : x2A, hiT ? x3B : x3A};
                bf8 pah = *(bf8*)&awh;
                int y0A = __shfl((int)wl[0][0], src0, 64), y0B = __shfl((int)wl[1][0], src0, 64);
                int y1A = __shfl((int)wl[0][1], src0, 64), y1B = __shfl((int)wl[1][1], src0, 64);
                int y2A = __shfl((int)wl[0][0], src1, 64), y2B = __shfl((int)wl[1][0], src1, 64);
                int y3A = __shfl((int)wl[0][1], src1, 64), y3B = __shfl((int)wl[1][1], src1, 64);
                i32x4 awl = {hiT ? y0B : y0A, hiT ? y1B : y1A, hiT ? y2B : y2A, hiT ? y3B : y3A};
                bf8 pal = *(bf8*)&awl;
#pragma unroll
                for (int fd = 0; fd < 4; ++fd) {
                    ctx_acc[fi][fd] = MFMA(pah, vfh[fd], ctx_acc[fi][fd]);
                    ctx_acc[fi][fd] = MFMA(pal, vfh[fd], ctx_acc[fi][fd]);
                    ctx_acc[fi][fd] = MFMA(pah, vfl[fd], ctx_acc[fi][fd]);
                }
            }
        }
    }

    // ---- reduce ctx_acc across the wj wave pair (Sh/Sl reused as scratch) ----
    __syncthreads();                         // all waves done reading Sh/Sl
    float* red = (wi == 0) ? (float*)Sh : (float*)Sl;   // 4096 floats each
    if (wj == 1) {
#pragma unroll
        for (int fi = 0; fi < 4; ++fi)
#pragma unroll
            for (int fd = 0; fd < 4; ++fd)
#pragma unroll
                for (int rg = 0; rg < 4; ++rg) {
                    int idx = (fi * 4 + fd) * 4 + rg;
                    red[lane * 64 + ((idx + lane) & 63)] = ctx_acc[fi][fd][rg];
                }
    }
    __syncthreads();
    if (wj == 0) {
        const int b_ = bh >> 4, h = bh & 15;
#pragma unroll
        for (int fi = 0; fi < 4; ++fi)
#pragma unroll
            for (int fd = 0; fd < 4; ++fd)
#pragma unroll
                for (int rg = 0; rg < 4; ++rg) {
                    int idx = (fi * 4 + fd) * 4 + rg;
                    float val = ctx_acc[fi][fd][rg] + red[lane * 64 + ((idx + lane) & 63)];
                    int ii = i0 + wi * 64 + fi * 16 + g * 4 + rg;
                    int d = fd * 16 + li;
                    size_t o = ((size_t)b_ * 1024 + ii) * 1024 + h * 64 + d;
                    unsigned short hv = f2bf(val);
                    unsigned short lv = f2bf(val - bf2f(hv));
                    __builtin_nontemporal_store(hv, &ctx_hi[o]);
                    __builtin_nontemporal_store(lv, &ctx_lo[o]);
                }
    }
}

extern "C" void kernel_launch(void* const* d_in, const int* in_sizes, int n_in,
                              void* d_out, int out_size, void* d_ws, size_t ws_size,
                              hipStream_t stream)
{
    const float* query = (const float*)d_in[0];
    const float* key_  = (const float*)d_in[1];
    const float* value = (const float*)d_in[2];
    const int*   mask  = (const int*)d_in[3];
    const float* Wq = (const float*)d_in[4];
    const float* bq = (const float*)d_in[5];
    const float* Wk = (const float*)d_in[6];
    const float* bk = (const float*)d_in[7];
    const float* Wv = (const float*)d_in[8];
    const float* bv = (const float*)d_in[9];
    const float* Wo = (const float*)d_in[10];
    const float* bo = (const float*)d_in[11];
    const float* emb = (const float*)d_in[12];

    // workspace: 80.0 MB (<= 84.1 MB proven in earlier rounds)
    unsigned short* wt_hi = (unsigned short*)d_ws;           // [4][1024][1024]
    unsigned short* wt_lo = wt_hi + (size_t)4 * 1048576;
    unsigned short* qh_hi = wt_lo + (size_t)4 * 1048576;     // [64][1024][64]
    unsigned short* qh_lo = qh_hi + 4194304;
    unsigned short* kh_hi = qh_lo + 4194304;
    unsigned short* kh_lo = kh_hi + 4194304;
    unsigned short* vt_hi = kh_lo + 4194304;                 // [64][64][1024]
    unsigned short* vt_lo = vt_hi + 4194304;
    unsigned short* ctx_hi = vt_lo + 4194304;                // [4][1024][1024]
    unsigned short* ctx_lo = ctx_hi + 4194304;
    // bitmask overlays the (dead-after-projection) Wq^T-hi region:
    unsigned long long* mb = (unsigned long long*)d_ws;      // [65536] = 512 KB
    // v-heads scratch lives in the out region (dead after vtrans; out written last):
    unsigned short* vh_hi = (unsigned short*)d_out;          // 16 MB region
    unsigned short* vh_lo = vh_hi + 4194304;

    float* out  = (float*)d_out;
    float* attn = (float*)d_out + 4194304;

    dim3 blk(256);
    wtrans_kernel<<<dim3(16, 16, 4), blk, 0, stream>>>(Wq, Wk, Wv, Wo, wt_hi, wt_lo);
    proj_qkv_kernel<<<dim3(32, 8, 3), blk, 0, stream>>>(query, key_, value, wt_hi, wt_lo,
                                                        bq, bk, bv, qh_hi, qh_lo,
                                                        kh_hi, kh_lo, vh_hi, vh_lo);
    maskbits_kernel<<<dim3(256), blk, 0, stream>>>(mask, mb);   // after proj (mb overlays Wq^T)
    vtrans_kernel<<<dim3(16, 64, 2), blk, 0, stream>>>(vh_hi, vh_lo, vt_hi, vt_lo);
    attn_fused_kernel<<<dim3(64, 8), blk, 0, stream>>>(qh_hi, qh_lo, kh_hi, kh_lo,
                                                       vt_hi, vt_lo, emb, mb,
                                                       attn, ctx_hi, ctx_lo);
    outproj_kernel<<<dim3(32, 8), blk, 0, stream>>>(ctx_hi, ctx_lo,
                                                    wt_hi + (size_t)3 * 1048576,
                                                    wt_lo + (size_t)3 * 1048576, bo, out);
}

// Round 16
// 466.163 us; speedup vs baseline: 1.3712x; 1.0353x over previous
//
#include <hip/hip_runtime.h>
#include <math.h>

#define BB 4
#define SS 1024
#define EE 1024
#define HH 16
#define DD 64
#define RR 129
#define PRELW 130   // Pr LDS row stride (ushorts)

typedef __attribute__((ext_vector_type(4))) float f32x4;
typedef __attribute__((ext_vector_type(4))) int   i32x4;
typedef __attribute__((ext_vector_type(8))) short bf8;   // 8 bf16 = 4 VGPR (MFMA A/B frag)
typedef __attribute__((ext_vector_type(4))) short s4v;   // 4 bf16 = 8B

#define MFMA(a, b, c) __builtin_amdgcn_mfma_f32_16x16x32_bf16(a, b, c, 0, 0, 0)

__device__ __forceinline__ float bf2f(unsigned short u) {
    return __uint_as_float(((unsigned)u) << 16);
}
__device__ __forceinline__ unsigned short f2bf(float x) {  // RNE
    unsigned u = __float_as_uint(x);
    return (unsigned short)((u + 0x7fffu + ((u >> 16) & 1u)) >> 16);
}

// async global->LDS, 16B per lane; LDS dest = wave-uniform base + lane*16
__device__ __forceinline__ void glds16(const unsigned short* g, unsigned short* l) {
    __builtin_amdgcn_global_load_lds(
        (const __attribute__((address_space(1))) void*)g,
        (__attribute__((address_space(3))) void*)l,
        16, 0, 0);
}

// ---------------------------------------------------------------------------
// Weight transpose+split: W[K][N] fp32 -> Wt_hi/lo[N][K] bf16.
// ---------------------------------------------------------------------------
__global__ __launch_bounds__(256, 4)
void wtrans_kernel(const float* __restrict__ Wq, const float* __restrict__ Wk,
                   const float* __restrict__ Wv, const float* __restrict__ Wo,
                   unsigned short* __restrict__ wt_hi, unsigned short* __restrict__ wt_lo)
{
    __shared__ float T[64][65];
    const int w = blockIdx.z;
    const float* W = w == 0 ? Wq : (w == 1 ? Wk : (w == 2 ? Wv : Wo));
    const int n0 = blockIdx.x * 64, k0 = blockIdx.y * 64;
    const int tid = threadIdx.x;
#pragma unroll
    for (int i = 0; i < 4; ++i) {
        int c = tid + 256 * i; int r = c >> 4, c4 = c & 15;
        f32x4 v = *(const f32x4*)(W + (size_t)(k0 + r) * EE + n0 + c4 * 4);
        T[r][c4 * 4 + 0] = v.x; T[r][c4 * 4 + 1] = v.y;
        T[r][c4 * 4 + 2] = v.z; T[r][c4 * 4 + 3] = v.w;
    }
    __syncthreads();
#pragma unroll
    for (int i = 0; i < 4; ++i) {
        int c = tid + 256 * i; int r = c >> 4, c4 = c & 15;   // r = n_local, c4 = k group
        float x0 = T[c4 * 4 + 0][r], x1 = T[c4 * 4 + 1][r];
        float x2 = T[c4 * 4 + 2][r], x3 = T[c4 * 4 + 3][r];
        unsigned short h0 = f2bf(x0), h1 = f2bf(x1), h2 = f2bf(x2), h3 = f2bf(x3);
        unsigned short l0 = f2bf(x0 - bf2f(h0)), l1 = f2bf(x1 - bf2f(h1));
        unsigned short l2 = f2bf(x2 - bf2f(h2)), l3 = f2bf(x3 - bf2f(h3));
        size_t o = (size_t)w * 1048576 + (size_t)(n0 + r) * 1024 + k0 + c4 * 4;
        *(s4v*)&wt_hi[o] = (s4v){(short)h0, (short)h1, (short)h2, (short)h3};
        *(s4v*)&wt_lo[o] = (s4v){(short)l0, (short)l1, (short)l2, (short)l3};
    }
}

// ---------------------------------------------------------------------------
// Pack attn_mask int32 -> bitmask u64 words. One thread per word (64 ints).
// ---------------------------------------------------------------------------
__global__ __launch_bounds__(256)
void maskbits_kernel(const int* __restrict__ mask, unsigned long long* __restrict__ mb)
{
    const int w = blockIdx.x * 256 + threadIdx.x;   // 65536 words
    const int* p = mask + (size_t)w * 64;
    unsigned long long bits = 0;
#pragma unroll
    for (int i = 0; i < 16; ++i) {
        int4 v = *(const int4*)(p + i * 4);
        bits |= (unsigned long long)(v.x != 0) << (i * 4 + 0);
        bits |= (unsigned long long)(v.y != 0) << (i * 4 + 1);
        bits |= (unsigned long long)(v.z != 0) << (i * 4 + 2);
        bits |= (unsigned long long)(v.w != 0) << (i * 4 + 3);
    }
    mb[w] = bits;
}

// ---------------------------------------------------------------------------
// Split-bf16 MFMA GEMM body (projections / out-proj).
// vt_out=1 (with EPI==0): write Y in transposed-heads layout [bh][d][s]
// (replaces the separate vtrans kernel; epilogue is a 2B scatter either way).
// ---------------------------------------------------------------------------
template<int ASRC, int EPI>
__device__ __forceinline__ void gemm_body(
    const float* __restrict__ Af,
    const unsigned short* __restrict__ Ah_g, const unsigned short* __restrict__ Al_g,
    const unsigned short* __restrict__ Bh_g, const unsigned short* __restrict__ Bl_g,
    const float* __restrict__ bias,
    float* __restrict__ Yf, unsigned short* __restrict__ Yh, unsigned short* __restrict__ Yl,
    unsigned short* As_h, unsigned short* As_l, unsigned short* Bs_h, unsigned short* Bs_l,
    int m0, int n0, int vt_out)
{
    const int tid = threadIdx.x, lane = tid & 63, wid = tid >> 6;
    const int wm = (wid >> 1) * 64, wn = (wid & 1) * 64;
    f32x4 zero4 = {0.f, 0.f, 0.f, 0.f};
    f32x4 acc[4][4];
#pragma unroll
    for (int a = 0; a < 4; ++a)
#pragma unroll
        for (int b = 0; b < 4; ++b) acc[a][b] = zero4;

    for (int kt = 0; kt < 1024; kt += 64) {
        __syncthreads();
        if (ASRC == 0) {
#pragma unroll
            for (int i = 0; i < 8; ++i) {
                int c = tid + 256 * i; int r = c >> 4, c4 = c & 15;
                f32x4 v = *(const f32x4*)(Af + (size_t)(m0 + r) * 1024 + kt + c4 * 4);
                unsigned short h0 = f2bf(v.x), h1 = f2bf(v.y), h2 = f2bf(v.z), h3 = f2bf(v.w);
                unsigned short l0 = f2bf(v.x - bf2f(h0)), l1 = f2bf(v.y - bf2f(h1));
                unsigned short l2 = f2bf(v.z - bf2f(h2)), l3 = f2bf(v.w - bf2f(h3));
                int off = r * 64 + (((c4 >> 1) ^ (r & 7)) * 8) + (c4 & 1) * 4;
                *(s4v*)&As_h[off] = (s4v){(short)h0, (short)h1, (short)h2, (short)h3};
                *(s4v*)&As_l[off] = (s4v){(short)l0, (short)l1, (short)l2, (short)l3};
            }
        } else {
#pragma unroll
            for (int i = 0; i < 4; ++i) {
                int c = tid + 256 * i; int r = c >> 3, cc = c & 7;
                int off = r * 64 + ((cc ^ (r & 7)) * 8);
                *(bf8*)&As_h[off] = *(const bf8*)(Ah_g + (size_t)(m0 + r) * 1024 + kt + cc * 8);
                *(bf8*)&As_l[off] = *(const bf8*)(Al_g + (size_t)(m0 + r) * 1024 + kt + cc * 8);
            }
        }
#pragma unroll
        for (int i = 0; i < 4; ++i) {
            int c = tid + 256 * i; int r = c >> 3, cc = c & 7;
            int off = r * 64 + ((cc ^ (r & 7)) * 8);
            *(bf8*)&Bs_h[off] = *(const bf8*)(Bh_g + (size_t)(n0 + r) * 1024 + kt + cc * 8);
            *(bf8*)&Bs_l[off] = *(const bf8*)(Bl_g + (size_t)(n0 + r) * 1024 + kt + cc * 8);
        }
        __syncthreads();
#pragma unroll
        for (int ks = 0; ks < 2; ++ks) {
            bf8 ah[4], al[4], bh[4], bl[4];
#pragma unroll
            for (int f = 0; f < 4; ++f) {
                int ra = wm + f * 16 + (lane & 15);
                int ca = (ks * 4 + (lane >> 4)) ^ (ra & 7);
                ah[f] = *(const bf8*)&As_h[ra * 64 + ca * 8];
                al[f] = *(const bf8*)&As_l[ra * 64 + ca * 8];
                int rb = wn + f * 16 + (lane & 15);
                int cb = (ks * 4 + (lane >> 4)) ^ (rb & 7);
                bh[f] = *(const bf8*)&Bs_h[rb * 64 + cb * 8];
                bl[f] = *(const bf8*)&Bs_l[rb * 64 + cb * 8];
            }
#pragma unroll
            for (int fi = 0; fi < 4; ++fi)
#pragma unroll
                for (int fj = 0; fj < 4; ++fj) {
                    acc[fi][fj] = MFMA(ah[fi], bh[fj], acc[fi][fj]);
                    acc[fi][fj] = MFMA(al[fi], bh[fj], acc[fi][fj]);
                    acc[fi][fj] = MFMA(ah[fi], bl[fj], acc[fi][fj]);
                }
        }
    }
    // epilogue: C/D layout (m89): col = lane&15, row = (lane>>4)*4 + reg
#pragma unroll
    for (int fi = 0; fi < 4; ++fi)
#pragma unroll
        for (int fj = 0; fj < 4; ++fj)
#pragma unroll
            for (int rg = 0; rg < 4; ++rg) {
                int m = m0 + wm + fi * 16 + ((lane >> 4) << 2) + rg;
                int n = n0 + wn + fj * 16 + (lane & 15);
                float val = acc[fi][fj][rg] + bias[n];
                if (EPI == 0) {
                    int b = m >> 10, s = m & 1023, h = n >> 6, d = n & 63;
                    size_t o = vt_out
                        ? (((size_t)(b * 16 + h)) * 64 + d) * 1024 + s
                        : (((size_t)(b * 16 + h)) * 1024 + s) * 64 + d;
                    unsigned short hv = f2bf(val);
                    unsigned short lv = f2bf(val - bf2f(hv));
                    Yh[o] = hv; Yl[o] = lv;
                } else {
                    Yf[(size_t)m * 1024 + n] = val;
                }
            }
}

__global__ __launch_bounds__(256, 2)
void proj_qkv_kernel(const float* __restrict__ q_in, const float* __restrict__ k_in,
                     const float* __restrict__ v_in,
                     const unsigned short* __restrict__ wt_hi, const unsigned short* __restrict__ wt_lo,
                     const float* __restrict__ bq, const float* __restrict__ bk,
                     const float* __restrict__ bv,
                     unsigned short* qh_hi, unsigned short* qh_lo,
                     unsigned short* kh_hi, unsigned short* kh_lo,
                     unsigned short* vt_hi, unsigned short* vt_lo)
{
    __shared__ __align__(16) unsigned short As_h[128 * 64], As_l[128 * 64];
    __shared__ __align__(16) unsigned short Bs_h[128 * 64], Bs_l[128 * 64];
    const int z = blockIdx.z;
    const float* X = z == 0 ? q_in : (z == 1 ? k_in : v_in);
    const float* bias = z == 0 ? bq : (z == 1 ? bk : bv);
    unsigned short* Yh = z == 0 ? qh_hi : (z == 1 ? kh_hi : vt_hi);
    unsigned short* Yl = z == 0 ? qh_lo : (z == 1 ? kh_lo : vt_lo);
    gemm_body<0, 0>(X, nullptr, nullptr,
                    wt_hi + (size_t)z * 1048576, wt_lo + (size_t)z * 1048576,
                    bias, nullptr, Yh, Yl, As_h, As_l, Bs_h, Bs_l,
                    blockIdx.x * 128, blockIdx.y * 128, z == 2 ? 1 : 0);
}

__global__ __launch_bounds__(256, 2)
void outproj_kernel(const unsigned short* __restrict__ ctx_hi, const unsigned short* __restrict__ ctx_lo,
                    const unsigned short* __restrict__ wo_hi, const unsigned short* __restrict__ wo_lo,
                    const float* __restrict__ bo, float* __restrict__ out)
{
    __shared__ __align__(16) unsigned short As_h[128 * 64], As_l[128 * 64];
    __shared__ __align__(16) unsigned short Bs_h[128 * 64], Bs_l[128 * 64];
    gemm_body<1, 1>(nullptr, ctx_hi, ctx_lo, wo_hi, wo_lo, bo, out, nullptr, nullptr,
                    As_h, As_l, Bs_h, Bs_l, blockIdx.x * 128, blockIdx.y * 128, 0);
}

// ---------------------------------------------------------------------------
// Fused attention (r8 structure + glds staging): per block 128 i-rows x one
// head. Grid (x=head, y=i-block): all i-blocks of a head on ONE XCD -> K/V
// L2 reuse. attn stream + ctx stored nontemporal (fastest measured).
// K/Q tiles staged via global_load_lds: LINEAR LDS dest (wave base + lane*16),
// XOR swizzle applied to the GLOBAL source address (rule #21); the LDS image
// is bit-identical to the old reg-staged path, reads unchanged.
//   lane l, iter i: LDS ushort off L=(wid*4+i)*512 + l*8 -> row r=L/64,
//   slot p=l&7; source chunk cc = p ^ (r&7).
// ---------------------------------------------------------------------------
__global__ __launch_bounds__(256, 2)
void attn_fused_kernel(const unsigned short* __restrict__ qh_hi, const unsigned short* __restrict__ qh_lo,
                       const unsigned short* __restrict__ kh_hi, const unsigned short* __restrict__ kh_lo,
                       const unsigned short* __restrict__ vt_hi, const unsigned short* __restrict__ vt_lo,
                       const float* __restrict__ emb, const unsigned long long* __restrict__ mb,
                       float* __restrict__ attn,
                       unsigned short* __restrict__ ctx_hi, unsigned short* __restrict__ ctx_lo)
{
    __shared__ __align__(16) unsigned short Sh[128 * 64], Sl[128 * 64];  // Q then K tiles
    __shared__ __align__(16) unsigned short Pr[128 * PRELW];
    __shared__ float Sm[2][128], Ss[2][128], SmF[128], SsF[128];
    const int tid = threadIdx.x, lane = tid & 63, wid = tid >> 6;
    const int wi = wid >> 1, wj = wid & 1;
    const int g = lane >> 4, li = lane & 15;
    const int bh = blockIdx.x, i0 = blockIdx.y * 128, b = bh >> 4;
    const f32x4 zero4 = {0.f, 0.f, 0.f, 0.f};

    // glds staging coordinates (constant per thread)
    int sr_[4], sc_[4];
#pragma unroll
    for (int i = 0; i < 4; ++i) {
        sr_[i] = (wid * 4 + i) * 8 + (lane >> 3);
        sc_[i] = (lane & 7) ^ (sr_[i] & 7);
    }

    // ---- stage Q tile (glds, linear dest / pre-swizzled source) ----
    const unsigned short* qbh = qh_hi + ((size_t)bh * 1024 + i0) * 64;
    const unsigned short* qbl = qh_lo + ((size_t)bh * 1024 + i0) * 64;
#pragma unroll
    for (int i = 0; i < 4; ++i) {
        glds16(qbh + sr_[i] * 64 + sc_[i] * 8, Sh + (size_t)(wid * 4 + i) * 512);
        glds16(qbl + sr_[i] * 64 + sc_[i] * 8, Sl + (size_t)(wid * 4 + i) * 512);
    }
    __syncthreads();

    // ---- Q fragments to registers ----
    bf8 qfh[4][2], qfl[4][2];
#pragma unroll
    for (int fi = 0; fi < 4; ++fi)
#pragma unroll
        for (int ks = 0; ks < 2; ++ks) {
            int rb = wi * 64 + fi * 16 + li;
            int cb = (ks * 4 + g) ^ (rb & 7);
            qfh[fi][ks] = *(const bf8*)&Sh[rb * 64 + cb * 8];
            qfl[fi][ks] = *(const bf8*)&Sl[rb * 64 + cb * 8];
        }

    // ---- rel-bias Pr[i][r] = q_hi[i]. emb[r] via MFMA, stored bf16 ----
    for (int t = wid; t < 72; t += 4) {       // 8 i-tiles x 9 r-tiles
        const int it = t / 9, rt = t % 9;
        f32x4 pc = zero4;
#pragma unroll
        for (int ks = 0; ks < 2; ++ks) {
            int ra = it * 16 + li;
            int ca = (ks * 4 + g) ^ (ra & 7);
            bf8 aq = *(const bf8*)&Sh[ra * 64 + ca * 8];
            int er = rt * 16 + li; if (er > 128) er = 128;   // clamp OOB rows
            const float* ep = emb + (size_t)er * 64 + ks * 32 + g * 8;
            f32x4 e0 = *(const f32x4*)ep;
            f32x4 e1 = *(const f32x4*)(ep + 4);
            bf8 be = {(short)f2bf(e0.x), (short)f2bf(e0.y), (short)f2bf(e0.z), (short)f2bf(e0.w),
                      (short)f2bf(e1.x), (short)f2bf(e1.y), (short)f2bf(e1.z), (short)f2bf(e1.w)};
            pc = MFMA(aq, be, pc);
        }
        const int rcol = rt * 16 + li;
        if (rcol < RR) {
#pragma unroll
            for (int rg = 0; rg < 4; ++rg)
                Pr[(it * 16 + g * 4 + rg) * PRELW + rcol] = f2bf(pc[rg]);
        }
    }

    float rm[4], rs[4];
#pragma unroll
    for (int i = 0; i < 4; ++i) { rm[i] = -3.0e38f; rs[i] = 0.f; }

    // ================= PASS 1: stats only =================
    for (int jt = 0; jt < 8; ++jt) {
        __syncthreads();   // Pr writes done (jt=0); prior frag reads done (jt>0)
        const unsigned short* kbh = kh_hi + ((size_t)bh * 1024 + jt * 128) * 64;
        const unsigned short* kbl = kh_lo + ((size_t)bh * 1024 + jt * 128) * 64;
#pragma unroll
        for (int i = 0; i < 4; ++i) {
            glds16(kbh + sr_[i] * 64 + sc_[i] * 8, Sh + (size_t)(wid * 4 + i) * 512);
            glds16(kbl + sr_[i] * 64 + sc_[i] * 8, Sl + (size_t)(wid * 4 + i) * 512);
        }
        __syncthreads();
        f32x4 acc[4][4];  // [fj][fi]
#pragma unroll
        for (int a = 0; a < 4; ++a)
#pragma unroll
            for (int c = 0; c < 4; ++c) acc[a][c] = zero4;
#pragma unroll
        for (int ks = 0; ks < 2; ++ks) {
            bf8 kfh[4], kfl[4];
#pragma unroll
            for (int fj = 0; fj < 4; ++fj) {
                int ra = wj * 64 + fj * 16 + li;
                int ca = (ks * 4 + g) ^ (ra & 7);
                kfh[fj] = *(const bf8*)&Sh[ra * 64 + ca * 8];
                kfl[fj] = *(const bf8*)&Sl[ra * 64 + ca * 8];
            }
#pragma unroll
            for (int fj = 0; fj < 4; ++fj)
#pragma unroll
                for (int fi = 0; fi < 4; ++fi) {
                    acc[fj][fi] = MFMA(kfh[fj], qfh[fi][ks], acc[fj][fi]);
                    acc[fj][fi] = MFMA(kfl[fj], qfh[fi][ks], acc[fj][fi]);
                    acc[fj][fi] = MFMA(kfh[fj], qfl[fi][ks], acc[fj][fi]);
                }
        }
#pragma unroll
        for (int fi = 0; fi < 4; ++fi) {
            const int rowL = wi * 64 + fi * 16 + li;
            const int ii = i0 + rowL;
            const unsigned long long mw = mb[((size_t)b * 1024 + ii) * 16 + jt * 2 + wj];
            float p16[4][4];
            float tmax = -3.0e38f;
#pragma unroll
            for (int fj = 0; fj < 4; ++fj)
#pragma unroll
                for (int rg = 0; rg < 4; ++rg) {
                    int jloc = fj * 16 + g * 4 + rg;
                    int jj = jt * 128 + wj * 64 + jloc;
                    int dd = ii - jj; dd = dd < -64 ? -64 : (dd > 64 ? 64 : dd);
                    float s = acc[fj][fi][rg] * 0.125f + bf2f(Pr[rowL * PRELW + dd + 64]);
                    if (!((mw >> jloc) & 1ull)) s = -1.0e30f;
                    p16[fj][rg] = s;
                    tmax = fmaxf(tmax, s);
                }
            tmax = fmaxf(tmax, __shfl_xor(tmax, 16, 64));
            tmax = fmaxf(tmax, __shfl_xor(tmax, 32, 64));
            float nm = fmaxf(rm[fi], tmax);
            float ps = 0.f;
#pragma unroll
            for (int fj = 0; fj < 4; ++fj)
#pragma unroll
                for (int rg = 0; rg < 4; ++rg) ps += __expf(p16[fj][rg] - nm);
            ps += __shfl_xor(ps, 16, 64);
            ps += __shfl_xor(ps, 32, 64);
            rs[fi] = rs[fi] * __expf(rm[fi] - nm) + ps;
            rm[fi] = nm;
        }
    }
    // combine the two j-half waves per i-row
#pragma unroll
    for (int fi = 0; fi < 4; ++fi) {
        if (lane < 16) {
            Sm[wj][wi * 64 + fi * 16 + li] = rm[fi];
            Ss[wj][wi * 64 + fi * 16 + li] = rs[fi];
        }
    }
    __syncthreads();
    if (tid < 128) {
        float m0_ = Sm[0][tid], m1_ = Sm[1][tid];
        float mmx = fmaxf(m0_, m1_);
        SmF[tid] = mmx;
        SsF[tid] = Ss[0][tid] * __expf(m0_ - mmx) + Ss[1][tid] * __expf(m1_ - mmx);
    }
    __syncthreads();
    float mm4[4], iv4[4];
#pragma unroll
    for (int fi = 0; fi < 4; ++fi) {
        mm4[fi] = SmF[wi * 64 + fi * 16 + li];
        iv4[fi] = 1.f / SsF[wi * 64 + fi * 16 + li];
    }

    f32x4 ctx_acc[4][4];  // [fi][fd]
#pragma unroll
    for (int a = 0; a < 4; ++a)
#pragma unroll
        for (int c = 0; c < 4; ++c) ctx_acc[a][c] = zero4;

    // ================= PASS 2: weights write + PV =================
    for (int jt = 0; jt < 8; ++jt) {
        __syncthreads();
        const unsigned short* kbh = kh_hi + ((size_t)bh * 1024 + jt * 128) * 64;
        const unsigned short* kbl = kh_lo + ((size_t)bh * 1024 + jt * 128) * 64;
#pragma unroll
        for (int i = 0; i < 4; ++i) {
            glds16(kbh + sr_[i] * 64 + sc_[i] * 8, Sh + (size_t)(wid * 4 + i) * 512);
            glds16(kbl + sr_[i] * 64 + sc_[i] * 8, Sl + (size_t)(wid * 4 + i) * 512);
        }
        __syncthreads();
        f32x4 acc[4][4];  // identical recompute -> identical s values
#pragma unroll
        for (int a = 0; a < 4; ++a)
#pragma unroll
            for (int c = 0; c < 4; ++c) acc[a][c] = zero4;
#pragma unroll
        for (int ks = 0; ks < 2; ++ks) {
            bf8 kfh[4], kfl[4];
#pragma unroll
            for (int fj = 0; fj < 4; ++fj) {
                int ra = wj * 64 + fj * 16 + li;
                int ca = (ks * 4 + g) ^ (ra & 7);
                kfh[fj] = *(const bf8*)&Sh[ra * 64 + ca * 8];
                kfl[fj] = *(const bf8*)&Sl[ra * 64 + ca * 8];
            }
#pragma unroll
            for (int fj = 0; fj < 4; ++fj)
#pragma unroll
                for (int fi = 0; fi < 4; ++fi) {
                    acc[fj][fi] = MFMA(kfh[fj], qfh[fi][ks], acc[fj][fi]);
                    acc[fj][fi] = MFMA(kfl[fj], qfh[fi][ks], acc[fj][fi]);
                    acc[fj][fi] = MFMA(kfh[fj], qfl[fi][ks], acc[fj][fi]);
                }
        }
        // per 32-j chunk: V frags from global vt, p+store+pack, shfl, PV MFMA
#pragma unroll
        for (int c = 0; c < 2; ++c) {
            bf8 vfh[4], vfl[4];
#pragma unroll
            for (int fd = 0; fd < 4; ++fd) {
                size_t vb = (size_t)bh * 65536 + (size_t)(fd * 16 + li) * 1024
                          + jt * 128 + wj * 64 + c * 32 + g * 8;
                vfh[fd] = *(const bf8*)(vt_hi + vb);
                vfl[fd] = *(const bf8*)(vt_lo + vb);
            }
#pragma unroll
            for (int fi = 0; fi < 4; ++fi) {
                const int rowL = wi * 64 + fi * 16 + li;
                const int ii = i0 + rowL;
                const unsigned long long mw = mb[((size_t)b * 1024 + ii) * 16 + jt * 2 + wj];
                const float mmf = mm4[fi], ivf = iv4[fi];
                float* arow = attn + ((size_t)bh * 1024 + ii) * 1024 + jt * 128 + wj * 64 + g * 4;
                unsigned wh[2][2], wl[2][2];
#pragma unroll
                for (int t = 0; t < 2; ++t) {
                    const int fj = c * 2 + t;
                    f32x4 pv;
#pragma unroll
                    for (int rg = 0; rg < 4; ++rg) {
                        int jloc = fj * 16 + g * 4 + rg;
                        int jj = jt * 128 + wj * 64 + jloc;
                        int dd = ii - jj; dd = dd < -64 ? -64 : (dd > 64 ? 64 : dd);
                        float s = acc[fj][fi][rg] * 0.125f + bf2f(Pr[rowL * PRELW + dd + 64]);
                        if (!((mw >> jloc) & 1ull)) s = -1.0e30f;
                        pv[rg] = __expf(s - mmf) * ivf;
                    }
                    __builtin_nontemporal_store(pv, (f32x4*)(arow + fj * 16));  // final weights
                    unsigned short h0 = f2bf(pv.x), h1 = f2bf(pv.y), h2 = f2bf(pv.z), h3 = f2bf(pv.w);
                    wh[t][0] = (unsigned)h0 | ((unsigned)h1 << 16);
                    wh[t][1] = (unsigned)h2 | ((unsigned)h3 << 16);
                    unsigned short l0 = f2bf(pv.x - bf2f(h0)), l1 = f2bf(pv.y - bf2f(h1));
                    unsigned short l2 = f2bf(pv.z - bf2f(h2)), l3 = f2bf(pv.w - bf2f(h3));
                    wl[t][0] = (unsigned)l0 | ((unsigned)l1 << 16);
                    wl[t][1] = (unsigned)l2 | ((unsigned)l3 << 16);
                }
                // redistribute: dest lane g needs tile (g>>1), source groups (g&1)*2, +1
                const int src0 = ((g & 1) * 2) * 16 + li;
                const int src1 = src0 + 16;
                const bool hiT = (g >> 1) & 1;
                int x0A = __shfl((int)wh[0][0], src0, 64), x0B = __shfl((int)wh[1][0], src0, 64);
                int x1A = __shfl((int)wh[0][1], src0, 64), x1B = __shfl((int)wh[1][1], src0, 64);
                int x2A = __shfl((int)wh[0][0], src1, 64), x2B = __shfl((int)wh[1][0], src1, 64);
                int x3A = __shfl((int)wh[0][1], src1, 64), x3B = __shfl((int)wh[1][1], src1, 64);
                i32x4 awh = {hiT ? x0B : x0A, hiT ? x1B : x1A, hiT ? x2B : x2A, hiT ? x3B : x3A};
                bf8 pah = *(bf8*)&awh;
                int y0A = __shfl((int)wl[0][0], src0, 64), y0B = __shfl((int)wl[1][0], src0, 64);
                int y1A = __shfl((int)wl[0][1], src0, 64), y1B = __shfl((int)wl[1][1], src0, 64);
                int y2A = __shfl((int)wl[0][0], src1, 64), y2B = __shfl((int)wl[1][0], src1, 64);
                int y3A = __shfl((int)wl[0][1], src1, 64), y3B = __shfl((int)wl[1][1], src1, 64);
                i32x4 awl = {hiT ? y0B : y0A, hiT ? y1B : y1A, hiT ? y2B : y2A, hiT ? y3B : y3A};
                bf8 pal = *(bf8*)&awl;
#pragma unroll
                for (int fd = 0; fd < 4; ++fd) {
                    ctx_acc[fi][fd] = MFMA(pah, vfh[fd], ctx_acc[fi][fd]);
                    ctx_acc[fi][fd] = MFMA(pal, vfh[fd], ctx_acc[fi][fd]);
                    ctx_acc[fi][fd] = MFMA(pah, vfl[fd], ctx_acc[fi][fd]);
                }
            }
        }
    }

    // ---- reduce ctx_acc across the wj wave pair (Sh/Sl reused as scratch) ----
    __syncthreads();                         // all waves done reading Sh/Sl
    float* red = (wi == 0) ? (float*)Sh : (float*)Sl;   // 4096 floats each
    if (wj == 1) {
#pragma unroll
        for (int fi = 0; fi < 4; ++fi)
#pragma unroll
            for (int fd = 0; fd < 4; ++fd)
#pragma unroll
                for (int rg = 0; rg < 4; ++rg) {
                    int idx = (fi * 4 + fd) * 4 + rg;
                    red[lane * 64 + ((idx + lane) & 63)] = ctx_acc[fi][fd][rg];
                }
    }
    __syncthreads();
    if (wj == 0) {
        const int b_ = bh >> 4, h = bh & 15;
#pragma unroll
        for (int fi = 0; fi < 4; ++fi)
#pragma unroll
            for (int fd = 0; fd < 4; ++fd)
#pragma unroll
                for (int rg = 0; rg < 4; ++rg) {
                    int idx = (fi * 4 + fd) * 4 + rg;
                    float val = ctx_acc[fi][fd][rg] + red[lane * 64 + ((idx + lane) & 63)];
                    int ii = i0 + wi * 64 + fi * 16 + g * 4 + rg;
                    int d = fd * 16 + li;
                    size_t o = ((size_t)b_ * 1024 + ii) * 1024 + h * 64 + d;
                    unsigned short hv = f2bf(val);
                    unsigned short lv = f2bf(val - bf2f(hv));
                    __builtin_nontemporal_store(hv, &ctx_hi[o]);
                    __builtin_nontemporal_store(lv, &ctx_lo[o]);
                }
    }
}

extern "C" void kernel_launch(void* const* d_in, const int* in_sizes, int n_in,
                              void* d_out, int out_size, void* d_ws, size_t ws_size,
                              hipStream_t stream)
{
    const float* query = (const float*)d_in[0];
    const float* key_  = (const float*)d_in[1];
    const float* value = (const float*)d_in[2];
    const int*   mask  = (const int*)d_in[3];
    const float* Wq = (const float*)d_in[4];
    const float* bq = (const float*)d_in[5];
    const float* Wk = (const float*)d_in[6];
    const float* bk = (const float*)d_in[7];
    const float* Wv = (const float*)d_in[8];
    const float* bv = (const float*)d_in[9];
    const float* Wo = (const float*)d_in[10];
    const float* bo = (const float*)d_in[11];
    const float* emb = (const float*)d_in[12];

    // workspace: 80.0 MB (<= 84.1 MB proven in earlier rounds)
    unsigned short* wt_hi = (unsigned short*)d_ws;           // [4][1024][1024]
    unsigned short* wt_lo = wt_hi + (size_t)4 * 1048576;
    unsigned short* qh_hi = wt_lo + (size_t)4 * 1048576;     // [64][1024][64]
    unsigned short* qh_lo = qh_hi + 4194304;
    unsigned short* kh_hi = qh_lo + 4194304;
    unsigned short* kh_lo = kh_hi + 4194304;
    unsigned short* vt_hi = kh_lo + 4194304;                 // [64][64][1024] (written by proj directly)
    unsigned short* vt_lo = vt_hi + 4194304;
    unsigned short* ctx_hi = vt_lo + 4194304;                // [4][1024][1024]
    unsigned short* ctx_lo = ctx_hi + 4194304;
    // bitmask overlays the (dead-after-projection) Wq^T-hi region:
    unsigned long long* mb = (unsigned long long*)d_ws;      // [65536] = 512 KB

    float* out  = (float*)d_out;
    float* attn = (float*)d_out + 4194304;

    dim3 blk(256);
    wtrans_kernel<<<dim3(16, 16, 4), blk, 0, stream>>>(Wq, Wk, Wv, Wo, wt_hi, wt_lo);
    proj_qkv_kernel<<<dim3(32, 8, 3), blk, 0, stream>>>(query, key_, value, wt_hi, wt_lo,
                                                        bq, bk, bv, qh_hi, qh_lo,
                                                        kh_hi, kh_lo, vt_hi, vt_lo);
    maskbits_kernel<<<dim3(256), blk, 0, stream>>>(mask, mb);   // after proj (mb overlays Wq^T)
    attn_fused_kernel<<<dim3(64, 8), blk, 0, stream>>>(qh_hi, qh_lo, kh_hi, kh_lo,
                                                       vt_hi, vt_lo, emb, mb,
                                                       attn, ctx_hi, ctx_lo);
    outproj_kernel<<<dim3(32, 8), blk, 0, stream>>>(ctx_hi, ctx_lo,
                                                    wt_hi + (size_t)3 * 1048576,
                                                    wt_lo + (size_t)3 * 1048576, bo, out);
}

// Round 17
// 465.788 us; speedup vs baseline: 1.3723x; 1.0008x over previous
//
#include <hip/hip_runtime.h>
#include <math.h>

#define BB 4
#define SS 1024
#define EE 1024
#define HH 16
#define DD 64
#define RR 129
#define PRELW 130   // Pr LDS row stride (ushorts)

typedef __attribute__((ext_vector_type(4))) float f32x4;
typedef __attribute__((ext_vector_type(4))) int   i32x4;
typedef __attribute__((ext_vector_type(8))) short bf8;   // 8 bf16 = 4 VGPR (MFMA A/B frag)
typedef __attribute__((ext_vector_type(4))) short s4v;   // 4 bf16 = 8B

#define MFMA(a, b, c) __builtin_amdgcn_mfma_f32_16x16x32_bf16(a, b, c, 0, 0, 0)

__device__ __forceinline__ float bf2f(unsigned short u) {
    return __uint_as_float(((unsigned)u) << 16);
}
__device__ __forceinline__ unsigned short f2bf(float x) {  // RNE
    unsigned u = __float_as_uint(x);
    return (unsigned short)((u + 0x7fffu + ((u >> 16) & 1u)) >> 16);
}

// async global->LDS, 16B per lane; LDS dest = wave-uniform base + lane*16
__device__ __forceinline__ void glds16(const unsigned short* g, unsigned short* l) {
    __builtin_amdgcn_global_load_lds(
        (const __attribute__((address_space(1))) void*)g,
        (__attribute__((address_space(3))) void*)l,
        16, 0, 0);
}

// ---------------------------------------------------------------------------
// Weight transpose+split: W[K][N] fp32 -> Wt_hi/lo[N][K] bf16.
// ---------------------------------------------------------------------------
__global__ __launch_bounds__(256, 4)
void wtrans_kernel(const float* __restrict__ Wq, const float* __restrict__ Wk,
                   const float* __restrict__ Wv, const float* __restrict__ Wo,
                   unsigned short* __restrict__ wt_hi, unsigned short* __restrict__ wt_lo)
{
    __shared__ float T[64][65];
    const int w = blockIdx.z;
    const float* W = w == 0 ? Wq : (w == 1 ? Wk : (w == 2 ? Wv : Wo));
    const int n0 = blockIdx.x * 64, k0 = blockIdx.y * 64;
    const int tid = threadIdx.x;
#pragma unroll
    for (int i = 0; i < 4; ++i) {
        int c = tid + 256 * i; int r = c >> 4, c4 = c & 15;
        f32x4 v = *(const f32x4*)(W + (size_t)(k0 + r) * EE + n0 + c4 * 4);
        T[r][c4 * 4 + 0] = v.x; T[r][c4 * 4 + 1] = v.y;
        T[r][c4 * 4 + 2] = v.z; T[r][c4 * 4 + 3] = v.w;
    }
    __syncthreads();
#pragma unroll
    for (int i = 0; i < 4; ++i) {
        int c = tid + 256 * i; int r = c >> 4, c4 = c & 15;   // r = n_local, c4 = k group
        float x0 = T[c4 * 4 + 0][r], x1 = T[c4 * 4 + 1][r];
        float x2 = T[c4 * 4 + 2][r], x3 = T[c4 * 4 + 3][r];
        unsigned short h0 = f2bf(x0), h1 = f2bf(x1), h2 = f2bf(x2), h3 = f2bf(x3);
        unsigned short l0 = f2bf(x0 - bf2f(h0)), l1 = f2bf(x1 - bf2f(h1));
        unsigned short l2 = f2bf(x2 - bf2f(h2)), l3 = f2bf(x3 - bf2f(h3));
        size_t o = (size_t)w * 1048576 + (size_t)(n0 + r) * 1024 + k0 + c4 * 4;
        *(s4v*)&wt_hi[o] = (s4v){(short)h0, (short)h1, (short)h2, (short)h3};
        *(s4v*)&wt_lo[o] = (s4v){(short)l0, (short)l1, (short)l2, (short)l3};
    }
}

// ---------------------------------------------------------------------------
// Pack attn_mask int32 -> bitmask u64 words. One thread per word (64 ints).
// ---------------------------------------------------------------------------
__global__ __launch_bounds__(256)
void maskbits_kernel(const int* __restrict__ mask, unsigned long long* __restrict__ mb)
{
    const int w = blockIdx.x * 256 + threadIdx.x;   // 65536 words
    const int* p = mask + (size_t)w * 64;
    unsigned long long bits = 0;
#pragma unroll
    for (int i = 0; i < 16; ++i) {
        int4 v = *(const int4*)(p + i * 4);
        bits |= (unsigned long long)(v.x != 0) << (i * 4 + 0);
        bits |= (unsigned long long)(v.y != 0) << (i * 4 + 1);
        bits |= (unsigned long long)(v.z != 0) << (i * 4 + 2);
        bits |= (unsigned long long)(v.w != 0) << (i * 4 + 3);
    }
    mb[w] = bits;
}

// ---------------------------------------------------------------------------
// Split-bf16 MFMA GEMM body (projections / out-proj).
// B staging (and A staging when ASRC==1) uses global_load_lds with linear
// LDS dest + pre-swizzled GLOBAL source (rule #21) — same verified mapping
// as the attn kernel: lane l, iter i -> base (wid*4+i)*512, row
// sr=(wid*4+i)*8+(l>>3), chunk sc=(l&7)^(sr&7). LDS image identical to the
// old reg-staged path; fragment reads unchanged.
// vt_out=1 (with EPI==0): write Y in transposed-heads layout [bh][d][s].
// ---------------------------------------------------------------------------
template<int ASRC, int EPI>
__device__ __forceinline__ void gemm_body(
    const float* __restrict__ Af,
    const unsigned short* __restrict__ Ah_g, const unsigned short* __restrict__ Al_g,
    const unsigned short* __restrict__ Bh_g, const unsigned short* __restrict__ Bl_g,
    const float* __restrict__ bias,
    float* __restrict__ Yf, unsigned short* __restrict__ Yh, unsigned short* __restrict__ Yl,
    unsigned short* As_h, unsigned short* As_l, unsigned short* Bs_h, unsigned short* Bs_l,
    int m0, int n0, int vt_out)
{
    const int tid = threadIdx.x, lane = tid & 63, wid = tid >> 6;
    const int wm = (wid >> 1) * 64, wn = (wid & 1) * 64;
    f32x4 zero4 = {0.f, 0.f, 0.f, 0.f};
    f32x4 acc[4][4];
#pragma unroll
    for (int a = 0; a < 4; ++a)
#pragma unroll
        for (int b = 0; b < 4; ++b) acc[a][b] = zero4;

    // glds staging coordinates (constant per thread)
    int gr_[4], gc_[4];
#pragma unroll
    for (int i = 0; i < 4; ++i) {
        gr_[i] = (wid * 4 + i) * 8 + (lane >> 3);
        gc_[i] = (lane & 7) ^ (gr_[i] & 7);
    }

    for (int kt = 0; kt < 1024; kt += 64) {
        __syncthreads();
        if (ASRC == 0) {
#pragma unroll
            for (int i = 0; i < 8; ++i) {
                int c = tid + 256 * i; int r = c >> 4, c4 = c & 15;
                f32x4 v = *(const f32x4*)(Af + (size_t)(m0 + r) * 1024 + kt + c4 * 4);
                unsigned short h0 = f2bf(v.x), h1 = f2bf(v.y), h2 = f2bf(v.z), h3 = f2bf(v.w);
                unsigned short l0 = f2bf(v.x - bf2f(h0)), l1 = f2bf(v.y - bf2f(h1));
                unsigned short l2 = f2bf(v.z - bf2f(h2)), l3 = f2bf(v.w - bf2f(h3));
                int off = r * 64 + (((c4 >> 1) ^ (r & 7)) * 8) + (c4 & 1) * 4;
                *(s4v*)&As_h[off] = (s4v){(short)h0, (short)h1, (short)h2, (short)h3};
                *(s4v*)&As_l[off] = (s4v){(short)l0, (short)l1, (short)l2, (short)l3};
            }
        } else {
#pragma unroll
            for (int i = 0; i < 4; ++i) {
                glds16(Ah_g + (size_t)(m0 + gr_[i]) * 1024 + kt + gc_[i] * 8,
                       As_h + (size_t)(wid * 4 + i) * 512);
                glds16(Al_g + (size_t)(m0 + gr_[i]) * 1024 + kt + gc_[i] * 8,
                       As_l + (size_t)(wid * 4 + i) * 512);
            }
        }
#pragma unroll
        for (int i = 0; i < 4; ++i) {
            glds16(Bh_g + (size_t)(n0 + gr_[i]) * 1024 + kt + gc_[i] * 8,
                   Bs_h + (size_t)(wid * 4 + i) * 512);
            glds16(Bl_g + (size_t)(n0 + gr_[i]) * 1024 + kt + gc_[i] * 8,
                   Bs_l + (size_t)(wid * 4 + i) * 512);
        }
        __syncthreads();
#pragma unroll
        for (int ks = 0; ks < 2; ++ks) {
            bf8 ah[4], al[4], bh[4], bl[4];
#pragma unroll
            for (int f = 0; f < 4; ++f) {
                int ra = wm + f * 16 + (lane & 15);
                int ca = (ks * 4 + (lane >> 4)) ^ (ra & 7);
                ah[f] = *(const bf8*)&As_h[ra * 64 + ca * 8];
                al[f] = *(const bf8*)&As_l[ra * 64 + ca * 8];
                int rb = wn + f * 16 + (lane & 15);
                int cb = (ks * 4 + (lane >> 4)) ^ (rb & 7);
                bh[f] = *(const bf8*)&Bs_h[rb * 64 + cb * 8];
                bl[f] = *(const bf8*)&Bs_l[rb * 64 + cb * 8];
            }
#pragma unroll
            for (int fi = 0; fi < 4; ++fi)
#pragma unroll
                for (int fj = 0; fj < 4; ++fj) {
                    acc[fi][fj] = MFMA(ah[fi], bh[fj], acc[fi][fj]);
                    acc[fi][fj] = MFMA(al[fi], bh[fj], acc[fi][fj]);
                    acc[fi][fj] = MFMA(ah[fi], bl[fj], acc[fi][fj]);
                }
        }
    }
    // epilogue: C/D layout (m89): col = lane&15, row = (lane>>4)*4 + reg
#pragma unroll
    for (int fi = 0; fi < 4; ++fi)
#pragma unroll
        for (int fj = 0; fj < 4; ++fj)
#pragma unroll
            for (int rg = 0; rg < 4; ++rg) {
                int m = m0 + wm + fi * 16 + ((lane >> 4) << 2) + rg;
                int n = n0 + wn + fj * 16 + (lane & 15);
                float val = acc[fi][fj][rg] + bias[n];
                if (EPI == 0) {
                    int b = m >> 10, s = m & 1023, h = n >> 6, d = n & 63;
                    size_t o = vt_out
                        ? (((size_t)(b * 16 + h)) * 64 + d) * 1024 + s
                        : (((size_t)(b * 16 + h)) * 1024 + s) * 64 + d;
                    unsigned short hv = f2bf(val);
                    unsigned short lv = f2bf(val - bf2f(hv));
                    Yh[o] = hv; Yl[o] = lv;
                } else {
                    Yf[(size_t)m * 1024 + n] = val;
                }
            }
}

__global__ __launch_bounds__(256, 2)
void proj_qkv_kernel(const float* __restrict__ q_in, const float* __restrict__ k_in,
                     const float* __restrict__ v_in,
                     const unsigned short* __restrict__ wt_hi, const unsigned short* __restrict__ wt_lo,
                     const float* __restrict__ bq, const float* __restrict__ bk,
                     const float* __restrict__ bv,
                     unsigned short* qh_hi, unsigned short* qh_lo,
                     unsigned short* kh_hi, unsigned short* kh_lo,
                     unsigned short* vt_hi, unsigned short* vt_lo)
{
    __shared__ __align__(16) unsigned short As_h[128 * 64], As_l[128 * 64];
    __shared__ __align__(16) unsigned short Bs_h[128 * 64], Bs_l[128 * 64];
    const int z = blockIdx.z;
    const float* X = z == 0 ? q_in : (z == 1 ? k_in : v_in);
    const float* bias = z == 0 ? bq : (z == 1 ? bk : bv);
    unsigned short* Yh = z == 0 ? qh_hi : (z == 1 ? kh_hi : vt_hi);
    unsigned short* Yl = z == 0 ? qh_lo : (z == 1 ? kh_lo : vt_lo);
    gemm_body<0, 0>(X, nullptr, nullptr,
                    wt_hi + (size_t)z * 1048576, wt_lo + (size_t)z * 1048576,
                    bias, nullptr, Yh, Yl, As_h, As_l, Bs_h, Bs_l,
                    blockIdx.x * 128, blockIdx.y * 128, z == 2 ? 1 : 0);
}

__global__ __launch_bounds__(256, 2)
void outproj_kernel(const unsigned short* __restrict__ ctx_hi, const unsigned short* __restrict__ ctx_lo,
                    const unsigned short* __restrict__ wo_hi, const unsigned short* __restrict__ wo_lo,
                    const float* __restrict__ bo, float* __restrict__ out)
{
    __shared__ __align__(16) unsigned short As_h[128 * 64], As_l[128 * 64];
    __shared__ __align__(16) unsigned short Bs_h[128 * 64], Bs_l[128 * 64];
    gemm_body<1, 1>(nullptr, ctx_hi, ctx_lo, wo_hi, wo_lo, bo, out, nullptr, nullptr,
                    As_h, As_l, Bs_h, Bs_l, blockIdx.x * 128, blockIdx.y * 128, 0);
}

// ---------------------------------------------------------------------------
// Fused attention (r16 config — best measured: attn 330 us / total 466 us).
// Grid (x=head, y=i-block): all i-blocks of a head on ONE XCD -> K/V L2
// reuse. attn stream + ctx stored nontemporal. K/Q staged via glds (linear
// LDS dest + pre-swizzled global source).
// ---------------------------------------------------------------------------
__global__ __launch_bounds__(256, 2)
void attn_fused_kernel(const unsigned short* __restrict__ qh_hi, const unsigned short* __restrict__ qh_lo,
                       const unsigned short* __restrict__ kh_hi, const unsigned short* __restrict__ kh_lo,
                       const unsigned short* __restrict__ vt_hi, const unsigned short* __restrict__ vt_lo,
                       const float* __restrict__ emb, const unsigned long long* __restrict__ mb,
                       float* __restrict__ attn,
                       unsigned short* __restrict__ ctx_hi, unsigned short* __restrict__ ctx_lo)
{
    __shared__ __align__(16) unsigned short Sh[128 * 64], Sl[128 * 64];  // Q then K tiles
    __shared__ __align__(16) unsigned short Pr[128 * PRELW];
    __shared__ float Sm[2][128], Ss[2][128], SmF[128], SsF[128];
    const int tid = threadIdx.x, lane = tid & 63, wid = tid >> 6;
    const int wi = wid >> 1, wj = wid & 1;
    const int g = lane >> 4, li = lane & 15;
    const int bh = blockIdx.x, i0 = blockIdx.y * 128, b = bh >> 4;
    const f32x4 zero4 = {0.f, 0.f, 0.f, 0.f};

    // glds staging coordinates (constant per thread)
    int sr_[4], sc_[4];
#pragma unroll
    for (int i = 0; i < 4; ++i) {
        sr_[i] = (wid * 4 + i) * 8 + (lane >> 3);
        sc_[i] = (lane & 7) ^ (sr_[i] & 7);
    }

    // ---- stage Q tile (glds, linear dest / pre-swizzled source) ----
    const unsigned short* qbh = qh_hi + ((size_t)bh * 1024 + i0) * 64;
    const unsigned short* qbl = qh_lo + ((size_t)bh * 1024 + i0) * 64;
#pragma unroll
    for (int i = 0; i < 4; ++i) {
        glds16(qbh + sr_[i] * 64 + sc_[i] * 8, Sh + (size_t)(wid * 4 + i) * 512);
        glds16(qbl + sr_[i] * 64 + sc_[i] * 8, Sl + (size_t)(wid * 4 + i) * 512);
    }
    __syncthreads();

    // ---- Q fragments to registers ----
    bf8 qfh[4][2], qfl[4][2];
#pragma unroll
    for (int fi = 0; fi < 4; ++fi)
#pragma unroll
        for (int ks = 0; ks < 2; ++ks) {
            int rb = wi * 64 + fi * 16 + li;
            int cb = (ks * 4 + g) ^ (rb & 7);
            qfh[fi][ks] = *(const bf8*)&Sh[rb * 64 + cb * 8];
            qfl[fi][ks] = *(const bf8*)&Sl[rb * 64 + cb * 8];
        }

    // ---- rel-bias Pr[i][r] = q_hi[i]. emb[r] via MFMA, stored bf16 ----
    for (int t = wid; t < 72; t += 4) {       // 8 i-tiles x 9 r-tiles
        const int it = t / 9, rt = t % 9;
        f32x4 pc = zero4;
#pragma unroll
        for (int ks = 0; ks < 2; ++ks) {
            int ra = it * 16 + li;
            int ca = (ks * 4 + g) ^ (ra & 7);
            bf8 aq = *(const bf8*)&Sh[ra * 64 + ca * 8];
            int er = rt * 16 + li; if (er > 128) er = 128;   // clamp OOB rows
            const float* ep = emb + (size_t)er * 64 + ks * 32 + g * 8;
            f32x4 e0 = *(const f32x4*)ep;
            f32x4 e1 = *(const f32x4*)(ep + 4);
            bf8 be = {(short)f2bf(e0.x), (short)f2bf(e0.y), (short)f2bf(e0.z), (short)f2bf(e0.w),
                      (short)f2bf(e1.x), (short)f2bf(e1.y), (short)f2bf(e1.z), (short)f2bf(e1.w)};
            pc = MFMA(aq, be, pc);
        }
        const int rcol = rt * 16 + li;
        if (rcol < RR) {
#pragma unroll
            for (int rg = 0; rg < 4; ++rg)
                Pr[(it * 16 + g * 4 + rg) * PRELW + rcol] = f2bf(pc[rg]);
        }
    }

    float rm[4], rs[4];
#pragma unroll
    for (int i = 0; i < 4; ++i) { rm[i] = -3.0e38f; rs[i] = 0.f; }

    // ================= PASS 1: stats only =================
    for (int jt = 0; jt < 8; ++jt) {
        __syncthreads();   // Pr writes done (jt=0); prior frag reads done (jt>0)
        const unsigned short* kbh = kh_hi + ((size_t)bh * 1024 + jt * 128) * 64;
        const unsigned short* kbl = kh_lo + ((size_t)bh * 1024 + jt * 128) * 64;
#pragma unroll
        for (int i = 0; i < 4; ++i) {
            glds16(kbh + sr_[i] * 64 + sc_[i] * 8, Sh + (size_t)(wid * 4 + i) * 512);
            glds16(kbl + sr_[i] * 64 + sc_[i] * 8, Sl + (size_t)(wid * 4 + i) * 512);
        }
        __syncthreads();
        f32x4 acc[4][4];  // [fj][fi]
#pragma unroll
        for (int a = 0; a < 4; ++a)
#pragma unroll
            for (int c = 0; c < 4; ++c) acc[a][c] = zero4;
#pragma unroll
        for (int ks = 0; ks < 2; ++ks) {
            bf8 kfh[4], kfl[4];
#pragma unroll
            for (int fj = 0; fj < 4; ++fj) {
                int ra = wj * 64 + fj * 16 + li;
                int ca = (ks * 4 + g) ^ (ra & 7);
                kfh[fj] = *(const bf8*)&Sh[ra * 64 + ca * 8];
                kfl[fj] = *(const bf8*)&Sl[ra * 64 + ca * 8];
            }
#pragma unroll
            for (int fj = 0; fj < 4; ++fj)
#pragma unroll
                for (int fi = 0; fi < 4; ++fi) {
                    acc[fj][fi] = MFMA(kfh[fj], qfh[fi][ks], acc[fj][fi]);
                    acc[fj][fi] = MFMA(kfl[fj], qfh[fi][ks], acc[fj][fi]);
                    acc[fj][fi] = MFMA(kfh[fj], qfl[fi][ks], acc[fj][fi]);
                }
        }
#pragma unroll
        for (int fi = 0; fi < 4; ++fi) {
            const int rowL = wi * 64 + fi * 16 + li;
            const int ii = i0 + rowL;
            const unsigned long long mw = mb[((size_t)b * 1024 + ii) * 16 + jt * 2 + wj];
            float p16[4][4];
            float tmax = -3.0e38f;
#pragma unroll
            for (int fj = 0; fj < 4; ++fj)
#pragma unroll
                for (int rg = 0; rg < 4; ++rg) {
                    int jloc = fj * 16 + g * 4 + rg;
                    int jj = jt * 128 + wj * 64 + jloc;
                    int dd = ii - jj; dd = dd < -64 ? -64 : (dd > 64 ? 64 : dd);
                    float s = acc[fj][fi][rg] * 0.125f + bf2f(Pr[rowL * PRELW + dd + 64]);
                    if (!((mw >> jloc) & 1ull)) s = -1.0e30f;
                    p16[fj][rg] = s;
                    tmax = fmaxf(tmax, s);
                }
            tmax = fmaxf(tmax, __shfl_xor(tmax, 16, 64));
            tmax = fmaxf(tmax, __shfl_xor(tmax, 32, 64));
            float nm = fmaxf(rm[fi], tmax);
            float ps = 0.f;
#pragma unroll
            for (int fj = 0; fj < 4; ++fj)
#pragma unroll
                for (int rg = 0; rg < 4; ++rg) ps += __expf(p16[fj][rg] - nm);
            ps += __shfl_xor(ps, 16, 64);
            ps += __shfl_xor(ps, 32, 64);
            rs[fi] = rs[fi] * __expf(rm[fi] - nm) + ps;
            rm[fi] = nm;
        }
    }
    // combine the two j-half waves per i-row
#pragma unroll
    for (int fi = 0; fi < 4; ++fi) {
        if (lane < 16) {
            Sm[wj][wi * 64 + fi * 16 + li] = rm[fi];
            Ss[wj][wi * 64 + fi * 16 + li] = rs[fi];
        }
    }
    __syncthreads();
    if (tid < 128) {
        float m0_ = Sm[0][tid], m1_ = Sm[1][tid];
        float mmx = fmaxf(m0_, m1_);
        SmF[tid] = mmx;
        SsF[tid] = Ss[0][tid] * __expf(m0_ - mmx) + Ss[1][tid] * __expf(m1_ - mmx);
    }
    __syncthreads();
    float mm4[4], iv4[4];
#pragma unroll
    for (int fi = 0; fi < 4; ++fi) {
        mm4[fi] = SmF[wi * 64 + fi * 16 + li];
        iv4[fi] = 1.f / SsF[wi * 64 + fi * 16 + li];
    }

    f32x4 ctx_acc[4][4];  // [fi][fd]
#pragma unroll
    for (int a = 0; a < 4; ++a)
#pragma unroll
        for (int c = 0; c < 4; ++c) ctx_acc[a][c] = zero4;

    // ================= PASS 2: weights write + PV =================
    for (int jt = 0; jt < 8; ++jt) {
        __syncthreads();
        const unsigned short* kbh = kh_hi + ((size_t)bh * 1024 + jt * 128) * 64;
        const unsigned short* kbl = kh_lo + ((size_t)bh * 1024 + jt * 128) * 64;
#pragma unroll
        for (int i = 0; i < 4; ++i) {
            glds16(kbh + sr_[i] * 64 + sc_[i] * 8, Sh + (size_t)(wid * 4 + i) * 512);
            glds16(kbl + sr_[i] * 64 + sc_[i] * 8, Sl + (size_t)(wid * 4 + i) * 512);
        }
        __syncthreads();
        f32x4 acc[4][4];  // identical recompute -> identical s values
#pragma unroll
        for (int a = 0; a < 4; ++a)
#pragma unroll
            for (int c = 0; c < 4; ++c) acc[a][c] = zero4;
#pragma unroll
        for (int ks = 0; ks < 2; ++ks) {
            bf8 kfh[4], kfl[4];
#pragma unroll
            for (int fj = 0; fj < 4; ++fj) {
                int ra = wj * 64 + fj * 16 + li;
                int ca = (ks * 4 + g) ^ (ra & 7);
                kfh[fj] = *(const bf8*)&Sh[ra * 64 + ca * 8];
                kfl[fj] = *(const bf8*)&Sl[ra * 64 + ca * 8];
            }
#pragma unroll
            for (int fj = 0; fj < 4; ++fj)
#pragma unroll
                for (int fi = 0; fi < 4; ++fi) {
                    acc[fj][fi] = MFMA(kfh[fj], qfh[fi][ks], acc[fj][fi]);
                    acc[fj][fi] = MFMA(kfl[fj], qfh[fi][ks], acc[fj][fi]);
                    acc[fj][fi] = MFMA(kfh[fj], qfl[fi][ks], acc[fj][fi]);
                }
        }
        // per 32-j chunk: V frags from global vt, p+store+pack, shfl, PV MFMA
#pragma unroll
        for (int c = 0; c < 2; ++c) {
            bf8 vfh[4], vfl[4];
#pragma unroll
            for (int fd = 0; fd < 4; ++fd) {
                size_t vb = (size_t)bh * 65536 + (size_t)(fd * 16 + li) * 1024
                          + jt * 128 + wj * 64 + c * 32 + g * 8;
                vfh[fd] = *(const bf8*)(vt_hi + vb);
                vfl[fd] = *(const bf8*)(vt_lo + vb);
            }
#pragma unroll
            for (int fi = 0; fi < 4; ++fi) {
                const int rowL = wi * 64 + fi * 16 + li;
                const int ii = i0 + rowL;
                const unsigned long long mw = mb[((size_t)b * 1024 + ii) * 16 + jt * 2 + wj];
                const float mmf = mm4[fi], ivf = iv4[fi];
                float* arow = attn + ((size_t)bh * 1024 + ii) * 1024 + jt * 128 + wj * 64 + g * 4;
                unsigned wh[2][2], wl[2][2];
#pragma unroll
                for (int t = 0; t < 2; ++t) {
                    const int fj = c * 2 + t;
                    f32x4 pv;
#pragma unroll
                    for (int rg = 0; rg < 4; ++rg) {
                        int jloc = fj * 16 + g * 4 + rg;
                        int jj = jt * 128 + wj * 64 + jloc;
                        int dd = ii - jj; dd = dd < -64 ? -64 : (dd > 64 ? 64 : dd);
                        float s = acc[fj][fi][rg] * 0.125f + bf2f(Pr[rowL * PRELW + dd + 64]);
                        if (!((mw >> jloc) & 1ull)) s = -1.0e30f;
                        pv[rg] = __expf(s - mmf) * ivf;
                    }
                    __builtin_nontemporal_store(pv, (f32x4*)(arow + fj * 16));  // final weights
                    unsigned short h0 = f2bf(pv.x), h1 = f2bf(pv.y), h2 = f2bf(pv.z), h3 = f2bf(pv.w);
                    wh[t][0] = (unsigned)h0 | ((unsigned)h1 << 16);
                    wh[t][1] = (unsigned)h2 | ((unsigned)h3 << 16);
                    unsigned short l0 = f2bf(pv.x - bf2f(h0)), l1 = f2bf(pv.y - bf2f(h1));
                    unsigned short l2 = f2bf(pv.z - bf2f(h2)), l3 = f2bf(pv.w - bf2f(h3));
                    wl[t][0] = (unsigned)l0 | ((unsigned)l1 << 16);
                    wl[t][1] = (unsigned)l2 | ((unsigned)l3 << 16);
                }
                // redistribute: dest lane g needs tile (g>>1), source groups (g&1)*2, +1
                const int src0 = ((g & 1) * 2) * 16 + li;
                const int src1 = src0 + 16;
                const bool hiT = (g >> 1) & 1;
                int x0A = __shfl((int)wh[0][0], src0, 64), x0B = __shfl((int)wh[1][0], src0, 64);
                int x1A = __shfl((int)wh[0][1], src0, 64), x1B = __shfl((int)wh[1][1], src0, 64);
                int x2A = __shfl((int)wh[0][0], src1, 64), x2B = __shfl((int)wh[1][0], src1, 64);
                int x3A = __shfl((int)wh[0][1], src1, 64), x3B = __shfl((int)wh[1][1], src1, 64);
                i32x4 awh = {hiT ? x0B : x0A, hiT ? x1B : x1A, hiT ? x2B : x2A, hiT ? x3B : x3A};
                bf8 pah = *(bf8*)&awh;
                int y0A = __shfl((int)wl[0][0], src0, 64), y0B = __shfl((int)wl[1][0], src0, 64);
                int y1A = __shfl((int)wl[0][1], src0, 64), y1B = __shfl((int)wl[1][1], src0, 64);
                int y2A = __shfl((int)wl[0][0], src1, 64), y2B = __shfl((int)wl[1][0], src1, 64);
                int y3A = __shfl((int)wl[0][1], src1, 64), y3B = __shfl((int)wl[1][1], src1, 64);
                i32x4 awl = {hiT ? y0B : y0A, hiT ? y1B : y1A, hiT ? y2B : y2A, hiT ? y3B : y3A};
                bf8 pal = *(bf8*)&awl;
#pragma unroll
                for (int fd = 0; fd < 4; ++fd) {
                    ctx_acc[fi][fd] = MFMA(pah, vfh[fd], ctx_acc[fi][fd]);
                    ctx_acc[fi][fd] = MFMA(pal, vfh[fd], ctx_acc[fi][fd]);
                    ctx_acc[fi][fd] = MFMA(pah, vfl[fd], ctx_acc[fi][fd]);
                }
            }
        }
    }

    // ---- reduce ctx_acc across the wj wave pair (Sh/Sl reused as scratch) ----
    __syncthreads();                         // all waves done reading Sh/Sl
    float* red = (wi == 0) ? (float*)Sh : (float*)Sl;   // 4096 floats each
    if (wj == 1) {
#pragma unroll
        for (int fi = 0; fi < 4; ++fi)
#pragma unroll
            for (int fd = 0; fd < 4; ++fd)
#pragma unroll
                for (int rg = 0; rg < 4; ++rg) {
                    int idx = (fi * 4 + fd) * 4 + rg;
                    red[lane * 64 + ((idx + lane) & 63)] = ctx_acc[fi][fd][rg];
                }
    }
    __syncthreads();
    if (wj == 0) {
        const int b_ = bh >> 4, h = bh & 15;
#pragma unroll
        for (int fi = 0; fi < 4; ++fi)
#pragma unroll
            for (int fd = 0; fd < 4; ++fd)
#pragma unroll
                for (int rg = 0; rg < 4; ++rg) {
                    int idx = (fi * 4 + fd) * 4 + rg;
                    float val = ctx_acc[fi][fd][rg] + red[lane * 64 + ((idx + lane) & 63)];
                    int ii = i0 + wi * 64 + fi * 16 + g * 4 + rg;
                    int d = fd * 16 + li;
                    size_t o = ((size_t)b_ * 1024 + ii) * 1024 + h * 64 + d;
                    unsigned short hv = f2bf(val);
                    unsigned short lv = f2bf(val - bf2f(hv));
                    __builtin_nontemporal_store(hv, &ctx_hi[o]);
                    __builtin_nontemporal_store(lv, &ctx_lo[o]);
                }
    }
}

extern "C" void kernel_launch(void* const* d_in, const int* in_sizes, int n_in,
                              void* d_out, int out_size, void* d_ws, size_t ws_size,
                              hipStream_t stream)
{
    const float* query = (const float*)d_in[0];
    const float* key_  = (const float*)d_in[1];
    const float* value = (const float*)d_in[2];
    const int*   mask  = (const int*)d_in[3];
    const float* Wq = (const float*)d_in[4];
    const float* bq = (const float*)d_in[5];
    const float* Wk = (const float*)d_in[6];
    const float* bk = (const float*)d_in[7];
    const float* Wv = (const float*)d_in[8];
    const float* bv = (const float*)d_in[9];
    const float* Wo = (const float*)d_in[10];
    const float* bo = (const float*)d_in[11];
    const float* emb = (const float*)d_in[12];

    // workspace: 80.0 MB (<= 84.1 MB proven in earlier rounds)
    unsigned short* wt_hi = (unsigned short*)d_ws;           // [4][1024][1024]
    unsigned short* wt_lo = wt_hi + (size_t)4 * 1048576;
    unsigned short* qh_hi = wt_lo + (size_t)4 * 1048576;     // [64][1024][64]
    unsigned short* qh_lo = qh_hi + 4194304;
    unsigned short* kh_hi = qh_lo + 4194304;
    unsigned short* kh_lo = kh_hi + 4194304;
    unsigned short* vt_hi = kh_lo + 4194304;                 // [64][64][1024] (written by proj directly)
    unsigned short* vt_lo = vt_hi + 4194304;
    unsigned short* ctx_hi = vt_lo + 4194304;                // [4][1024][1024]
    unsigned short* ctx_lo = ctx_hi + 4194304;
    // bitmask overlays the (dead-after-projection) Wq^T-hi region:
    unsigned long long* mb = (unsigned long long*)d_ws;      // [65536] = 512 KB

    float* out  = (float*)d_out;
    float* attn = (float*)d_out + 4194304;

    dim3 blk(256);
    wtrans_kernel<<<dim3(16, 16, 4), blk, 0, stream>>>(Wq, Wk, Wv, Wo, wt_hi, wt_lo);
    proj_qkv_kernel<<<dim3(32, 8, 3), blk, 0, stream>>>(query, key_, value, wt_hi, wt_lo,
                                                        bq, bk, bv, qh_hi, qh_lo,
                                                        kh_hi, kh_lo, vt_hi, vt_lo);
    maskbits_kernel<<<dim3(256), blk, 0, stream>>>(mask, mb);   // after proj (mb overlays Wq^T)
    attn_fused_kernel<<<dim3(64, 8), blk, 0, stream>>>(qh_hi, qh_lo, kh_hi, kh_lo,
                                                       vt_hi, vt_lo, emb, mb,
                                                       attn, ctx_hi, ctx_lo);
    outproj_kernel<<<dim3(32, 8), blk, 0, stream>>>(ctx_hi, ctx_lo,
                                                    wt_hi + (size_t)3 * 1048576,
                                                    wt_lo + (size_t)3 * 1048576, bo, out);
}